// Round 3
// baseline (10324.835 us; speedup 1.0000x reference)
//
#include <hip/hip_runtime.h>
#include <cmath>

// ---------------------------------------------------------------------------
// DragonHGT: 3-layer HGT + MLP stack + 7 task heads. fp32, ~218MB workspace.
// N=50000 nodes x 2 types, E=200000 edges x 3 relations, C=256 (H=4,D=64).
// Workspace plan (4 NxC buffers): xe, xs (persistent), B1 (kA/vM scratch),
// B2 (q/agg scratch). Schedule ordered so all projections read pre-update
// features; xs updated mid-phase only after vM2 is captured.
// ---------------------------------------------------------------------------

#define CDIM 256
#define HDIM 4
#define DDIM 64

__device__ __forceinline__ float gelu_f(float x) {
    return 0.5f * x * (1.0f + erff(x * 0.70710678118654752f));
}

__global__ __launch_bounds__(256) void zero_k(float* __restrict__ p, size_t n) {
    size_t i = (size_t)blockIdx.x * blockDim.x + threadIdx.x;
    const size_t stride = (size_t)gridDim.x * blockDim.x;
    for (; i < n; i += stride) p[i] = 0.0f;
}

// ---------------------------------------------------------------------------
// Tiled fp32 GEMM: C[M,Ncols] = op(A[M,256]) @ B[256,Ncols]  (+ epilogue)
// EPI: 0 = plain store
//      1 = skip blend: out = be*acc + (1-be)*Xold,  be = sigmoid(*skipv)
//          (safe when Cout == Xold: each element read+written by one thread)
//      2 = bias + relu: out = max(acc + bias[col], 0)
// PREGELU: apply exact gelu to A elements while loading.
// ---------------------------------------------------------------------------
template <int EPI, bool PREGELU>
__global__ __launch_bounds__(256) void gemm_k(
    const float* __restrict__ A, const float* __restrict__ B,
    float* __restrict__ Cout, int M, int Ncols,
    const float* __restrict__ bias, const float* __restrict__ skipv,
    const float* __restrict__ Xold) {
    __shared__ float As[16][68];  // [k][m]
    __shared__ float Bs[16][68];  // [k][n]
    const int tid = threadIdx.x;
    const int tx = tid & 15, ty = tid >> 4;
    const int bm = blockIdx.x * 64, bn = blockIdx.y * 64;
    const int K = 256;

    float acc[4][4] = {};
    const int ar = tid >> 2, ac4 = (tid & 3) * 4;   // A tile: 64 rows x 16 k
    const int br = tid >> 4, bc4 = (tid & 15) * 4;  // B tile: 16 k x 64 cols

    for (int k0 = 0; k0 < K; k0 += 16) {
        float4 av = make_float4(0.f, 0.f, 0.f, 0.f);
        const int arow = bm + ar;
        if (arow < M) av = *(const float4*)&A[(size_t)arow * K + k0 + ac4];
        if (PREGELU) {
            av.x = gelu_f(av.x); av.y = gelu_f(av.y);
            av.z = gelu_f(av.z); av.w = gelu_f(av.w);
        }
        const float4 bv = *(const float4*)&B[(size_t)(k0 + br) * Ncols + bn + bc4];
        __syncthreads();
        As[ac4 + 0][ar] = av.x; As[ac4 + 1][ar] = av.y;
        As[ac4 + 2][ar] = av.z; As[ac4 + 3][ar] = av.w;
        *(float4*)&Bs[br][bc4] = bv;
        __syncthreads();
#pragma unroll
        for (int k = 0; k < 16; ++k) {
            const float4 a = *(const float4*)&As[k][ty * 4];
            const float4 b = *(const float4*)&Bs[k][tx * 4];
            const float aa[4] = {a.x, a.y, a.z, a.w};
            const float bb[4] = {b.x, b.y, b.z, b.w};
#pragma unroll
            for (int i = 0; i < 4; ++i)
#pragma unroll
                for (int j = 0; j < 4; ++j) acc[i][j] += aa[i] * bb[j];
        }
    }

    float be = 0.f, ombe = 0.f;
    if (EPI == 1) {
        const float s = skipv[0];
        be = 1.0f / (1.0f + expf(-s));
        ombe = 1.0f - be;
    }
    const int cb = bn + tx * 4;
#pragma unroll
    for (int i = 0; i < 4; ++i) {
        const int r = bm + ty * 4 + i;
        if (r >= M) continue;
        float4 o = make_float4(acc[i][0], acc[i][1], acc[i][2], acc[i][3]);
        if (EPI == 1) {
            const float4 xo = *(const float4*)&Xold[(size_t)r * Ncols + cb];
            o.x = be * o.x + ombe * xo.x; o.y = be * o.y + ombe * xo.y;
            o.z = be * o.z + ombe * xo.z; o.w = be * o.w + ombe * xo.w;
        }
        if (EPI == 2) {
            o.x = fmaxf(o.x + bias[cb + 0], 0.f);
            o.y = fmaxf(o.y + bias[cb + 1], 0.f);
            o.z = fmaxf(o.z + bias[cb + 2], 0.f);
            o.w = fmaxf(o.w + bias[cb + 3], 0.f);
        }
        *(float4*)&Cout[(size_t)r * Ncols + cb] = o;
    }
}

// ---------------------------------------------------------------------------
// Fold per-head relation transform into projection weight:
// Wout[c, h*64+f] = sum_d Wbase[c, h*64+d] * T[h, d, f]
// ---------------------------------------------------------------------------
__global__ __launch_bounds__(256) void fold_k(const float* __restrict__ Wbase,
                                              const float* __restrict__ T,
                                              float* __restrict__ Wout) {
    __shared__ float row[256];
    const int c = blockIdx.x, t = threadIdx.x;
    row[t] = Wbase[c * 256 + t];
    __syncthreads();
    const int h = t >> 6, f = t & 63;
    const float* Th = T + h * 64 * 64;
    float acc = 0.f;
#pragma unroll 8
    for (int d = 0; d < 64; ++d) acc += row[h * 64 + d] * Th[d * 64 + f];
    Wout[c * 256 + t] = acc;
}

// ---------------------------------------------------------------------------
// Edge scoring: one wave per edge. score[e,h] = mu[h]/8 * <q[dst,h,:], kA[src,h,:]>
// ---------------------------------------------------------------------------
__device__ __forceinline__ unsigned fmap(float f) {
    unsigned u = __float_as_uint(f);
    return (u & 0x80000000u) ? ~u : (u | 0x80000000u);
}
__device__ __forceinline__ float finvmap(unsigned m) {
    return (m & 0x80000000u) ? __uint_as_float(m & 0x7FFFFFFFu)
                             : __uint_as_float(~m);
}

__global__ __launch_bounds__(256) void score_k(
    const float* __restrict__ q, const float* __restrict__ kA,
    const int* __restrict__ src, const int* __restrict__ dst,
    const float* __restrict__ mu, float* __restrict__ sc,
    unsigned* __restrict__ mkey, int E) {
    const int e = (blockIdx.x * blockDim.x + threadIdx.x) >> 6;
    if (e >= E) return;
    const int lane = threadIdx.x & 63;
    const int s = src[e], d = dst[e];
    const float4 qv = *(const float4*)&q[(size_t)d * 256 + lane * 4];
    const float4 kv = *(const float4*)&kA[(size_t)s * 256 + lane * 4];
    float p = qv.x * kv.x + qv.y * kv.y + qv.z * kv.z + qv.w * kv.w;
    p += __shfl_xor(p, 1);
    p += __shfl_xor(p, 2);
    p += __shfl_xor(p, 4);
    p += __shfl_xor(p, 8);
    const int h = lane >> 4;
    if ((lane & 15) == 0) {
        const float val = p * mu[h] * 0.125f;
        sc[(size_t)e * 4 + h] = val;
        atomicMax(&mkey[(size_t)d * 4 + h], fmap(val));
    }
}

// exp(score - max) and denominator accumulation. one thread per (edge, head).
__global__ __launch_bounds__(256) void expden_k(
    float* __restrict__ sc, const int* __restrict__ dst,
    const unsigned* __restrict__ mkey, float* __restrict__ den, int EH) {
    const int i = blockIdx.x * blockDim.x + threadIdx.x;
    if (i >= EH) return;
    const int e = i >> 2, h = i & 3;
    const int d = dst[e];
    const float mv = finvmap(mkey[(size_t)d * 4 + h]);
    const float ex = expf(sc[i] - mv);
    sc[i] = ex;
    atomicAdd(&den[(size_t)d * 4 + h], ex);
}

// Weighted aggregation: one wave per edge, atomicAdd into agg[dst].
__global__ __launch_bounds__(256) void agg_k(
    const float* __restrict__ sc, const float* __restrict__ den,
    const float* __restrict__ vM, const int* __restrict__ src,
    const int* __restrict__ dst, float* __restrict__ agg, int E) {
    const int e = (blockIdx.x * blockDim.x + threadIdx.x) >> 6;
    if (e >= E) return;
    const int lane = threadIdx.x & 63;
    const int s = src[e], d = dst[e];
    const int h = lane >> 4;
    const float w = sc[(size_t)e * 4 + h] / (den[(size_t)d * 4 + h] + 1e-16f);
    const float4 v = *(const float4*)&vM[(size_t)s * 256 + lane * 4];
    float* dp = &agg[(size_t)d * 256 + lane * 4];
    atomicAdd(dp + 0, w * v.x);
    atomicAdd(dp + 1, w * v.y);
    atomicAdd(dp + 2, w * v.z);
    atomicAdd(dp + 3, w * v.w);
}

// ---------------------------------------------------------------------------
// Final tiny head GEMM: o[n, 0..7] = t[n,:] @ W2[128,8] + b2; slice into out.
// ---------------------------------------------------------------------------
__global__ __launch_bounds__(256) void head_k(
    const float* __restrict__ t, const float* __restrict__ W2,
    const float* __restrict__ b2, float* __restrict__ out, int M, int off,
    int dims) {
    __shared__ float Ws[128 * 8];
    __shared__ float bs[8];
    const int tid = threadIdx.x;
    for (int i = tid; i < 1024; i += 256) Ws[i] = W2[i];
    if (tid < 8) bs[tid] = b2[tid];
    __syncthreads();
    const int nl = tid >> 3, o = tid & 7;
    const int n = blockIdx.x * 32 + nl;
    if (n >= M) return;
    const float* tr = &t[(size_t)n * 128];
    float acc = bs[o];
#pragma unroll 8
    for (int d = 0; d < 128; ++d) acc += tr[d] * Ws[d * 8 + o];
    if (o < dims) out[(size_t)n * 24 + off + o] = acc;
}

// ---------------------------------------------------------------------------

extern "C" void kernel_launch(void* const* d_in, const int* in_sizes, int n_in,
                              void* d_out, int out_size, void* d_ws,
                              size_t ws_size, hipStream_t stream) {
    const float* xe_in = (const float*)d_in[0];
    const float* xs_in = (const float*)d_in[1];
    const int* ee_src = (const int*)d_in[2];
    const int* ee_dst = (const int*)d_in[3];
    const int* es_src = (const int*)d_in[4];
    const int* es_dst = (const int*)d_in[5];
    const int* se_src = (const int*)d_in[6];
    const int* se_dst = (const int*)d_in[7];
    const float* Wk = (const float*)d_in[8];
    const float* Wq = (const float*)d_in[9];
    const float* Wv = (const float*)d_in[10];
    const float* Wa = (const float*)d_in[11];
    const float* skip = (const float*)d_in[12];
    const float* Arel = (const float*)d_in[13];
    const float* Mrel = (const float*)d_in[14];
    const float* mu = (const float*)d_in[15];
    const float* Wsh = (const float*)d_in[16];
    const float* bsh = (const float*)d_in[17];
    const float* Wt1 = (const float*)d_in[18];
    const float* bt1 = (const float*)d_in[19];
    const float* Wt2 = (const float*)d_in[20];
    const float* bt2 = (const float*)d_in[21];
    float* out = (float*)d_out;

    const int N = in_sizes[0] / CDIM;  // 50000
    const int E = in_sizes[2];         // 200000
    const size_t NC = (size_t)N * CDIM;
    const size_t CC = (size_t)CDIM * CDIM;
    const size_t HDD = (size_t)HDIM * DDIM * DDIM;
    const size_t E4 = (size_t)E * 4;
    const size_t N4 = (size_t)N * 4;

    // Workspace: 4 NxC buffers + edge scores + stats + folded weight = ~218MB
    const size_t need =
        (4 * NC + 3 * E4 + 4 * N4 + CDIM * CDIM) * sizeof(float);
    if (ws_size < need) return;  // diagnostic: fail accuracy, not crash

    float* ws = (float*)d_ws;
    float* xeA = ws;        // persistent updated expr features
    float* xsA = xeA + NC;  // persistent updated stmt features
    float* B1 = xsA + NC;   // kA / vM scratch
    float* B2 = B1 + NC;    // q / agg scratch
    float* s0 = B2 + NC;
    float* s1 = s0 + E4;
    float* s2 = s1 + E4;
    unsigned* mkey_e = (unsigned*)(s2 + E4);
    unsigned* mkey_s = mkey_e + N4;
    float* den_e = (float*)(mkey_s + N4);
    float* den_s = den_e + N4;
    float* wf = den_s + N4;  // 65536 floats folded weight

    const dim3 gemm_grid((N + 63) / 64, 4);
    const dim3 gemm_grid128((N + 63) / 64, 2);
    const int edge_blocks = (E * 64 + 255) / 256;
    const int eh_blocks = (E * 4 + 255) / 256;

    const float* cur_xe = xe_in;
    const float* cur_xs = xs_in;

    for (int l = 0; l < 3; ++l) {
        // zero softmax stats (mkey_e..den_s contiguous: 4*N4 words)
        zero_k<<<1024, 256, 0, stream>>>((float*)mkey_e, 4 * N4);

        // ---- scoring phase (all projections read pre-update features) ----
        // q_e -> B2; rel0 (expr->expr) and rel2 (stmt->expr) use it
        gemm_k<0, false><<<gemm_grid, 256, 0, stream>>>(
            cur_xe, Wq + (l * 2 + 0) * CC, B2, N, 256, nullptr, nullptr, nullptr);
        // rel0: kA from xe
        fold_k<<<256, 256, 0, stream>>>(Wk + (l * 2 + 0) * CC,
                                        Arel + (l * 3 + 0) * HDD, wf);
        gemm_k<0, false><<<gemm_grid, 256, 0, stream>>>(
            cur_xe, wf, B1, N, 256, nullptr, nullptr, nullptr);
        score_k<<<edge_blocks, 256, 0, stream>>>(
            B2, B1, ee_src, ee_dst, mu + (l * 3 + 0) * 4, s0, mkey_e, E);
        // rel2: kA from xs
        fold_k<<<256, 256, 0, stream>>>(Wk + (l * 2 + 1) * CC,
                                        Arel + (l * 3 + 2) * HDD, wf);
        gemm_k<0, false><<<gemm_grid, 256, 0, stream>>>(
            cur_xs, wf, B1, N, 256, nullptr, nullptr, nullptr);
        score_k<<<edge_blocks, 256, 0, stream>>>(
            B2, B1, se_src, se_dst, mu + (l * 3 + 2) * 4, s2, mkey_e, E);
        // q_s -> B2; rel1 (expr->stmt)
        gemm_k<0, false><<<gemm_grid, 256, 0, stream>>>(
            cur_xs, Wq + (l * 2 + 1) * CC, B2, N, 256, nullptr, nullptr, nullptr);
        fold_k<<<256, 256, 0, stream>>>(Wk + (l * 2 + 0) * CC,
                                        Arel + (l * 3 + 1) * HDD, wf);
        gemm_k<0, false><<<gemm_grid, 256, 0, stream>>>(
            cur_xe, wf, B1, N, 256, nullptr, nullptr, nullptr);
        score_k<<<edge_blocks, 256, 0, stream>>>(
            B2, B1, es_src, es_dst, mu + (l * 3 + 1) * 4, s1, mkey_s, E);

        // ---- softmax stats ----
        expden_k<<<eh_blocks, 256, 0, stream>>>(s0, ee_dst, mkey_e, den_e, E * 4);
        expden_k<<<eh_blocks, 256, 0, stream>>>(s1, es_dst, mkey_s, den_s, E * 4);
        expden_k<<<eh_blocks, 256, 0, stream>>>(s2, se_dst, mkey_e, den_e, E * 4);

        // ---- aggregation + update ----
        // rel1: vM from xe -> agg_s in B2 -> update xs (after vM2 captured)
        fold_k<<<256, 256, 0, stream>>>(Wv + (l * 2 + 0) * CC,
                                        Mrel + (l * 3 + 1) * HDD, wf);
        gemm_k<0, false><<<gemm_grid, 256, 0, stream>>>(
            cur_xe, wf, B1, N, 256, nullptr, nullptr, nullptr);
        zero_k<<<2048, 256, 0, stream>>>(B2, NC);
        agg_k<<<edge_blocks, 256, 0, stream>>>(s1, den_s, B1, es_src, es_dst,
                                               B2, E);
        // rel2 vM from OLD xs, captured into B1 before xs update
        fold_k<<<256, 256, 0, stream>>>(Wv + (l * 2 + 1) * CC,
                                        Mrel + (l * 3 + 2) * HDD, wf);
        gemm_k<0, false><<<gemm_grid, 256, 0, stream>>>(
            cur_xs, wf, B1, N, 256, nullptr, nullptr, nullptr);
        // xs update (in place for l>=1; layer 0 reads const input)
        gemm_k<1, true><<<gemm_grid, 256, 0, stream>>>(
            B2, Wa + (l * 2 + 1) * CC, xsA, N, 256, nullptr,
            skip + l * 2 + 1, cur_xs);
        cur_xs = xsA;
        // rel2 aggregation into fresh agg_e (B2)
        zero_k<<<2048, 256, 0, stream>>>(B2, NC);
        agg_k<<<edge_blocks, 256, 0, stream>>>(s2, den_e, B1, se_src, se_dst,
                                               B2, E);
        // rel0: vM from xe (still pre-update)
        fold_k<<<256, 256, 0, stream>>>(Wv + (l * 2 + 0) * CC,
                                        Mrel + (l * 3 + 0) * HDD, wf);
        gemm_k<0, false><<<gemm_grid, 256, 0, stream>>>(
            cur_xe, wf, B1, N, 256, nullptr, nullptr, nullptr);
        agg_k<<<edge_blocks, 256, 0, stream>>>(s0, den_e, B1, ee_src, ee_dst,
                                               B2, E);
        // xe update (last, so all xe-sourced projections saw old xe)
        gemm_k<1, true><<<gemm_grid, 256, 0, stream>>>(
            B2, Wa + (l * 2 + 0) * CC, xeA, N, 256, nullptr,
            skip + l * 2 + 0, cur_xe);
        cur_xe = xeA;
    }

    // shared linear stack (relu(x@W+b)) x2 on expr nodes
    gemm_k<2, false><<<gemm_grid, 256, 0, stream>>>(
        cur_xe, Wsh, B2, N, 256, bsh, nullptr, nullptr);
    gemm_k<2, false><<<gemm_grid, 256, 0, stream>>>(
        B2, Wsh + CC, B1, N, 256, bsh + 256, nullptr, nullptr);

    // 7 task heads
    const int OFF[7] = {0, 3, 6, 9, 14, 15, 16};
    const int DIMS[7] = {3, 3, 3, 5, 1, 1, 8};
    const int head_blocks = (N + 31) / 32;
    for (int k = 0; k < 7; ++k) {
        gemm_k<2, false><<<gemm_grid128, 256, 0, stream>>>(
            B1, Wt1 + (size_t)k * 256 * 128, B2, N, 128, bt1 + k * 128,
            nullptr, nullptr);
        head_k<<<head_blocks, 256, 0, stream>>>(
            B2, Wt2 + (size_t)k * 128 * 8, bt2 + k * 8, out, N, OFF[k], DIMS[k]);
    }
}

// Round 4
// 5090.136 us; speedup vs baseline: 2.0284x; 2.0284x over previous
//
#include <hip/hip_runtime.h>
#include <cmath>

// ---------------------------------------------------------------------------
// DragonHGT: 3-layer HGT + MLP stack + 7 task heads. fp32, ~221MB workspace.
// N=50000 nodes x 2 types, E=200000 edges x 3 relations, C=256 (H=4,D=64).
// R4: CSR-gather aggregation (built once, graph static across layers)
// replaces atomicAdd scatter (was 800MB HBM write traffic per dispatch).
// ---------------------------------------------------------------------------

#define CDIM 256
#define HDIM 4
#define DDIM 64

__device__ __forceinline__ float gelu_f(float x) {
    return 0.5f * x * (1.0f + erff(x * 0.70710678118654752f));
}

__global__ __launch_bounds__(256) void zero_k(float* __restrict__ p, size_t n) {
    size_t i = (size_t)blockIdx.x * blockDim.x + threadIdx.x;
    const size_t stride = (size_t)gridDim.x * blockDim.x;
    for (; i < n; i += stride) p[i] = 0.0f;
}

// ---------------------------------------------------------------------------
// Tiled fp32 GEMM: C[M,Ncols] = op(A[M,256]) @ B[256,Ncols]  (+ epilogue)
// EPI: 0 plain; 1 skip blend (in-place safe); 2 bias+relu. PREGELU on A.
// ---------------------------------------------------------------------------
template <int EPI, bool PREGELU>
__global__ __launch_bounds__(256) void gemm_k(
    const float* __restrict__ A, const float* __restrict__ B,
    float* __restrict__ Cout, int M, int Ncols,
    const float* __restrict__ bias, const float* __restrict__ skipv,
    const float* __restrict__ Xold) {
    __shared__ float As[16][68];  // [k][m]
    __shared__ float Bs[16][68];  // [k][n]
    const int tid = threadIdx.x;
    const int tx = tid & 15, ty = tid >> 4;
    const int bm = blockIdx.x * 64, bn = blockIdx.y * 64;
    const int K = 256;

    float acc[4][4] = {};
    const int ar = tid >> 2, ac4 = (tid & 3) * 4;   // A tile: 64 rows x 16 k
    const int br = tid >> 4, bc4 = (tid & 15) * 4;  // B tile: 16 k x 64 cols

    for (int k0 = 0; k0 < K; k0 += 16) {
        float4 av = make_float4(0.f, 0.f, 0.f, 0.f);
        const int arow = bm + ar;
        if (arow < M) av = *(const float4*)&A[(size_t)arow * K + k0 + ac4];
        if (PREGELU) {
            av.x = gelu_f(av.x); av.y = gelu_f(av.y);
            av.z = gelu_f(av.z); av.w = gelu_f(av.w);
        }
        const float4 bv = *(const float4*)&B[(size_t)(k0 + br) * Ncols + bn + bc4];
        __syncthreads();
        As[ac4 + 0][ar] = av.x; As[ac4 + 1][ar] = av.y;
        As[ac4 + 2][ar] = av.z; As[ac4 + 3][ar] = av.w;
        *(float4*)&Bs[br][bc4] = bv;
        __syncthreads();
#pragma unroll
        for (int k = 0; k < 16; ++k) {
            const float4 a = *(const float4*)&As[k][ty * 4];
            const float4 b = *(const float4*)&Bs[k][tx * 4];
            const float aa[4] = {a.x, a.y, a.z, a.w};
            const float bb[4] = {b.x, b.y, b.z, b.w};
#pragma unroll
            for (int i = 0; i < 4; ++i)
#pragma unroll
                for (int j = 0; j < 4; ++j) acc[i][j] += aa[i] * bb[j];
        }
    }

    float be = 0.f, ombe = 0.f;
    if (EPI == 1) {
        const float s = skipv[0];
        be = 1.0f / (1.0f + expf(-s));
        ombe = 1.0f - be;
    }
    const int cb = bn + tx * 4;
#pragma unroll
    for (int i = 0; i < 4; ++i) {
        const int r = bm + ty * 4 + i;
        if (r >= M) continue;
        float4 o = make_float4(acc[i][0], acc[i][1], acc[i][2], acc[i][3]);
        if (EPI == 1) {
            const float4 xo = *(const float4*)&Xold[(size_t)r * Ncols + cb];
            o.x = be * o.x + ombe * xo.x; o.y = be * o.y + ombe * xo.y;
            o.z = be * o.z + ombe * xo.z; o.w = be * o.w + ombe * xo.w;
        }
        if (EPI == 2) {
            o.x = fmaxf(o.x + bias[cb + 0], 0.f);
            o.y = fmaxf(o.y + bias[cb + 1], 0.f);
            o.z = fmaxf(o.z + bias[cb + 2], 0.f);
            o.w = fmaxf(o.w + bias[cb + 3], 0.f);
        }
        *(float4*)&Cout[(size_t)r * Ncols + cb] = o;
    }
}

// ---------------------------------------------------------------------------
// Fold per-head relation transform into projection weight.
// ---------------------------------------------------------------------------
__global__ __launch_bounds__(256) void fold_k(const float* __restrict__ Wbase,
                                              const float* __restrict__ T,
                                              float* __restrict__ Wout) {
    __shared__ float row[256];
    const int c = blockIdx.x, t = threadIdx.x;
    row[t] = Wbase[c * 256 + t];
    __syncthreads();
    const int h = t >> 6, f = t & 63;
    const float* Th = T + h * 64 * 64;
    float acc = 0.f;
#pragma unroll 8
    for (int d = 0; d < 64; ++d) acc += row[h * 64 + d] * Th[d * 64 + f];
    Wout[c * 256 + t] = acc;
}

// ---------------------------------------------------------------------------
// Edge scoring + atomic softmax stats (unchanged from R3 — cheap).
// ---------------------------------------------------------------------------
__device__ __forceinline__ unsigned fmap(float f) {
    unsigned u = __float_as_uint(f);
    return (u & 0x80000000u) ? ~u : (u | 0x80000000u);
}
__device__ __forceinline__ float finvmap(unsigned m) {
    return (m & 0x80000000u) ? __uint_as_float(m & 0x7FFFFFFFu)
                             : __uint_as_float(~m);
}

__global__ __launch_bounds__(256) void score_k(
    const float* __restrict__ q, const float* __restrict__ kA,
    const int* __restrict__ src, const int* __restrict__ dst,
    const float* __restrict__ mu, float* __restrict__ sc,
    unsigned* __restrict__ mkey, int E) {
    const int e = (blockIdx.x * blockDim.x + threadIdx.x) >> 6;
    if (e >= E) return;
    const int lane = threadIdx.x & 63;
    const int s = src[e], d = dst[e];
    const float4 qv = *(const float4*)&q[(size_t)d * 256 + lane * 4];
    const float4 kv = *(const float4*)&kA[(size_t)s * 256 + lane * 4];
    float p = qv.x * kv.x + qv.y * kv.y + qv.z * kv.z + qv.w * kv.w;
    p += __shfl_xor(p, 1);
    p += __shfl_xor(p, 2);
    p += __shfl_xor(p, 4);
    p += __shfl_xor(p, 8);
    const int h = lane >> 4;
    if ((lane & 15) == 0) {
        const float val = p * mu[h] * 0.125f;
        sc[(size_t)e * 4 + h] = val;
        atomicMax(&mkey[(size_t)d * 4 + h], fmap(val));
    }
}

__global__ __launch_bounds__(256) void expden_k(
    float* __restrict__ sc, const int* __restrict__ dst,
    const unsigned* __restrict__ mkey, float* __restrict__ den, int EH) {
    const int i = blockIdx.x * blockDim.x + threadIdx.x;
    if (i >= EH) return;
    const int e = i >> 2, h = i & 3;
    const int d = dst[e];
    const float mv = finvmap(mkey[(size_t)d * 4 + h]);
    const float ex = expf(sc[i] - mv);
    sc[i] = ex;
    atomicAdd(&den[(size_t)d * 4 + h], ex);
}

// ---------------------------------------------------------------------------
// CSR build (once per launch; graph static across layers).
// ---------------------------------------------------------------------------
__global__ __launch_bounds__(256) void hist_k(const int* __restrict__ dst,
                                              int* __restrict__ cnt, int E) {
    const int i = blockIdx.x * blockDim.x + threadIdx.x;
    if (i < E) atomicAdd(&cnt[dst[i]], 1);
}

// single-block exclusive scan: rp[0..n] from cnt[0..n-1]
__global__ __launch_bounds__(256) void scan_k(const int* __restrict__ cnt,
                                              int* __restrict__ rp, int n) {
    __shared__ int sums[256];
    const int tid = threadIdx.x;
    const int chunk = (n + 255) / 256;
    const int lo = min(tid * chunk, n), hi = min(lo + chunk, n);
    int s = 0;
    for (int i = lo; i < hi; ++i) s += cnt[i];
    sums[tid] = s;
    __syncthreads();
    for (int off = 1; off < 256; off <<= 1) {
        const int v = (tid >= off) ? sums[tid - off] : 0;
        __syncthreads();
        sums[tid] += v;
        __syncthreads();
    }
    int run = (tid == 0) ? 0 : sums[tid - 1];
    for (int i = lo; i < hi; ++i) {
        rp[i] = run;
        run += cnt[i];
    }
    if (tid == 255) rp[n] = run;
}

__global__ __launch_bounds__(256) void scatter_k(const int* __restrict__ dst,
                                                 const int* __restrict__ rp,
                                                 int* __restrict__ fill,
                                                 int* __restrict__ col, int E) {
    const int e = blockIdx.x * blockDim.x + threadIdx.x;
    if (e < E) {
        const int d = dst[e];
        const int p = rp[d] + atomicAdd(&fill[d], 1);
        col[p] = e;
    }
}

// ---------------------------------------------------------------------------
// CSR aggregation: one wave per destination node, registers hold the row.
// MODE 0: write (also writes zeros for isolated nodes); MODE 1: accumulate.
// ---------------------------------------------------------------------------
template <int MODE>
__global__ __launch_bounds__(256) void agg_csr_k(
    const float* __restrict__ sc, const float* __restrict__ den,
    const float* __restrict__ vM, const int* __restrict__ srcarr,
    const int* __restrict__ rp, const int* __restrict__ col,
    float* __restrict__ aggout, int Nn) {
    const int wid = (blockIdx.x * blockDim.x + threadIdx.x) >> 6;
    if (wid >= Nn) return;
    const int lane = threadIdx.x & 63;
    const int h = lane >> 4;
    const int beg = rp[wid], end = rp[wid + 1];
    const float dinv = 1.0f / (den[(size_t)wid * 4 + h] + 1e-16f);
    float4 acc = make_float4(0.f, 0.f, 0.f, 0.f);
    for (int i = beg; i < end; ++i) {
        const int e = col[i];
        const int s = srcarr[e];
        const float w = sc[(size_t)e * 4 + h] * dinv;
        const float4 v = *(const float4*)&vM[(size_t)s * 256 + lane * 4];
        acc.x += w * v.x; acc.y += w * v.y;
        acc.z += w * v.z; acc.w += w * v.w;
    }
    float* dp = &aggout[(size_t)wid * 256 + lane * 4];
    if (MODE == 1) {
        const float4 old = *(const float4*)dp;
        acc.x += old.x; acc.y += old.y; acc.z += old.z; acc.w += old.w;
    }
    *(float4*)dp = acc;
}

// Fallback: atomic scatter aggregation (R3 path, used only if ws too small).
__global__ __launch_bounds__(256) void agg_k(
    const float* __restrict__ sc, const float* __restrict__ den,
    const float* __restrict__ vM, const int* __restrict__ src,
    const int* __restrict__ dst, float* __restrict__ agg, int E) {
    const int e = (blockIdx.x * blockDim.x + threadIdx.x) >> 6;
    if (e >= E) return;
    const int lane = threadIdx.x & 63;
    const int s = src[e], d = dst[e];
    const int h = lane >> 4;
    const float w = sc[(size_t)e * 4 + h] / (den[(size_t)d * 4 + h] + 1e-16f);
    const float4 v = *(const float4*)&vM[(size_t)s * 256 + lane * 4];
    float* dp = &agg[(size_t)d * 256 + lane * 4];
    atomicAdd(dp + 0, w * v.x);
    atomicAdd(dp + 1, w * v.y);
    atomicAdd(dp + 2, w * v.z);
    atomicAdd(dp + 3, w * v.w);
}

// ---------------------------------------------------------------------------
// Final tiny head GEMM.
// ---------------------------------------------------------------------------
__global__ __launch_bounds__(256) void head_k(
    const float* __restrict__ t, const float* __restrict__ W2,
    const float* __restrict__ b2, float* __restrict__ out, int M, int off,
    int dims) {
    __shared__ float Ws[128 * 8];
    __shared__ float bs[8];
    const int tid = threadIdx.x;
    for (int i = tid; i < 1024; i += 256) Ws[i] = W2[i];
    if (tid < 8) bs[tid] = b2[tid];
    __syncthreads();
    const int nl = tid >> 3, o = tid & 7;
    const int n = blockIdx.x * 32 + nl;
    if (n >= M) return;
    const float* tr = &t[(size_t)n * 128];
    float acc = bs[o];
#pragma unroll 8
    for (int d = 0; d < 128; ++d) acc += tr[d] * Ws[d * 8 + o];
    if (o < dims) out[(size_t)n * 24 + off + o] = acc;
}

// ---------------------------------------------------------------------------

extern "C" void kernel_launch(void* const* d_in, const int* in_sizes, int n_in,
                              void* d_out, int out_size, void* d_ws,
                              size_t ws_size, hipStream_t stream) {
    const float* xe_in = (const float*)d_in[0];
    const float* xs_in = (const float*)d_in[1];
    const int* ee_src = (const int*)d_in[2];
    const int* ee_dst = (const int*)d_in[3];
    const int* es_src = (const int*)d_in[4];
    const int* es_dst = (const int*)d_in[5];
    const int* se_src = (const int*)d_in[6];
    const int* se_dst = (const int*)d_in[7];
    const float* Wk = (const float*)d_in[8];
    const float* Wq = (const float*)d_in[9];
    const float* Wv = (const float*)d_in[10];
    const float* Wa = (const float*)d_in[11];
    const float* skip = (const float*)d_in[12];
    const float* Arel = (const float*)d_in[13];
    const float* Mrel = (const float*)d_in[14];
    const float* mu = (const float*)d_in[15];
    const float* Wsh = (const float*)d_in[16];
    const float* bsh = (const float*)d_in[17];
    const float* Wt1 = (const float*)d_in[18];
    const float* bt1 = (const float*)d_in[19];
    const float* Wt2 = (const float*)d_in[20];
    const float* bt2 = (const float*)d_in[21];
    float* out = (float*)d_out;

    const int N = in_sizes[0] / CDIM;  // 50000
    const int E = in_sizes[2];         // 200000
    const size_t NC = (size_t)N * CDIM;
    const size_t CC = (size_t)CDIM * CDIM;
    const size_t HDD = (size_t)HDIM * DDIM * DDIM;
    const size_t E4 = (size_t)E * 4;
    const size_t N4 = (size_t)N * 4;

    const size_t base_floats = 4 * NC + 3 * E4 + 4 * N4 + CDIM * CDIM;
    const size_t csr_ints = 3 * (size_t)(N + 1) + 3 * (size_t)E + N;
    const size_t need_base = base_floats * sizeof(float);
    const size_t need_csr = need_base + csr_ints * sizeof(int);
    if (ws_size < need_base) return;  // diagnostic: fail accuracy, not crash
    const bool use_csr = (ws_size >= need_csr);

    float* ws = (float*)d_ws;
    float* xeA = ws;        // persistent updated expr features
    float* xsA = xeA + NC;  // persistent updated stmt features
    float* B1 = xsA + NC;   // kA / vM scratch
    float* B2 = B1 + NC;    // q / agg scratch
    float* s0 = B2 + NC;
    float* s1 = s0 + E4;
    float* s2 = s1 + E4;
    unsigned* mkey_e = (unsigned*)(s2 + E4);
    unsigned* mkey_s = mkey_e + N4;
    float* den_e = (float*)(mkey_s + N4);
    float* den_s = den_e + N4;
    float* wf = den_s + N4;  // 65536 floats folded weight
    // CSR region (only touched when use_csr)
    int* rp0 = (int*)(wf + CDIM * CDIM);
    int* rp1 = rp0 + (N + 1);
    int* rp2 = rp1 + (N + 1);
    int* col0 = rp2 + (N + 1);
    int* col1 = col0 + E;
    int* col2 = col1 + E;
    int* cnt = col2 + E;  // N ints, reused as hist then fill

    const dim3 gemm_grid((N + 63) / 64, 4);
    const dim3 gemm_grid128((N + 63) / 64, 2);
    const int edge_blocks = (E * 64 + 255) / 256;
    const int eh_blocks = (E * 4 + 255) / 256;
    const int e_blocks = (E + 255) / 256;
    const int n_blocks = (N + 255) / 256;
    const int wave_blocks = (N + 3) / 4;  // one wave per dst node

    // ---- build CSR once (graph identical across layers) ----
    if (use_csr) {
        const int* dsts[3] = {ee_dst, es_dst, se_dst};
        int* rps[3] = {rp0, rp1, rp2};
        int* cols[3] = {col0, col1, col2};
        for (int r = 0; r < 3; ++r) {
            zero_k<<<n_blocks, 256, 0, stream>>>((float*)cnt, N);
            hist_k<<<e_blocks, 256, 0, stream>>>(dsts[r], cnt, E);
            scan_k<<<1, 256, 0, stream>>>(cnt, rps[r], N);
            zero_k<<<n_blocks, 256, 0, stream>>>((float*)cnt, N);
            scatter_k<<<e_blocks, 256, 0, stream>>>(dsts[r], rps[r], cnt,
                                                    cols[r], E);
        }
    }

    const float* cur_xe = xe_in;
    const float* cur_xs = xs_in;

    for (int l = 0; l < 3; ++l) {
        // zero softmax stats (mkey_e..den_s contiguous: 4*N4 words)
        zero_k<<<1024, 256, 0, stream>>>((float*)mkey_e, 4 * N4);

        // ---- scoring phase (all projections read pre-update features) ----
        gemm_k<0, false><<<gemm_grid, 256, 0, stream>>>(
            cur_xe, Wq + (l * 2 + 0) * CC, B2, N, 256, nullptr, nullptr, nullptr);
        fold_k<<<256, 256, 0, stream>>>(Wk + (l * 2 + 0) * CC,
                                        Arel + (l * 3 + 0) * HDD, wf);
        gemm_k<0, false><<<gemm_grid, 256, 0, stream>>>(
            cur_xe, wf, B1, N, 256, nullptr, nullptr, nullptr);
        score_k<<<edge_blocks, 256, 0, stream>>>(
            B2, B1, ee_src, ee_dst, mu + (l * 3 + 0) * 4, s0, mkey_e, E);
        fold_k<<<256, 256, 0, stream>>>(Wk + (l * 2 + 1) * CC,
                                        Arel + (l * 3 + 2) * HDD, wf);
        gemm_k<0, false><<<gemm_grid, 256, 0, stream>>>(
            cur_xs, wf, B1, N, 256, nullptr, nullptr, nullptr);
        score_k<<<edge_blocks, 256, 0, stream>>>(
            B2, B1, se_src, se_dst, mu + (l * 3 + 2) * 4, s2, mkey_e, E);
        gemm_k<0, false><<<gemm_grid, 256, 0, stream>>>(
            cur_xs, Wq + (l * 2 + 1) * CC, B2, N, 256, nullptr, nullptr, nullptr);
        fold_k<<<256, 256, 0, stream>>>(Wk + (l * 2 + 0) * CC,
                                        Arel + (l * 3 + 1) * HDD, wf);
        gemm_k<0, false><<<gemm_grid, 256, 0, stream>>>(
            cur_xe, wf, B1, N, 256, nullptr, nullptr, nullptr);
        score_k<<<edge_blocks, 256, 0, stream>>>(
            B2, B1, es_src, es_dst, mu + (l * 3 + 1) * 4, s1, mkey_s, E);

        // ---- softmax stats ----
        expden_k<<<eh_blocks, 256, 0, stream>>>(s0, ee_dst, mkey_e, den_e, E * 4);
        expden_k<<<eh_blocks, 256, 0, stream>>>(s1, es_dst, mkey_s, den_s, E * 4);
        expden_k<<<eh_blocks, 256, 0, stream>>>(s2, se_dst, mkey_e, den_e, E * 4);

        // ---- aggregation + update ----
        // rel1: vM from xe -> agg_s (B2)
        fold_k<<<256, 256, 0, stream>>>(Wv + (l * 2 + 0) * CC,
                                        Mrel + (l * 3 + 1) * HDD, wf);
        gemm_k<0, false><<<gemm_grid, 256, 0, stream>>>(
            cur_xe, wf, B1, N, 256, nullptr, nullptr, nullptr);
        if (use_csr) {
            agg_csr_k<0><<<wave_blocks, 256, 0, stream>>>(
                s1, den_s, B1, es_src, rp1, col1, B2, N);
        } else {
            zero_k<<<2048, 256, 0, stream>>>(B2, NC);
            agg_k<<<edge_blocks, 256, 0, stream>>>(s1, den_s, B1, es_src,
                                                   es_dst, B2, E);
        }
        // rel2 vM from OLD xs, captured into B1 before xs update
        fold_k<<<256, 256, 0, stream>>>(Wv + (l * 2 + 1) * CC,
                                        Mrel + (l * 3 + 2) * HDD, wf);
        gemm_k<0, false><<<gemm_grid, 256, 0, stream>>>(
            cur_xs, wf, B1, N, 256, nullptr, nullptr, nullptr);
        // xs update (in place for l>=1; layer 0 reads const input)
        gemm_k<1, true><<<gemm_grid, 256, 0, stream>>>(
            B2, Wa + (l * 2 + 1) * CC, xsA, N, 256, nullptr,
            skip + l * 2 + 1, cur_xs);
        cur_xs = xsA;
        // agg_e: rel2 (write) then rel0 (accumulate)
        if (use_csr) {
            agg_csr_k<0><<<wave_blocks, 256, 0, stream>>>(
                s2, den_e, B1, se_src, rp2, col2, B2, N);
        } else {
            zero_k<<<2048, 256, 0, stream>>>(B2, NC);
            agg_k<<<edge_blocks, 256, 0, stream>>>(s2, den_e, B1, se_src,
                                                   se_dst, B2, E);
        }
        fold_k<<<256, 256, 0, stream>>>(Wv + (l * 2 + 0) * CC,
                                        Mrel + (l * 3 + 0) * HDD, wf);
        gemm_k<0, false><<<gemm_grid, 256, 0, stream>>>(
            cur_xe, wf, B1, N, 256, nullptr, nullptr, nullptr);
        if (use_csr) {
            agg_csr_k<1><<<wave_blocks, 256, 0, stream>>>(
                s0, den_e, B1, ee_src, rp0, col0, B2, N);
        } else {
            agg_k<<<edge_blocks, 256, 0, stream>>>(s0, den_e, B1, ee_src,
                                                   ee_dst, B2, E);
        }
        // xe update (last, so all xe-sourced projections saw old xe)
        gemm_k<1, true><<<gemm_grid, 256, 0, stream>>>(
            B2, Wa + (l * 2 + 0) * CC, xeA, N, 256, nullptr,
            skip + l * 2 + 0, cur_xe);
        cur_xe = xeA;
    }

    // shared linear stack (relu(x@W+b)) x2 on expr nodes
    gemm_k<2, false><<<gemm_grid, 256, 0, stream>>>(
        cur_xe, Wsh, B2, N, 256, bsh, nullptr, nullptr);
    gemm_k<2, false><<<gemm_grid, 256, 0, stream>>>(
        B2, Wsh + CC, B1, N, 256, bsh + 256, nullptr, nullptr);

    // 7 task heads
    const int OFF[7] = {0, 3, 6, 9, 14, 15, 16};
    const int DIMS[7] = {3, 3, 3, 5, 1, 1, 8};
    const int head_blocks = (N + 31) / 32;
    for (int k = 0; k < 7; ++k) {
        gemm_k<2, false><<<gemm_grid128, 256, 0, stream>>>(
            B1, Wt1 + (size_t)k * 256 * 128, B2, N, 128, bt1 + k * 128,
            nullptr, nullptr);
        head_k<<<head_blocks, 256, 0, stream>>>(
            B2, Wt2 + (size_t)k * 128 * 8, bt2 + k * 8, out, N, OFF[k], DIMS[k]);
    }
}

// Round 5
// 2446.996 us; speedup vs baseline: 4.2194x; 2.0802x over previous
//
#include <hip/hip_runtime.h>
#include <hip/hip_fp16.h>
#include <cmath>

// ---------------------------------------------------------------------------
// DragonHGT: 3-layer HGT + MLP stack + 7 task heads.
// R5: fp16 MFMA GEMMs (fp32 accumulate), CSR-gather aggregation.
// N=50000 nodes x 2 types, E=200000 edges x 3 relations, C=256 (H=4,D=64).
// Workspace ~221 MB (same budget as R4 which passed).
// ---------------------------------------------------------------------------

#define CDIM 256
#define HDIM 4
#define DDIM 64

using f16x8 = __attribute__((ext_vector_type(8))) _Float16;
using f16x4 = __attribute__((ext_vector_type(4))) _Float16;
using f32x4 = __attribute__((ext_vector_type(4))) float;

__device__ __forceinline__ float gelu_f(float x) {
    return 0.5f * x * (1.0f + erff(x * 0.70710678118654752f));
}

__global__ __launch_bounds__(256) void zero_k(float* __restrict__ p, size_t n) {
    size_t i = (size_t)blockIdx.x * blockDim.x + threadIdx.x;
    const size_t stride = (size_t)gridDim.x * blockDim.x;
    for (; i < n; i += stride) p[i] = 0.0f;
}

// fp32 -> fp16 convert, optional exact-GELU pre-op. n multiple of 4.
template <bool GELU>
__global__ __launch_bounds__(256) void cvt_k(const float* __restrict__ in,
                                             _Float16* __restrict__ out,
                                             size_t n4) {
    size_t i = (size_t)blockIdx.x * blockDim.x + threadIdx.x;
    const size_t stride = (size_t)gridDim.x * blockDim.x;
    for (; i < n4; i += stride) {
        const float4 v = ((const float4*)in)[i];
        f16x4 o;
        if (GELU) {
            o[0] = (_Float16)gelu_f(v.x); o[1] = (_Float16)gelu_f(v.y);
            o[2] = (_Float16)gelu_f(v.z); o[3] = (_Float16)gelu_f(v.w);
        } else {
            o[0] = (_Float16)v.x; o[1] = (_Float16)v.y;
            o[2] = (_Float16)v.z; o[3] = (_Float16)v.w;
        }
        ((f16x4*)out)[i] = o;
    }
}

// Transpose+convert plain weight W[256, Ncw] -> BtH[Ncw, 256] fp16.
// grid = Ncw blocks, 256 threads.
__global__ __launch_bounds__(256) void cvtT_k(const float* __restrict__ W,
                                              _Float16* __restrict__ BtH,
                                              int Ncw) {
    const int o = blockIdx.x, c = threadIdx.x;
    BtH[(size_t)o * 256 + c] = (_Float16)W[(size_t)c * Ncw + o];
}

// Fold per-head relation transform into projection weight; output transposed
// fp16: BtH[t, c] = sum_d Wbase[c, h*64+d] * T[h, d, f],  t = h*64+f.
__global__ __launch_bounds__(256) void foldT_k(const float* __restrict__ Wbase,
                                               const float* __restrict__ T,
                                               _Float16* __restrict__ BtH) {
    __shared__ float row[256];
    const int c = blockIdx.x, t = threadIdx.x;
    row[t] = Wbase[c * 256 + t];
    __syncthreads();
    const int h = t >> 6, f = t & 63;
    const float* Th = T + h * 64 * 64;
    float acc = 0.f;
#pragma unroll 8
    for (int d = 0; d < 64; ++d) acc += row[h * 64 + d] * Th[d * 64 + f];
    BtH[(size_t)t * 256 + c] = (_Float16)acc;
}

// ---------------------------------------------------------------------------
// fp16 MFMA GEMM: C[M,Nc] = A[M,256] @ Bt[Nc,256]^T, fp32 accumulate.
// 128x128 tile, 4 waves x (64x64), K-loop 8 x 32.
// EPI: 0 plain; 1 skip-blend (in-place safe); 2 bias+relu.
// OUTH: store fp16 (and read Xold fp16 for EPI1) else fp32.
// ---------------------------------------------------------------------------
template <int EPI, bool OUTH>
__global__ __launch_bounds__(256) void gemm_h(
    const _Float16* __restrict__ A, const _Float16* __restrict__ Bt,
    void* __restrict__ Cout, int M, int Nc,
    const float* __restrict__ bias, const float* __restrict__ skipv,
    const void* __restrict__ Xold) {
    __shared__ _Float16 As[128][40];  // pad to 40 halfs (80B row stride)
    __shared__ _Float16 Bs[128][40];
    const int tid = threadIdx.x;
    const int bm = blockIdx.x * 128, bn = blockIdx.y * 128;
    const int wave = tid >> 6, lane = tid & 63;
    const int wm = (wave >> 1) * 64, wn = (wave & 1) * 64;
    const int l15 = lane & 15, g = lane >> 4;
    const int srow = tid >> 2, soff = (tid & 3) * 8;  // 4 thr/row, 16B each

    f32x4 acc[4][4] = {};

    for (int k0 = 0; k0 < 256; k0 += 32) {
        __syncthreads();
#pragma unroll
        for (int p = 0; p < 2; ++p) {
            const int r = p * 64 + srow;
            int gr = bm + r; if (gr >= M) gr = M - 1;
            *(f16x8*)&As[r][soff] =
                *(const f16x8*)&A[(size_t)gr * 256 + k0 + soff];
            *(f16x8*)&Bs[r][soff] =
                *(const f16x8*)&Bt[(size_t)(bn + r) * 256 + k0 + soff];
        }
        __syncthreads();
        f16x8 af[4], bf[4];
#pragma unroll
        for (int i = 0; i < 4; ++i) {
            af[i] = *(const f16x8*)&As[wm + i * 16 + l15][g * 8];
            bf[i] = *(const f16x8*)&Bs[wn + i * 16 + l15][g * 8];
        }
#pragma unroll
        for (int mi = 0; mi < 4; ++mi)
#pragma unroll
            for (int ni = 0; ni < 4; ++ni)
                acc[mi][ni] = __builtin_amdgcn_mfma_f32_16x16x32_f16(
                    af[mi], bf[ni], acc[mi][ni], 0, 0, 0);
    }

    float be = 0.f, ombe = 0.f;
    if (EPI == 1) {
        const float s = skipv[0];
        be = 1.0f / (1.0f + expf(-s));
        ombe = 1.0f - be;
    }
#pragma unroll
    for (int mi = 0; mi < 4; ++mi) {
#pragma unroll
        for (int r = 0; r < 4; ++r) {
            const int row = bm + wm + mi * 16 + g * 4 + r;
            if (row >= M) continue;
#pragma unroll
            for (int ni = 0; ni < 4; ++ni) {
                const int col = bn + wn + ni * 16 + l15;
                float v = acc[mi][ni][r];
                if (EPI == 1) {
                    const float xo =
                        OUTH ? (float)((const _Float16*)Xold)[(size_t)row * Nc + col]
                             : ((const float*)Xold)[(size_t)row * Nc + col];
                    v = be * v + ombe * xo;
                }
                if (EPI == 2) v = fmaxf(v + bias[col], 0.f);
                if (OUTH)
                    ((_Float16*)Cout)[(size_t)row * Nc + col] = (_Float16)v;
                else
                    ((float*)Cout)[(size_t)row * Nc + col] = v;
            }
        }
    }
}

// ---------------------------------------------------------------------------
// Edge scoring (q, kA fp16) + atomic softmax stats.
// ---------------------------------------------------------------------------
__device__ __forceinline__ unsigned fmap(float f) {
    unsigned u = __float_as_uint(f);
    return (u & 0x80000000u) ? ~u : (u | 0x80000000u);
}
__device__ __forceinline__ float finvmap(unsigned m) {
    return (m & 0x80000000u) ? __uint_as_float(m & 0x7FFFFFFFu)
                             : __uint_as_float(~m);
}

__global__ __launch_bounds__(256) void score_k(
    const _Float16* __restrict__ q, const _Float16* __restrict__ kA,
    const int* __restrict__ src, const int* __restrict__ dst,
    const float* __restrict__ mu, float* __restrict__ sc,
    unsigned* __restrict__ mkey, int E) {
    const int e = (blockIdx.x * blockDim.x + threadIdx.x) >> 6;
    if (e >= E) return;
    const int lane = threadIdx.x & 63;
    const int s = src[e], d = dst[e];
    const f16x4 qv = *(const f16x4*)&q[(size_t)d * 256 + lane * 4];
    const f16x4 kv = *(const f16x4*)&kA[(size_t)s * 256 + lane * 4];
    float p = (float)qv[0] * (float)kv[0] + (float)qv[1] * (float)kv[1] +
              (float)qv[2] * (float)kv[2] + (float)qv[3] * (float)kv[3];
    p += __shfl_xor(p, 1);
    p += __shfl_xor(p, 2);
    p += __shfl_xor(p, 4);
    p += __shfl_xor(p, 8);
    const int h = lane >> 4;
    if ((lane & 15) == 0) {
        const float val = p * mu[h] * 0.125f;
        sc[(size_t)e * 4 + h] = val;
        atomicMax(&mkey[(size_t)d * 4 + h], fmap(val));
    }
}

__global__ __launch_bounds__(256) void expden_k(
    float* __restrict__ sc, const int* __restrict__ dst,
    const unsigned* __restrict__ mkey, float* __restrict__ den, int EH) {
    const int i = blockIdx.x * blockDim.x + threadIdx.x;
    if (i >= EH) return;
    const int e = i >> 2, h = i & 3;
    const int d = dst[e];
    const float mv = finvmap(mkey[(size_t)d * 4 + h]);
    const float ex = expf(sc[i] - mv);
    sc[i] = ex;
    atomicAdd(&den[(size_t)d * 4 + h], ex);
}

// ---------------------------------------------------------------------------
// CSR build (once; graph static across layers).
// ---------------------------------------------------------------------------
__global__ __launch_bounds__(256) void hist_k(const int* __restrict__ dst,
                                              int* __restrict__ cnt, int E) {
    const int i = blockIdx.x * blockDim.x + threadIdx.x;
    if (i < E) atomicAdd(&cnt[dst[i]], 1);
}

__global__ __launch_bounds__(256) void scan_k(const int* __restrict__ cnt,
                                              int* __restrict__ rp, int n) {
    __shared__ int sums[256];
    const int tid = threadIdx.x;
    const int chunk = (n + 255) / 256;
    const int lo = min(tid * chunk, n), hi = min(lo + chunk, n);
    int s = 0;
    for (int i = lo; i < hi; ++i) s += cnt[i];
    sums[tid] = s;
    __syncthreads();
    for (int off = 1; off < 256; off <<= 1) {
        const int v = (tid >= off) ? sums[tid - off] : 0;
        __syncthreads();
        sums[tid] += v;
        __syncthreads();
    }
    int run = (tid == 0) ? 0 : sums[tid - 1];
    for (int i = lo; i < hi; ++i) {
        rp[i] = run;
        run += cnt[i];
    }
    if (tid == 255) rp[n] = run;
}

__global__ __launch_bounds__(256) void scatter_k(const int* __restrict__ dst,
                                                 const int* __restrict__ rp,
                                                 int* __restrict__ fill,
                                                 int* __restrict__ col, int E) {
    const int e = blockIdx.x * blockDim.x + threadIdx.x;
    if (e < E) {
        const int d = dst[e];
        const int p = rp[d] + atomicAdd(&fill[d], 1);
        col[p] = e;
    }
}

// ---------------------------------------------------------------------------
// CSR aggregation: one wave per dst node; vM fp16; agg fp32.
// MODE 0: write; MODE 1: accumulate into existing.
// ---------------------------------------------------------------------------
template <int MODE>
__global__ __launch_bounds__(256) void agg_csr_k(
    const float* __restrict__ sc, const float* __restrict__ den,
    const _Float16* __restrict__ vM, const int* __restrict__ srcarr,
    const int* __restrict__ rp, const int* __restrict__ col,
    float* __restrict__ aggout, int Nn) {
    const int wid = (blockIdx.x * blockDim.x + threadIdx.x) >> 6;
    if (wid >= Nn) return;
    const int lane = threadIdx.x & 63;
    const int h = lane >> 4;
    const int beg = rp[wid], end = rp[wid + 1];
    const float dinv = 1.0f / (den[(size_t)wid * 4 + h] + 1e-16f);
    float4 acc = make_float4(0.f, 0.f, 0.f, 0.f);
    for (int i = beg; i < end; ++i) {
        const int e = col[i];
        const int s = srcarr[e];
        const float w = sc[(size_t)e * 4 + h] * dinv;
        const f16x4 v = *(const f16x4*)&vM[(size_t)s * 256 + lane * 4];
        acc.x += w * (float)v[0]; acc.y += w * (float)v[1];
        acc.z += w * (float)v[2]; acc.w += w * (float)v[3];
    }
    float* dp = &aggout[(size_t)wid * 256 + lane * 4];
    if (MODE == 1) {
        const float4 old = *(const float4*)dp;
        acc.x += old.x; acc.y += old.y; acc.z += old.z; acc.w += old.w;
    }
    *(float4*)dp = acc;
}

// ---------------------------------------------------------------------------
// Final tiny head GEMM: o[n,0..7] = t[n,:] @ W2[128,8] + b2; slice into out.
// ---------------------------------------------------------------------------
__global__ __launch_bounds__(256) void head_k(
    const _Float16* __restrict__ t, const float* __restrict__ W2,
    const float* __restrict__ b2, float* __restrict__ out, int M, int off,
    int dims) {
    __shared__ float Ws[128 * 8];
    __shared__ float bs[8];
    const int tid = threadIdx.x;
    for (int i = tid; i < 1024; i += 256) Ws[i] = W2[i];
    if (tid < 8) bs[tid] = b2[tid];
    __syncthreads();
    const int nl = tid >> 3, o = tid & 7;
    const int n = blockIdx.x * 32 + nl;
    if (n >= M) return;
    const _Float16* tr = &t[(size_t)n * 128];
    float acc = bs[o];
#pragma unroll 8
    for (int d = 0; d < 128; ++d) acc += (float)tr[d] * Ws[d * 8 + o];
    if (o < dims) out[(size_t)n * 24 + off + o] = acc;
}

// ---------------------------------------------------------------------------

extern "C" void kernel_launch(void* const* d_in, const int* in_sizes, int n_in,
                              void* d_out, int out_size, void* d_ws,
                              size_t ws_size, hipStream_t stream) {
    const float* xe_in = (const float*)d_in[0];
    const float* xs_in = (const float*)d_in[1];
    const int* ee_src = (const int*)d_in[2];
    const int* ee_dst = (const int*)d_in[3];
    const int* es_src = (const int*)d_in[4];
    const int* es_dst = (const int*)d_in[5];
    const int* se_src = (const int*)d_in[6];
    const int* se_dst = (const int*)d_in[7];
    const float* Wk = (const float*)d_in[8];
    const float* Wq = (const float*)d_in[9];
    const float* Wv = (const float*)d_in[10];
    const float* Wa = (const float*)d_in[11];
    const float* skip = (const float*)d_in[12];
    const float* Arel = (const float*)d_in[13];
    const float* Mrel = (const float*)d_in[14];
    const float* mu = (const float*)d_in[15];
    const float* Wsh = (const float*)d_in[16];
    const float* bsh = (const float*)d_in[17];
    const float* Wt1 = (const float*)d_in[18];
    const float* bt1 = (const float*)d_in[19];
    const float* Wt2 = (const float*)d_in[20];
    const float* bt2 = (const float*)d_in[21];
    float* out = (float*)d_out;

    const int N = in_sizes[0] / CDIM;  // 50000
    const int E = in_sizes[2];         // 200000
    const size_t NC = (size_t)N * CDIM;
    const size_t CC = (size_t)CDIM * CDIM;
    const size_t HDD = (size_t)HDIM * DDIM * DDIM;
    const size_t E4 = (size_t)E * 4;
    const size_t N4 = (size_t)N * 4;

    // floats: xeA + aggB + 4 half-buffers (NC/2 floats each) + scores + stats + BtH
    const size_t wfloats =
        2 * NC + 4 * (NC / 2) + 3 * E4 + 4 * N4 + (CC / 2);
    const size_t csr_ints = 3 * (size_t)(N + 1) + 3 * (size_t)E + N;
    const size_t need = wfloats * sizeof(float) + csr_ints * sizeof(int);
    if (ws_size < need) return;  // diagnostic: fail accuracy, not crash

    float* ws = (float*)d_ws;
    float* xeA = ws;         // fp32 expr state
    float* aggB = xeA + NC;  // fp32 aggregation buffer
    _Float16* xeH = (_Float16*)(aggB + NC);  // fp16 expr activations
    _Float16* xsH = xeH + NC;                // fp16 stmt state
    _Float16* P1h = xsH + NC;                // kA / vM outputs
    _Float16* P2h = P1h + NC;                // q / gelu-agg / mlp outputs
    float* s0 = (float*)(P2h + NC);
    float* s1 = s0 + E4;
    float* s2 = s1 + E4;
    unsigned* mkey_e = (unsigned*)(s2 + E4);
    unsigned* mkey_s = mkey_e + N4;
    float* den_e = (float*)(mkey_s + N4);
    float* den_s = den_e + N4;
    _Float16* BtH = (_Float16*)(den_s + N4);  // 256x256 fp16 weight
    int* rp0 = (int*)(BtH + CC);
    int* rp1 = rp0 + (N + 1);
    int* rp2 = rp1 + (N + 1);
    int* col0 = rp2 + (N + 1);
    int* col1 = col0 + E;
    int* col2 = col1 + E;
    int* cnt = col2 + E;

    const dim3 gh_grid((N + 127) / 128, 2);   // Nc=256
    const dim3 gh_grid1((N + 127) / 128, 1);  // Nc=128
    const int edge_blocks = (E * 64 + 255) / 256;
    const int eh_blocks = (E * 4 + 255) / 256;
    const int e_blocks = (E + 255) / 256;
    const int n_blocks = (N + 255) / 256;
    const int wave_blocks = (N + 3) / 4;
    const int cvt_blocks = 1024;

    // ---- CSR build (graph identical across layers) ----
    {
        const int* dsts[3] = {ee_dst, es_dst, se_dst};
        int* rps[3] = {rp0, rp1, rp2};
        int* cols[3] = {col0, col1, col2};
        for (int r = 0; r < 3; ++r) {
            zero_k<<<n_blocks, 256, 0, stream>>>((float*)cnt, N);
            hist_k<<<e_blocks, 256, 0, stream>>>(dsts[r], cnt, E);
            scan_k<<<1, 256, 0, stream>>>(cnt, rps[r], N);
            zero_k<<<n_blocks, 256, 0, stream>>>((float*)cnt, N);
            scatter_k<<<e_blocks, 256, 0, stream>>>(dsts[r], rps[r], cnt,
                                                    cols[r], E);
        }
    }

    // initial fp16 activations
    cvt_k<false><<<cvt_blocks, 256, 0, stream>>>(xe_in, xeH, NC / 4);
    cvt_k<false><<<cvt_blocks, 256, 0, stream>>>(xs_in, xsH, NC / 4);

    for (int l = 0; l < 3; ++l) {
        zero_k<<<1024, 256, 0, stream>>>((float*)mkey_e, 4 * N4);

        // ---- scoring ----
        // q_e -> P2h
        cvtT_k<<<256, 256, 0, stream>>>(Wq + (l * 2 + 0) * CC, BtH, 256);
        gemm_h<0, true><<<gh_grid, 256, 0, stream>>>(
            xeH, BtH, P2h, N, 256, nullptr, nullptr, nullptr);
        // rel0: kA from xe
        foldT_k<<<256, 256, 0, stream>>>(Wk + (l * 2 + 0) * CC,
                                         Arel + (l * 3 + 0) * HDD, BtH);
        gemm_h<0, true><<<gh_grid, 256, 0, stream>>>(
            xeH, BtH, P1h, N, 256, nullptr, nullptr, nullptr);
        score_k<<<edge_blocks, 256, 0, stream>>>(
            P2h, P1h, ee_src, ee_dst, mu + (l * 3 + 0) * 4, s0, mkey_e, E);
        // rel2: kA from xs
        foldT_k<<<256, 256, 0, stream>>>(Wk + (l * 2 + 1) * CC,
                                         Arel + (l * 3 + 2) * HDD, BtH);
        gemm_h<0, true><<<gh_grid, 256, 0, stream>>>(
            xsH, BtH, P1h, N, 256, nullptr, nullptr, nullptr);
        score_k<<<edge_blocks, 256, 0, stream>>>(
            P2h, P1h, se_src, se_dst, mu + (l * 3 + 2) * 4, s2, mkey_e, E);
        // q_s -> P2h; rel1: kA from xe
        cvtT_k<<<256, 256, 0, stream>>>(Wq + (l * 2 + 1) * CC, BtH, 256);
        gemm_h<0, true><<<gh_grid, 256, 0, stream>>>(
            xsH, BtH, P2h, N, 256, nullptr, nullptr, nullptr);
        foldT_k<<<256, 256, 0, stream>>>(Wk + (l * 2 + 0) * CC,
                                         Arel + (l * 3 + 1) * HDD, BtH);
        gemm_h<0, true><<<gh_grid, 256, 0, stream>>>(
            xeH, BtH, P1h, N, 256, nullptr, nullptr, nullptr);
        score_k<<<edge_blocks, 256, 0, stream>>>(
            P2h, P1h, es_src, es_dst, mu + (l * 3 + 1) * 4, s1, mkey_s, E);

        // ---- softmax stats ----
        expden_k<<<eh_blocks, 256, 0, stream>>>(s0, ee_dst, mkey_e, den_e, E * 4);
        expden_k<<<eh_blocks, 256, 0, stream>>>(s1, es_dst, mkey_s, den_s, E * 4);
        expden_k<<<eh_blocks, 256, 0, stream>>>(s2, se_dst, mkey_e, den_e, E * 4);

        // ---- aggregation + updates ----
        // rel1: vM from xe -> agg_s
        foldT_k<<<256, 256, 0, stream>>>(Wv + (l * 2 + 0) * CC,
                                         Mrel + (l * 3 + 1) * HDD, BtH);
        gemm_h<0, true><<<gh_grid, 256, 0, stream>>>(
            xeH, BtH, P1h, N, 256, nullptr, nullptr, nullptr);
        agg_csr_k<0><<<wave_blocks, 256, 0, stream>>>(
            s1, den_s, P1h, es_src, rp1, col1, aggB, N);
        cvt_k<true><<<cvt_blocks, 256, 0, stream>>>(aggB, P2h, NC / 4);
        // rel2: vM from OLD xs (before xs update)
        foldT_k<<<256, 256, 0, stream>>>(Wv + (l * 2 + 1) * CC,
                                         Mrel + (l * 3 + 2) * HDD, BtH);
        gemm_h<0, true><<<gh_grid, 256, 0, stream>>>(
            xsH, BtH, P1h, N, 256, nullptr, nullptr, nullptr);
        // xs update (in-place fp16 blend)
        cvtT_k<<<256, 256, 0, stream>>>(Wa + (l * 2 + 1) * CC, BtH, 256);
        gemm_h<1, true><<<gh_grid, 256, 0, stream>>>(
            P2h, BtH, xsH, N, 256, nullptr, skip + l * 2 + 1, xsH);
        // agg_e: rel2 write, rel0 accumulate
        agg_csr_k<0><<<wave_blocks, 256, 0, stream>>>(
            s2, den_e, P1h, se_src, rp2, col2, aggB, N);
        foldT_k<<<256, 256, 0, stream>>>(Wv + (l * 2 + 0) * CC,
                                         Mrel + (l * 3 + 0) * HDD, BtH);
        gemm_h<0, true><<<gh_grid, 256, 0, stream>>>(
            xeH, BtH, P1h, N, 256, nullptr, nullptr, nullptr);
        agg_csr_k<1><<<wave_blocks, 256, 0, stream>>>(
            s0, den_e, P1h, ee_src, rp0, col0, aggB, N);
        // xe update (fp32 state)
        cvt_k<true><<<cvt_blocks, 256, 0, stream>>>(aggB, P2h, NC / 4);
        cvtT_k<<<256, 256, 0, stream>>>(Wa + (l * 2 + 0) * CC, BtH, 256);
        gemm_h<1, false><<<gh_grid, 256, 0, stream>>>(
            P2h, BtH, xeA, N, 256, nullptr, skip + l * 2 + 0,
            (l == 0) ? (const void*)xe_in : (const void*)xeA);
        // refresh fp16 copy of xe for next layer / final stack
        cvt_k<false><<<cvt_blocks, 256, 0, stream>>>(xeA, xeH, NC / 4);
    }

    // shared linear stack (relu(x@W+b)) x2 on expr nodes
    cvtT_k<<<256, 256, 0, stream>>>(Wsh, BtH, 256);
    gemm_h<2, true><<<gh_grid, 256, 0, stream>>>(
        xeH, BtH, P2h, N, 256, bsh, nullptr, nullptr);
    cvtT_k<<<256, 256, 0, stream>>>(Wsh + CC, BtH, 256);
    gemm_h<2, true><<<gh_grid, 256, 0, stream>>>(
        P2h, BtH, P1h, N, 256, bsh + 256, nullptr, nullptr);

    // 7 task heads
    const int OFF[7] = {0, 3, 6, 9, 14, 15, 16};
    const int DIMS[7] = {3, 3, 3, 5, 1, 1, 8};
    const int head_blocks = (N + 31) / 32;
    for (int k = 0; k < 7; ++k) {
        cvtT_k<<<128, 256, 0, stream>>>(Wt1 + (size_t)k * 256 * 128, BtH, 128);
        gemm_h<2, true><<<gh_grid1, 256, 0, stream>>>(
            P1h, BtH, P2h, N, 128, bt1 + k * 128, nullptr, nullptr);
        head_k<<<head_blocks, 256, 0, stream>>>(
            P2h, Wt2 + (size_t)k * 128 * 8, bt2 + k * 8, out, N, OFF[k],
            DIMS[k]);
    }
}

// Round 6
// 1799.234 us; speedup vs baseline: 5.7385x; 1.3600x over previous
//
#include <hip/hip_runtime.h>
#include <hip/hip_fp16.h>
#include <cmath>

// ---------------------------------------------------------------------------
// DragonHGT R6: fp16 MFMA GEMMs + fully fused CSR edge pipeline.
// N=50000 x 2 node types, E=200000 x 3 relations, C=256 (H=4, D=64).
// Workspace ~173 MB. No atomics in the steady path (CSR build only).
// ---------------------------------------------------------------------------

#define CDIM 256
#define HDIM 4
#define DDIM 64

using f16x8 = __attribute__((ext_vector_type(8))) _Float16;
using f16x4 = __attribute__((ext_vector_type(4))) _Float16;
using f32x4 = __attribute__((ext_vector_type(4))) float;

__device__ __forceinline__ float gelu_f(float x) {
    return 0.5f * x * (1.0f + erff(x * 0.70710678118654752f));
}

__global__ __launch_bounds__(256) void zero_k(float* __restrict__ p, size_t n) {
    size_t i = (size_t)blockIdx.x * blockDim.x + threadIdx.x;
    const size_t stride = (size_t)gridDim.x * blockDim.x;
    for (; i < n; i += stride) p[i] = 0.0f;
}

__global__ __launch_bounds__(256) void cvt_k(const float* __restrict__ in,
                                             _Float16* __restrict__ out,
                                             size_t n4) {
    size_t i = (size_t)blockIdx.x * blockDim.x + threadIdx.x;
    const size_t stride = (size_t)gridDim.x * blockDim.x;
    for (; i < n4; i += stride) {
        const float4 v = ((const float4*)in)[i];
        f16x4 o;
        o[0] = (_Float16)v.x; o[1] = (_Float16)v.y;
        o[2] = (_Float16)v.z; o[3] = (_Float16)v.w;
        ((f16x4*)out)[i] = o;
    }
}

// ---------------------------------------------------------------------------
// Weight prep: transpose/convert (and fold Arel/Mrel) into the fp16 arena.
// ---------------------------------------------------------------------------
__device__ __forceinline__ void cvtT_dev(const float* __restrict__ W,
                                         _Float16* __restrict__ dst) {
    const int o = blockIdx.x, c = threadIdx.x;  // dst[o,c] = W[c,o]
    dst[(size_t)o * 256 + c] = (_Float16)W[(size_t)c * 256 + o];
}

__device__ __forceinline__ void foldT_dev(const float* __restrict__ Wbase,
                                          const float* __restrict__ T,
                                          _Float16* __restrict__ dst) {
    __shared__ float row[256];
    const int c = blockIdx.x, t = threadIdx.x;
    row[t] = Wbase[(size_t)c * 256 + t];
    __syncthreads();
    const int h = t >> 6, f = t & 63;
    const float* Th = T + h * 4096;
    float acc = 0.f;
#pragma unroll 8
    for (int d = 0; d < 64; ++d) acc += row[h * 64 + d] * Th[d * 64 + f];
    dst[(size_t)t * 256 + c] = (_Float16)acc;
}

#define AR_R (256 * 256)  // one 256x256 fp16 weight block

__global__ __launch_bounds__(256) void prep_layer_k(
    const float* __restrict__ Wk, const float* __restrict__ Wq,
    const float* __restrict__ Wv, const float* __restrict__ Wa,
    const float* __restrict__ Arel, const float* __restrict__ Mrel, int l,
    _Float16* __restrict__ arena) {
    const size_t CC = 65536, HDD = 16384;
    _Float16* L = arena + (size_t)l * 10 * AR_R;
    const float* Wk0 = Wk + (l * 2 + 0) * CC;
    const float* Wk1 = Wk + (l * 2 + 1) * CC;
    const float* Wv0 = Wv + (l * 2 + 0) * CC;
    const float* Wv1 = Wv + (l * 2 + 1) * CC;
    switch (blockIdx.y) {
        case 0: cvtT_dev(Wq + (l * 2 + 0) * CC, L); break;                    // q_e
        case 1: foldT_dev(Wk0, Arel + (l * 3 + 0) * HDD, L + 1 * AR_R); break; // kA0
        case 2: foldT_dev(Wk1, Arel + (l * 3 + 2) * HDD, L + 2 * AR_R); break; // kA2
        case 3: cvtT_dev(Wq + (l * 2 + 1) * CC, L + 3 * AR_R); break;          // q_s
        case 4: foldT_dev(Wk0, Arel + (l * 3 + 1) * HDD, L + 4 * AR_R); break; // kA1
        case 5: foldT_dev(Wv0, Mrel + (l * 3 + 1) * HDD, L + 5 * AR_R); break; // vM1
        case 6: foldT_dev(Wv0, Mrel + (l * 3 + 0) * HDD, L + 6 * AR_R); break; // vM0
        case 7: foldT_dev(Wv1, Mrel + (l * 3 + 2) * HDD, L + 7 * AR_R); break; // vM2
        case 8: cvtT_dev(Wa + (l * 2 + 1) * CC, L + 8 * AR_R); break;          // WaT1
        case 9: cvtT_dev(Wa + (l * 2 + 0) * CC, L + 9 * AR_R); break;          // WaT0
    }
}

__global__ __launch_bounds__(256) void prep_stack_k(const float* __restrict__ Wsh,
                                                    _Float16* __restrict__ SA) {
    cvtT_dev(Wsh + (size_t)blockIdx.y * 65536, SA + (size_t)blockIdx.y * AR_R);
}

// Wt1[k]: [256,128] -> HA[k]: [128,256] fp16. grid (128, 7).
__global__ __launch_bounds__(256) void prep_heads_k(const float* __restrict__ Wt1,
                                                    _Float16* __restrict__ HA) {
    const int o = blockIdx.x, k = blockIdx.y, c = threadIdx.x;
    HA[(size_t)k * 128 * 256 + (size_t)o * 256 + c] =
        (_Float16)Wt1[(size_t)k * 256 * 128 + (size_t)c * 128 + o];
}

// ---------------------------------------------------------------------------
// fp16 MFMA GEMM: C[M,Nc] = A[M,256] @ Bt[Nc,256]^T, fp32 accumulate.
// 128x128 tile, 4 waves x (64x64). All outputs fp16.
// EPI: 0 plain; 1 skip-blend (in-place safe, Xold fp16); 2 bias+relu.
// SPLIT: Nc=512, cols<256 -> C0, cols>=256 -> C1 (each ld 256).
// ---------------------------------------------------------------------------
template <int EPI, bool SPLIT>
__global__ __launch_bounds__(256) void gemm_h(
    const _Float16* __restrict__ A, const _Float16* __restrict__ Bt,
    _Float16* __restrict__ C0, _Float16* __restrict__ C1, int M, int Nc,
    const float* __restrict__ bias, const float* __restrict__ skipv,
    const _Float16* __restrict__ Xold) {
    __shared__ _Float16 As[128][40];
    __shared__ _Float16 Bs[128][40];
    const int tid = threadIdx.x;
    const int bm = blockIdx.x * 128, bn = blockIdx.y * 128;
    const int wave = tid >> 6, lane = tid & 63;
    const int wm = (wave >> 1) * 64, wn = (wave & 1) * 64;
    const int l15 = lane & 15, g = lane >> 4;
    const int srow = tid >> 2, soff = (tid & 3) * 8;

    f32x4 acc[4][4] = {};

    for (int k0 = 0; k0 < 256; k0 += 32) {
        __syncthreads();
#pragma unroll
        for (int p = 0; p < 2; ++p) {
            const int r = p * 64 + srow;
            int gr = bm + r; if (gr >= M) gr = M - 1;
            *(f16x8*)&As[r][soff] =
                *(const f16x8*)&A[(size_t)gr * 256 + k0 + soff];
            *(f16x8*)&Bs[r][soff] =
                *(const f16x8*)&Bt[(size_t)(bn + r) * 256 + k0 + soff];
        }
        __syncthreads();
        f16x8 af[4], bf[4];
#pragma unroll
        for (int i = 0; i < 4; ++i) {
            af[i] = *(const f16x8*)&As[wm + i * 16 + l15][g * 8];
            bf[i] = *(const f16x8*)&Bs[wn + i * 16 + l15][g * 8];
        }
#pragma unroll
        for (int mi = 0; mi < 4; ++mi)
#pragma unroll
            for (int ni = 0; ni < 4; ++ni)
                acc[mi][ni] = __builtin_amdgcn_mfma_f32_16x16x32_f16(
                    af[mi], bf[ni], acc[mi][ni], 0, 0, 0);
    }

    float be = 0.f, ombe = 0.f;
    if (EPI == 1) {
        const float s = skipv[0];
        be = 1.0f / (1.0f + expf(-s));
        ombe = 1.0f - be;
    }
    const int ldc = SPLIT ? 256 : Nc;
#pragma unroll
    for (int mi = 0; mi < 4; ++mi) {
#pragma unroll
        for (int r = 0; r < 4; ++r) {
            const int row = bm + wm + mi * 16 + g * 4 + r;
            if (row >= M) continue;
#pragma unroll
            for (int ni = 0; ni < 4; ++ni) {
                const int colg = bn + wn + ni * 16 + l15;
                float v = acc[mi][ni][r];
                _Float16* C = SPLIT ? (colg < 256 ? C0 : C1) : C0;
                const int cc = SPLIT ? (colg & 255) : colg;
                if (EPI == 1)
                    v = be * v + ombe * (float)Xold[(size_t)row * ldc + cc];
                if (EPI == 2) v = fmaxf(v + bias[colg], 0.f);
                C[(size_t)row * ldc + cc] = (_Float16)v;
            }
        }
    }
}

// ---------------------------------------------------------------------------
// CSR build (batched over 3 relations).
// ---------------------------------------------------------------------------
__global__ __launch_bounds__(256) void hist3_k(const int* __restrict__ d0,
                                               const int* __restrict__ d1,
                                               const int* __restrict__ d2,
                                               int* __restrict__ cnt, int N,
                                               int E) {
    const int i = blockIdx.x * 256 + threadIdx.x;
    if (i >= E) return;
    const int r = blockIdx.y;
    const int* d = r == 0 ? d0 : r == 1 ? d1 : d2;
    atomicAdd(&cnt[(size_t)r * N + d[i]], 1);
}

__global__ __launch_bounds__(1024) void scan3_k(const int* __restrict__ cnt,
                                                int* __restrict__ rp, int N) {
    __shared__ int sums[1024];
    const int r = blockIdx.y;
    const int* c = cnt + (size_t)r * N;
    int* o = rp + (size_t)r * (N + 1);
    const int tid = threadIdx.x;
    const int chunk = (N + 1023) / 1024;
    const int lo = min(tid * chunk, N), hi = min(lo + chunk, N);
    int s = 0;
    for (int i = lo; i < hi; ++i) s += c[i];
    sums[tid] = s;
    __syncthreads();
    for (int off = 1; off < 1024; off <<= 1) {
        const int v = (tid >= off) ? sums[tid - off] : 0;
        __syncthreads();
        sums[tid] += v;
        __syncthreads();
    }
    int run = (tid == 0) ? 0 : sums[tid - 1];
    for (int i = lo; i < hi; ++i) { o[i] = run; run += c[i]; }
    if (tid == 1023) o[N] = run;
}

__global__ __launch_bounds__(256) void scatter3_k(
    const int* __restrict__ d0, const int* __restrict__ d1,
    const int* __restrict__ d2, const int* __restrict__ rp,
    int* __restrict__ fill, int* __restrict__ col, int N, int E) {
    const int i = blockIdx.x * 256 + threadIdx.x;
    if (i >= E) return;
    const int r = blockIdx.y;
    const int* d = r == 0 ? d0 : r == 1 ? d1 : d2;
    const int dd = d[i];
    const int p = rp[(size_t)r * (N + 1) + dd] + atomicAdd(&fill[(size_t)r * N + dd], 1);
    col[(size_t)r * E + p] = i;
}

// ---------------------------------------------------------------------------
// Fused scoring: one wave per dst node. Computes raw scores + per-(dst,head)
// max in-wave (no atomics). NREL=2 handles the combined expr softmax domain.
// ---------------------------------------------------------------------------
template <int NREL>
__global__ __launch_bounds__(256) void score_csr_k(
    const _Float16* __restrict__ q, const _Float16* __restrict__ kA,
    const _Float16* __restrict__ kB, const int* __restrict__ srcA,
    const int* __restrict__ srcB, const int* __restrict__ rpA,
    const int* __restrict__ colA, const int* __restrict__ rpB,
    const int* __restrict__ colB, const float* __restrict__ muA,
    const float* __restrict__ muB, float* __restrict__ scA,
    float* __restrict__ scB, float* __restrict__ mx, int Nn) {
    const int wid = (blockIdx.x * blockDim.x + threadIdx.x) >> 6;
    if (wid >= Nn) return;
    const int lane = threadIdx.x & 63;
    const int h = lane >> 4;
    const f16x4 qv = *(const f16x4*)&q[(size_t)wid * 256 + lane * 4];
    float m = -1e30f;
    {
        const float mA = muA[h] * 0.125f;
        const int b = rpA[wid], e_ = rpA[wid + 1];
        for (int i = b; i < e_; ++i) {
            const int e = colA[i], s = srcA[e];
            const f16x4 kv = *(const f16x4*)&kA[(size_t)s * 256 + lane * 4];
            float p = (float)qv[0] * (float)kv[0] + (float)qv[1] * (float)kv[1] +
                      (float)qv[2] * (float)kv[2] + (float)qv[3] * (float)kv[3];
            p += __shfl_xor(p, 1); p += __shfl_xor(p, 2);
            p += __shfl_xor(p, 4); p += __shfl_xor(p, 8);
            if ((lane & 15) == 0) {
                const float val = p * mA;
                scA[(size_t)e * 4 + h] = val;
                m = fmaxf(m, val);
            }
        }
    }
    if (NREL == 2) {
        const float mB = muB[h] * 0.125f;
        const int b = rpB[wid], e_ = rpB[wid + 1];
        for (int i = b; i < e_; ++i) {
            const int e = colB[i], s = srcB[e];
            const f16x4 kv = *(const f16x4*)&kB[(size_t)s * 256 + lane * 4];
            float p = (float)qv[0] * (float)kv[0] + (float)qv[1] * (float)kv[1] +
                      (float)qv[2] * (float)kv[2] + (float)qv[3] * (float)kv[3];
            p += __shfl_xor(p, 1); p += __shfl_xor(p, 2);
            p += __shfl_xor(p, 4); p += __shfl_xor(p, 8);
            if ((lane & 15) == 0) {
                const float val = p * mB;
                scB[(size_t)e * 4 + h] = val;
                m = fmaxf(m, val);
            }
        }
    }
    if ((lane & 15) == 0) mx[(size_t)wid * 4 + h] = m;
}

// ---------------------------------------------------------------------------
// Fused aggregation: one wave per dst. Pass1: den = sum(exp(sc-max)) (lanes
// cover 16 edges x 4 heads). Pass2: weighted fp32 accumulate of fp16 vM rows,
// gelu, store fp16. No atomics, no intermediate fp32 buffer.
// ---------------------------------------------------------------------------
template <int NREL>
__global__ __launch_bounds__(256) void agg_csr_k(
    const float* __restrict__ scA, const float* __restrict__ scB,
    const float* __restrict__ mx, const _Float16* __restrict__ vA,
    const _Float16* __restrict__ vB, const int* __restrict__ srcA,
    const int* __restrict__ srcB, const int* __restrict__ rpA,
    const int* __restrict__ colA, const int* __restrict__ rpB,
    const int* __restrict__ colB, _Float16* __restrict__ outH, int Nn) {
    const int wid = (blockIdx.x * blockDim.x + threadIdx.x) >> 6;
    if (wid >= Nn) return;
    const int lane = threadIdx.x & 63;
    const int hHi = lane >> 4, hLo = lane & 3, sl = lane >> 2;
    const float mHi = mx[(size_t)wid * 4 + hHi];
    const float mLo = mx[(size_t)wid * 4 + hLo];
    const int bA = rpA[wid], eA = rpA[wid + 1];
    int bB = 0, eB = 0;
    if (NREL == 2) { bB = rpB[wid]; eB = rpB[wid + 1]; }

    float dl = 0.f;
    for (int base = bA; base < eA; base += 16) {
        const int i = base + sl;
        if (i < eA) dl += expf(scA[(size_t)colA[i] * 4 + hLo] - mLo);
    }
    if (NREL == 2) {
        for (int base = bB; base < eB; base += 16) {
            const int i = base + sl;
            if (i < eB) dl += expf(scB[(size_t)colB[i] * 4 + hLo] - mLo);
        }
    }
    dl += __shfl_xor(dl, 4); dl += __shfl_xor(dl, 8);
    dl += __shfl_xor(dl, 16); dl += __shfl_xor(dl, 32);
    const float dinv = 1.0f / (__shfl(dl, hHi) + 1e-16f);

    float4 acc = make_float4(0.f, 0.f, 0.f, 0.f);
    for (int i = bA; i < eA; ++i) {
        const int e = colA[i], s = srcA[e];
        const float w = expf(scA[(size_t)e * 4 + hHi] - mHi) * dinv;
        const f16x4 v = *(const f16x4*)&vA[(size_t)s * 256 + lane * 4];
        acc.x += w * (float)v[0]; acc.y += w * (float)v[1];
        acc.z += w * (float)v[2]; acc.w += w * (float)v[3];
    }
    if (NREL == 2) {
        for (int i = bB; i < eB; ++i) {
            const int e = colB[i], s = srcB[e];
            const float w = expf(scB[(size_t)e * 4 + hHi] - mHi) * dinv;
            const f16x4 v = *(const f16x4*)&vB[(size_t)s * 256 + lane * 4];
            acc.x += w * (float)v[0]; acc.y += w * (float)v[1];
            acc.z += w * (float)v[2]; acc.w += w * (float)v[3];
        }
    }
    f16x4 o;
    o[0] = (_Float16)gelu_f(acc.x); o[1] = (_Float16)gelu_f(acc.y);
    o[2] = (_Float16)gelu_f(acc.z); o[3] = (_Float16)gelu_f(acc.w);
    *(f16x4*)&outH[(size_t)wid * 256 + lane * 4] = o;
}

// ---------------------------------------------------------------------------
// Final tiny head GEMM.
// ---------------------------------------------------------------------------
__global__ __launch_bounds__(256) void head_k(
    const _Float16* __restrict__ t, const float* __restrict__ W2,
    const float* __restrict__ b2, float* __restrict__ out, int M, int off,
    int dims) {
    __shared__ float Ws[128 * 8];
    __shared__ float bs[8];
    const int tid = threadIdx.x;
    for (int i = tid; i < 1024; i += 256) Ws[i] = W2[i];
    if (tid < 8) bs[tid] = b2[tid];
    __syncthreads();
    const int nl = tid >> 3, o = tid & 7;
    const int n = blockIdx.x * 32 + nl;
    if (n >= M) return;
    const _Float16* tr = &t[(size_t)n * 128];
    float acc = bs[o];
#pragma unroll 8
    for (int d = 0; d < 128; ++d) acc += (float)tr[d] * Ws[d * 8 + o];
    if (o < dims) out[(size_t)n * 24 + off + o] = acc;
}

// ---------------------------------------------------------------------------

extern "C" void kernel_launch(void* const* d_in, const int* in_sizes, int n_in,
                              void* d_out, int out_size, void* d_ws,
                              size_t ws_size, hipStream_t stream) {
    const float* xe_in = (const float*)d_in[0];
    const float* xs_in = (const float*)d_in[1];
    const int* ee_src = (const int*)d_in[2];
    const int* ee_dst = (const int*)d_in[3];
    const int* es_src = (const int*)d_in[4];
    const int* es_dst = (const int*)d_in[5];
    const int* se_src = (const int*)d_in[6];
    const int* se_dst = (const int*)d_in[7];
    const float* Wk = (const float*)d_in[8];
    const float* Wq = (const float*)d_in[9];
    const float* Wv = (const float*)d_in[10];
    const float* Wa = (const float*)d_in[11];
    const float* skip = (const float*)d_in[12];
    const float* Arel = (const float*)d_in[13];
    const float* Mrel = (const float*)d_in[14];
    const float* mu = (const float*)d_in[15];
    const float* Wsh = (const float*)d_in[16];
    const float* bsh = (const float*)d_in[17];
    const float* Wt1 = (const float*)d_in[18];
    const float* bt1 = (const float*)d_in[19];
    const float* Wt2 = (const float*)d_in[20];
    const float* bt2 = (const float*)d_in[21];
    float* out = (float*)d_out;

    const int N = in_sizes[0] / CDIM;  // 50000
    const int E = in_sizes[2];         // 200000
    const size_t NC = (size_t)N * CDIM;
    const size_t E4 = (size_t)E * 4;
    const size_t N4 = (size_t)N * 4;
    const size_t AROWS = 3 * 10 * 256 + 2 * 256 + 7 * 128;  // layer + stack + heads

    const size_t need = (3 * E4 + 2 * N4) * 4            // scores + mx (f32)
                        + (6 * NC + AROWS * 256) * 2     // fp16 buffers + arena
                        + (3 * (size_t)(N + 1) + 3 * (size_t)E + 3 * (size_t)N) * 4;
    if (ws_size < need) return;  // diagnostic: fail accuracy, not crash

    float* s0 = (float*)d_ws;
    float* s1 = s0 + E4;
    float* s2 = s1 + E4;
    float* mx_e = s2 + E4;
    float* mx_s = mx_e + N4;
    _Float16* xeH = (_Float16*)(mx_s + N4);
    _Float16* xsH = xeH + NC;
    _Float16* H1 = xsH + NC;
    _Float16* H2 = H1 + NC;
    _Float16* H3 = H2 + NC;
    _Float16* H4 = H3 + NC;
    _Float16* arena = H4 + NC;                       // 3 layers x 10 blocks
    _Float16* SA = arena + (size_t)3 * 10 * AR_R;    // stack (2 blocks)
    _Float16* HA = SA + (size_t)2 * AR_R;            // heads (7 x 128 rows)
    int* rp = (int*)(HA + (size_t)7 * 128 * 256);    // [3][N+1]
    int* col = rp + 3 * (size_t)(N + 1);             // [3][E]
    int* cnt = col + 3 * (size_t)E;                  // [3][N]

    const int* rp0 = rp, *rp1 = rp + (N + 1), *rp2 = rp + 2 * (N + 1);
    const int* col0 = col, *col1 = col + E, *col2 = col + 2 * E;

    const dim3 g512((N + 127) / 128, 4);
    const dim3 g256((N + 127) / 128, 2);
    const dim3 g128((N + 127) / 128, 1);
    const dim3 e3((E + 255) / 256, 3);
    const int wave_blocks = (N + 3) / 4;
    const int zc_blocks = (3 * N + 255) / 256;

    // ---- CSR build ----
    zero_k<<<zc_blocks, 256, 0, stream>>>((float*)cnt, 3 * (size_t)N);
    hist3_k<<<e3, 256, 0, stream>>>(ee_dst, es_dst, se_dst, cnt, N, E);
    scan3_k<<<dim3(1, 3), 1024, 0, stream>>>(cnt, rp, N);
    zero_k<<<zc_blocks, 256, 0, stream>>>((float*)cnt, 3 * (size_t)N);
    scatter3_k<<<e3, 256, 0, stream>>>(ee_dst, es_dst, se_dst, rp, cnt, col, N, E);

    // ---- weight prep ----
    for (int l = 0; l < 3; ++l)
        prep_layer_k<<<dim3(256, 10), 256, 0, stream>>>(Wk, Wq, Wv, Wa, Arel,
                                                        Mrel, l, arena);
    prep_stack_k<<<dim3(256, 2), 256, 0, stream>>>(Wsh, SA);
    prep_heads_k<<<dim3(128, 7), 256, 0, stream>>>(Wt1, HA);

    // ---- initial fp16 activations ----
    cvt_k<<<1024, 256, 0, stream>>>(xe_in, xeH, NC / 4);
    cvt_k<<<1024, 256, 0, stream>>>(xs_in, xsH, NC / 4);

    for (int l = 0; l < 3; ++l) {
        _Float16* L = arena + (size_t)l * 10 * AR_R;
        const float* mu0 = mu + (l * 3 + 0) * 4;
        const float* mu1 = mu + (l * 3 + 1) * 4;
        const float* mu2 = mu + (l * 3 + 2) * 4;

        // scoring
        gemm_h<0, true><<<g512, 256, 0, stream>>>(xeH, L, H1, H2, N, 512,
                                                  nullptr, nullptr, nullptr);
        gemm_h<0, false><<<g256, 256, 0, stream>>>(xsH, L + 2 * AR_R, H3,
                                                   nullptr, N, 256, nullptr,
                                                   nullptr, nullptr);
        score_csr_k<2><<<wave_blocks, 256, 0, stream>>>(
            H1, H2, H3, ee_src, se_src, rp0, col0, rp2, col2, mu0, mu2, s0, s2,
            mx_e, N);
        gemm_h<0, false><<<g256, 256, 0, stream>>>(xsH, L + 3 * AR_R, H1,
                                                   nullptr, N, 256, nullptr,
                                                   nullptr, nullptr);
        gemm_h<0, false><<<g256, 256, 0, stream>>>(xeH, L + 4 * AR_R, H2,
                                                   nullptr, N, 256, nullptr,
                                                   nullptr, nullptr);
        score_csr_k<1><<<wave_blocks, 256, 0, stream>>>(
            H1, H2, nullptr, es_src, nullptr, rp1, col1, nullptr, nullptr, mu1,
            nullptr, s1, nullptr, mx_s, N);

        // aggregation + updates
        gemm_h<0, true><<<g512, 256, 0, stream>>>(xeH, L + 5 * AR_R, H1, H2, N,
                                                  512, nullptr, nullptr,
                                                  nullptr);  // vM1|vM0
        gemm_h<0, false><<<g256, 256, 0, stream>>>(xsH, L + 7 * AR_R, H3,
                                                   nullptr, N, 256, nullptr,
                                                   nullptr, nullptr);  // vM2
        agg_csr_k<1><<<wave_blocks, 256, 0, stream>>>(
            s1, nullptr, mx_s, H1, nullptr, es_src, nullptr, rp1, col1, nullptr,
            nullptr, H4, N);
        gemm_h<1, false><<<g256, 256, 0, stream>>>(H4, L + 8 * AR_R, xsH,
                                                   nullptr, N, 256, nullptr,
                                                   skip + l * 2 + 1, xsH);
        agg_csr_k<2><<<wave_blocks, 256, 0, stream>>>(
            s0, s2, mx_e, H2, H3, ee_src, se_src, rp0, col0, rp2, col2, H4, N);
        gemm_h<1, false><<<g256, 256, 0, stream>>>(H4, L + 9 * AR_R, xeH,
                                                   nullptr, N, 256, nullptr,
                                                   skip + l * 2 + 0, xeH);
    }

    // shared linear stack
    gemm_h<2, false><<<g256, 256, 0, stream>>>(xeH, SA, H1, nullptr, N, 256,
                                               bsh, nullptr, nullptr);
    gemm_h<2, false><<<g256, 256, 0, stream>>>(H1, SA + AR_R, H2, nullptr, N,
                                               256, bsh + 256, nullptr, nullptr);

    // 7 task heads
    const int OFF[7] = {0, 3, 6, 9, 14, 15, 16};
    const int DIMS[7] = {3, 3, 3, 5, 1, 1, 8};
    const int head_blocks = (N + 31) / 32;
    for (int k = 0; k < 7; ++k) {
        gemm_h<2, false><<<g128, 256, 0, stream>>>(
            H2, HA + (size_t)k * 128 * 256, H3, nullptr, N, 128, bt1 + k * 128,
            nullptr, nullptr);
        head_k<<<head_blocks, 256, 0, stream>>>(
            H3, Wt2 + (size_t)k * 128 * 8, bt2 + k * 8, out, N, OFF[k], DIMS[k]);
    }
}

// Round 7
// 1281.565 us; speedup vs baseline: 8.0564x; 1.4039x over previous
//
#include <hip/hip_runtime.h>
#include <hip/hip_fp16.h>
#include <cmath>

// ---------------------------------------------------------------------------
// DragonHGT R7: fused fp16 MFMA GEMMs + CSR edge pipeline with colsrc +
// online-softmax in scoring. ~200 MB workspace, ~37 dispatches.
// N=50000 x 2 node types, E=200000 x 3 relations, C=256 (H=4, D=64).
// ---------------------------------------------------------------------------

#define CDIM 256
#define AR_R (256 * 256)

using f16x8 = __attribute__((ext_vector_type(8))) _Float16;
using f16x4 = __attribute__((ext_vector_type(4))) _Float16;
using f32x4 = __attribute__((ext_vector_type(4))) float;

__device__ __forceinline__ float gelu_f(float x) {
    return 0.5f * x * (1.0f + erff(x * 0.70710678118654752f));
}
__device__ __forceinline__ float dot4(const f16x4 a, const f16x4 b) {
    return (float)a[0] * (float)b[0] + (float)a[1] * (float)b[1] +
           (float)a[2] * (float)b[2] + (float)a[3] * (float)b[3];
}

__global__ __launch_bounds__(256) void zero_k(int* __restrict__ p, size_t n) {
    size_t i = (size_t)blockIdx.x * blockDim.x + threadIdx.x;
    const size_t stride = (size_t)gridDim.x * blockDim.x;
    for (; i < n; i += stride) p[i] = 0;
}

__global__ __launch_bounds__(256) void cvt_k(const float* __restrict__ in,
                                             _Float16* __restrict__ out,
                                             size_t n4) {
    size_t i = (size_t)blockIdx.x * blockDim.x + threadIdx.x;
    const size_t stride = (size_t)gridDim.x * blockDim.x;
    for (; i < n4; i += stride) {
        const float4 v = ((const float4*)in)[i];
        f16x4 o;
        o[0] = (_Float16)v.x; o[1] = (_Float16)v.y;
        o[2] = (_Float16)v.z; o[3] = (_Float16)v.w;
        ((f16x4*)out)[i] = o;
    }
}

// ---------------------------------------------------------------------------
// Weight prep.
// ---------------------------------------------------------------------------
__device__ __forceinline__ void cvtT_dev(const float* __restrict__ W,
                                         _Float16* __restrict__ dst) {
    const int o = blockIdx.x, c = threadIdx.x;
    dst[(size_t)o * 256 + c] = (_Float16)W[(size_t)c * 256 + o];
}

__device__ __forceinline__ void foldT_dev(const float* __restrict__ Wbase,
                                          const float* __restrict__ T,
                                          _Float16* __restrict__ dst) {
    __shared__ float row[256];
    const int c = blockIdx.x, t = threadIdx.x;
    row[t] = Wbase[(size_t)c * 256 + t];
    __syncthreads();
    const int h = t >> 6, f = t & 63;
    const float* Th = T + h * 4096;
    float acc = 0.f;
#pragma unroll 8
    for (int d = 0; d < 64; ++d) acc += row[h * 64 + d] * Th[d * 64 + f];
    dst[(size_t)t * 256 + c] = (_Float16)acc;
}

// arena layout per layer (10 blocks): q_e|kA0|kA1 | q_s|kA2 | vM0|vM1 | vM2 | WaT0|WaT1
__global__ __launch_bounds__(256) void prep_layer_k(
    const float* __restrict__ Wk, const float* __restrict__ Wq,
    const float* __restrict__ Wv, const float* __restrict__ Wa,
    const float* __restrict__ Arel, const float* __restrict__ Mrel, int l,
    _Float16* __restrict__ arena) {
    const size_t CC = 65536, HDD = 16384;
    _Float16* L = arena + (size_t)l * 10 * AR_R;
    const float* Wk0 = Wk + (l * 2 + 0) * CC;
    const float* Wk1 = Wk + (l * 2 + 1) * CC;
    const float* Wv0 = Wv + (l * 2 + 0) * CC;
    const float* Wv1 = Wv + (l * 2 + 1) * CC;
    switch (blockIdx.y) {
        case 0: cvtT_dev(Wq + (l * 2 + 0) * CC, L); break;
        case 1: foldT_dev(Wk0, Arel + (l * 3 + 0) * HDD, L + 1 * AR_R); break;
        case 2: foldT_dev(Wk0, Arel + (l * 3 + 1) * HDD, L + 2 * AR_R); break;
        case 3: cvtT_dev(Wq + (l * 2 + 1) * CC, L + 3 * AR_R); break;
        case 4: foldT_dev(Wk1, Arel + (l * 3 + 2) * HDD, L + 4 * AR_R); break;
        case 5: foldT_dev(Wv0, Mrel + (l * 3 + 0) * HDD, L + 5 * AR_R); break;
        case 6: foldT_dev(Wv0, Mrel + (l * 3 + 1) * HDD, L + 6 * AR_R); break;
        case 7: foldT_dev(Wv1, Mrel + (l * 3 + 2) * HDD, L + 7 * AR_R); break;
        case 8: cvtT_dev(Wa + (l * 2 + 0) * CC, L + 8 * AR_R); break;
        case 9: cvtT_dev(Wa + (l * 2 + 1) * CC, L + 9 * AR_R); break;
    }
}

__global__ __launch_bounds__(256) void prep_stack_k(const float* __restrict__ Wsh,
                                                    _Float16* __restrict__ SA) {
    cvtT_dev(Wsh + (size_t)blockIdx.y * 65536, SA + (size_t)blockIdx.y * AR_R);
}

// Wt1[k]: [256,128] -> HA rows [k*128+o][c]
__global__ __launch_bounds__(256) void prep_heads_k(const float* __restrict__ Wt1,
                                                    _Float16* __restrict__ HA) {
    const int o = blockIdx.x, k = blockIdx.y, c = threadIdx.x;
    HA[(size_t)(k * 128 + o) * 256 + c] =
        (_Float16)Wt1[(size_t)k * 256 * 128 + (size_t)c * 128 + o];
}

// ---------------------------------------------------------------------------
// fp16 MFMA GEMM body: C = A[M,256] @ Bt[Nc,256]^T (128x128 tile, 4 waves).
// SPLIT: store into (colg>>8)-th [M,256] buffer (stride bufStride halfs).
// FLAT : C[row*Nc + colg].
// EPI: 0 plain; 1 skip-blend in place (FLAT, Nc=256); 2 bias+relu.
// ---------------------------------------------------------------------------
template <int EPI, bool SPLIT>
__device__ __forceinline__ void gemm_body(
    const _Float16* __restrict__ A, const _Float16* __restrict__ Bt,
    _Float16* __restrict__ C, int M, int Nc, int bn, size_t bufStride,
    const float* __restrict__ bias, const float* __restrict__ skipv,
    _Float16 (*As)[40], _Float16 (*Bs)[40]) {
    const int tid = threadIdx.x;
    const int bm = blockIdx.x * 128;
    const int wave = tid >> 6, lane = tid & 63;
    const int wm = (wave >> 1) * 64, wn = (wave & 1) * 64;
    const int l15 = lane & 15, g = lane >> 4;
    const int srow = tid >> 2, soff = (tid & 3) * 8;

    f32x4 acc[4][4] = {};

    for (int k0 = 0; k0 < 256; k0 += 32) {
        __syncthreads();
#pragma unroll
        for (int p = 0; p < 2; ++p) {
            const int r = p * 64 + srow;
            int gr = bm + r; if (gr >= M) gr = M - 1;
            *(f16x8*)&As[r][soff] =
                *(const f16x8*)&A[(size_t)gr * 256 + k0 + soff];
            *(f16x8*)&Bs[r][soff] =
                *(const f16x8*)&Bt[(size_t)(bn + r) * 256 + k0 + soff];
        }
        __syncthreads();
        f16x8 af[4], bf[4];
#pragma unroll
        for (int i = 0; i < 4; ++i) {
            af[i] = *(const f16x8*)&As[wm + i * 16 + l15][g * 8];
            bf[i] = *(const f16x8*)&Bs[wn + i * 16 + l15][g * 8];
        }
#pragma unroll
        for (int mi = 0; mi < 4; ++mi)
#pragma unroll
            for (int ni = 0; ni < 4; ++ni)
                acc[mi][ni] = __builtin_amdgcn_mfma_f32_16x16x32_f16(
                    af[mi], bf[ni], acc[mi][ni], 0, 0, 0);
    }

    float be = 0.f, ombe = 0.f;
    if (EPI == 1) {
        const float s = skipv[0];
        be = 1.0f / (1.0f + expf(-s));
        ombe = 1.0f - be;
    }
#pragma unroll
    for (int mi = 0; mi < 4; ++mi) {
#pragma unroll
        for (int r = 0; r < 4; ++r) {
            const int row = bm + wm + mi * 16 + g * 4 + r;
            if (row >= M) continue;
#pragma unroll
            for (int ni = 0; ni < 4; ++ni) {
                const int colg = bn + wn + ni * 16 + l15;
                float v = acc[mi][ni][r];
                size_t idx;
                if (SPLIT)
                    idx = (size_t)(colg >> 8) * bufStride + (size_t)row * 256 +
                          (colg & 255);
                else
                    idx = (size_t)row * Nc + colg;
                if (EPI == 1) v = be * v + ombe * (float)C[idx];
                if (EPI == 2) v = fmaxf(v + bias[colg], 0.f);
                C[idx] = (_Float16)v;
            }
        }
    }
}

template <int EPI, bool SPLIT>
__global__ __launch_bounds__(256) void gemm_h(
    const _Float16* __restrict__ A, const _Float16* __restrict__ Bt,
    _Float16* __restrict__ C, int M, int Nc, size_t bufStride,
    const float* __restrict__ bias, const float* __restrict__ skipv) {
    __shared__ _Float16 As[128][40];
    __shared__ _Float16 Bs[128][40];
    gemm_body<EPI, SPLIT>(A, Bt, C, M, Nc, blockIdx.y * 128, bufStride, bias,
                          skipv, As, Bs);
}

// Fused skip-updates: y>>1==0 -> xe (A=aggE, Bt=WaT0); ==1 -> xs.
__global__ __launch_bounds__(256) void update2_k(
    const _Float16* __restrict__ aggE, const _Float16* __restrict__ aggS,
    const _Float16* __restrict__ WaT0, const _Float16* __restrict__ WaT1,
    _Float16* __restrict__ xeH, _Float16* __restrict__ xsH,
    const float* __restrict__ skipb, int M) {
    __shared__ _Float16 As[128][40];
    __shared__ _Float16 Bs[128][40];
    const int sel = blockIdx.y >> 1;
    const int bn = (blockIdx.y & 1) * 128;
    if (sel == 0)
        gemm_body<1, false>(aggE, WaT0, xeH, M, 256, bn, 0, nullptr, skipb, As, Bs);
    else
        gemm_body<1, false>(aggS, WaT1, xsH, M, 256, bn, 0, nullptr, skipb + 1, As, Bs);
}

// ---------------------------------------------------------------------------
// CSR build: rp + colsrc (src node per CSR slot; edge ids never needed again).
// ---------------------------------------------------------------------------
__global__ __launch_bounds__(256) void hist3_k(const int* __restrict__ d0,
                                               const int* __restrict__ d1,
                                               const int* __restrict__ d2,
                                               int* __restrict__ cnt, int N,
                                               int E) {
    const int i = blockIdx.x * 256 + threadIdx.x;
    if (i >= E) return;
    const int r = blockIdx.y;
    const int* d = r == 0 ? d0 : r == 1 ? d1 : d2;
    atomicAdd(&cnt[(size_t)r * N + d[i]], 1);
}

__global__ __launch_bounds__(1024) void scan3_k(const int* __restrict__ cnt,
                                                int* __restrict__ rp, int N) {
    __shared__ int sums[1024];
    const int r = blockIdx.y;
    const int* c = cnt + (size_t)r * N;
    int* o = rp + (size_t)r * (N + 1);
    const int tid = threadIdx.x;
    const int chunk = (N + 1023) / 1024;
    const int lo = min(tid * chunk, N), hi = min(lo + chunk, N);
    int s = 0;
    for (int i = lo; i < hi; ++i) s += c[i];
    sums[tid] = s;
    __syncthreads();
    for (int off = 1; off < 1024; off <<= 1) {
        const int v = (tid >= off) ? sums[tid - off] : 0;
        __syncthreads();
        sums[tid] += v;
        __syncthreads();
    }
    int run = (tid == 0) ? 0 : sums[tid - 1];
    for (int i = lo; i < hi; ++i) { o[i] = run; run += c[i]; }
    if (tid == 1023) o[N] = run;
}

__global__ __launch_bounds__(256) void scatter3_k(
    const int* __restrict__ d0, const int* __restrict__ d1,
    const int* __restrict__ d2, const int* __restrict__ s0_,
    const int* __restrict__ s1_, const int* __restrict__ s2_,
    const int* __restrict__ rp, int* __restrict__ fill,
    int* __restrict__ colsrc, int N, int E) {
    const int i = blockIdx.x * 256 + threadIdx.x;
    if (i >= E) return;
    const int r = blockIdx.y;
    const int* d = r == 0 ? d0 : r == 1 ? d1 : d2;
    const int* s = r == 0 ? s0_ : r == 1 ? s1_ : s2_;
    const int dd = d[i];
    const int p = rp[(size_t)r * (N + 1) + dd] + atomicAdd(&fill[(size_t)r * N + dd], 1);
    colsrc[(size_t)r * E + p] = s[i];
}

// ---------------------------------------------------------------------------
// Fused scoring with online softmax stats. One wave per dst node.
// grid.y: 0 = expr domain (rel0 + rel2), 1 = stmt domain (rel1).
// Writes raw scores in CSR order + per-(dst,head) max and denominator.
// ---------------------------------------------------------------------------
__device__ __forceinline__ void score_rel(
    const f16x4 qv, const _Float16* __restrict__ kA,
    const int* __restrict__ cs, int beg, int end, float scale,
    float* __restrict__ sc, int lane, int h, float& m, float& den) {
    int i = beg;
    for (; i + 1 < end; i += 2) {
        const int sA = cs[i], sB = cs[i + 1];
        const f16x4 k0 = *(const f16x4*)&kA[(size_t)sA * 256 + lane * 4];
        const f16x4 k1 = *(const f16x4*)&kA[(size_t)sB * 256 + lane * 4];
        float p0 = dot4(qv, k0), p1 = dot4(qv, k1);
        p0 += __shfl_xor(p0, 1); p1 += __shfl_xor(p1, 1);
        p0 += __shfl_xor(p0, 2); p1 += __shfl_xor(p1, 2);
        p0 += __shfl_xor(p0, 4); p1 += __shfl_xor(p1, 4);
        p0 += __shfl_xor(p0, 8); p1 += __shfl_xor(p1, 8);
        const float v0 = p0 * scale, v1 = p1 * scale;
        if ((lane & 15) == 0) {
            sc[(size_t)i * 4 + h] = v0;
            sc[(size_t)(i + 1) * 4 + h] = v1;
        }
        const float nm = fmaxf(m, fmaxf(v0, v1));
        den = den * expf(m - nm) + expf(v0 - nm) + expf(v1 - nm);
        m = nm;
    }
    if (i < end) {
        const int sA = cs[i];
        const f16x4 k0 = *(const f16x4*)&kA[(size_t)sA * 256 + lane * 4];
        float p0 = dot4(qv, k0);
        p0 += __shfl_xor(p0, 1); p0 += __shfl_xor(p0, 2);
        p0 += __shfl_xor(p0, 4); p0 += __shfl_xor(p0, 8);
        const float v0 = p0 * scale;
        if ((lane & 15) == 0) sc[(size_t)i * 4 + h] = v0;
        const float nm = fmaxf(m, v0);
        den = den * expf(m - nm) + expf(v0 - nm);
        m = nm;
    }
}

__global__ __launch_bounds__(256) void score3_k(
    const _Float16* __restrict__ qe, const _Float16* __restrict__ kA0,
    const _Float16* __restrict__ kA1, const _Float16* __restrict__ qs,
    const _Float16* __restrict__ kA2, const int* __restrict__ rp,
    const int* __restrict__ colsrc, const float* __restrict__ muL,
    float* __restrict__ sc, float* __restrict__ mx_e,
    float* __restrict__ den_e, float* __restrict__ mx_s,
    float* __restrict__ den_s, int N, int E) {
    const int wid = (blockIdx.x * blockDim.x + threadIdx.x) >> 6;
    if (wid >= N) return;
    const int lane = threadIdx.x & 63;
    const int h = lane >> 4;
    const size_t E4 = (size_t)E * 4;
    float m = -1e30f, den = 0.f;
    if (blockIdx.y == 0) {
        const f16x4 qv = *(const f16x4*)&qe[(size_t)wid * 256 + lane * 4];
        score_rel(qv, kA0, colsrc, rp[wid], rp[wid + 1],
                  muL[0 * 4 + h] * 0.125f, sc, lane, h, m, den);
        const int* rp2 = rp + 2 * (N + 1);
        score_rel(qv, kA2, colsrc + 2 * (size_t)E, rp2[wid], rp2[wid + 1],
                  muL[2 * 4 + h] * 0.125f, sc + 2 * E4, lane, h, m, den);
        if ((lane & 15) == 0) {
            mx_e[(size_t)wid * 4 + h] = m;
            den_e[(size_t)wid * 4 + h] = den;
        }
    } else {
        const f16x4 qv = *(const f16x4*)&qs[(size_t)wid * 256 + lane * 4];
        const int* rp1 = rp + (N + 1);
        score_rel(qv, kA1, colsrc + (size_t)E, rp1[wid], rp1[wid + 1],
                  muL[1 * 4 + h] * 0.125f, sc + E4, lane, h, m, den);
        if ((lane & 15) == 0) {
            mx_s[(size_t)wid * 4 + h] = m;
            den_s[(size_t)wid * 4 + h] = den;
        }
    }
}

// ---------------------------------------------------------------------------
// Fused aggregation: weights from stored scores + (mx, den); gather vM rows;
// gelu; store fp16. grid.y: 0 = expr (rel0+rel2) -> outE, 1 = stmt -> outS.
// ---------------------------------------------------------------------------
__device__ __forceinline__ void agg_rel(const float* __restrict__ sc,
                                        const _Float16* __restrict__ vM,
                                        const int* __restrict__ cs, int beg,
                                        int end, float m, float dinv, int lane,
                                        int h, float4& acc) {
    int i = beg;
    for (; i + 1 < end; i += 2) {
        const int sA = cs[i], sB = cs[i + 1];
        const float w0 = expf(sc[(size_t)i * 4 + h] - m) * dinv;
        const float w1 = expf(sc[(size_t)(i + 1) * 4 + h] - m) * dinv;
        const f16x4 v0 = *(const f16x4*)&vM[(size_t)sA * 256 + lane * 4];
        const f16x4 v1 = *(const f16x4*)&vM[(size_t)sB * 256 + lane * 4];
        acc.x += w0 * (float)v0[0] + w1 * (float)v1[0];
        acc.y += w0 * (float)v0[1] + w1 * (float)v1[1];
        acc.z += w0 * (float)v0[2] + w1 * (float)v1[2];
        acc.w += w0 * (float)v0[3] + w1 * (float)v1[3];
    }
    if (i < end) {
        const int sA = cs[i];
        const float w0 = expf(sc[(size_t)i * 4 + h] - m) * dinv;
        const f16x4 v0 = *(const f16x4*)&vM[(size_t)sA * 256 + lane * 4];
        acc.x += w0 * (float)v0[0]; acc.y += w0 * (float)v0[1];
        acc.z += w0 * (float)v0[2]; acc.w += w0 * (float)v0[3];
    }
}

__global__ __launch_bounds__(256) void agg3_k(
    const float* __restrict__ sc, const _Float16* __restrict__ vM0,
    const _Float16* __restrict__ vM1, const _Float16* __restrict__ vM2,
    const int* __restrict__ rp, const int* __restrict__ colsrc,
    const float* __restrict__ mx_e, const float* __restrict__ den_e,
    const float* __restrict__ mx_s, const float* __restrict__ den_s,
    _Float16* __restrict__ outE, _Float16* __restrict__ outS, int N, int E) {
    const int wid = (blockIdx.x * blockDim.x + threadIdx.x) >> 6;
    if (wid >= N) return;
    const int lane = threadIdx.x & 63;
    const int h = lane >> 4;
    const size_t E4 = (size_t)E * 4;
    float4 acc = make_float4(0.f, 0.f, 0.f, 0.f);
    if (blockIdx.y == 0) {
        const float m = mx_e[(size_t)wid * 4 + h];
        const float dinv = 1.0f / (den_e[(size_t)wid * 4 + h] + 1e-16f);
        agg_rel(sc, vM0, colsrc, rp[wid], rp[wid + 1], m, dinv, lane, h, acc);
        const int* rp2 = rp + 2 * (N + 1);
        agg_rel(sc + 2 * E4, vM2, colsrc + 2 * (size_t)E, rp2[wid],
                rp2[wid + 1], m, dinv, lane, h, acc);
        f16x4 o;
        o[0] = (_Float16)gelu_f(acc.x); o[1] = (_Float16)gelu_f(acc.y);
        o[2] = (_Float16)gelu_f(acc.z); o[3] = (_Float16)gelu_f(acc.w);
        *(f16x4*)&outE[(size_t)wid * 256 + lane * 4] = o;
    } else {
        const float m = mx_s[(size_t)wid * 4 + h];
        const float dinv = 1.0f / (den_s[(size_t)wid * 4 + h] + 1e-16f);
        const int* rp1 = rp + (N + 1);
        agg_rel(sc + E4, vM1, colsrc + (size_t)E, rp1[wid], rp1[wid + 1], m,
                dinv, lane, h, acc);
        f16x4 o;
        o[0] = (_Float16)gelu_f(acc.x); o[1] = (_Float16)gelu_f(acc.y);
        o[2] = (_Float16)gelu_f(acc.z); o[3] = (_Float16)gelu_f(acc.w);
        *(f16x4*)&outS[(size_t)wid * 256 + lane * 4] = o;
    }
}

// ---------------------------------------------------------------------------
// Batched head epilogue: t is [N][896]; head k uses cols k*128..k*128+127.
// ---------------------------------------------------------------------------
__global__ __launch_bounds__(256) void head2_k(const _Float16* __restrict__ t,
                                               const float* __restrict__ Wt2,
                                               const float* __restrict__ bt2,
                                               float* __restrict__ out, int M) {
    const int k = blockIdx.y;
    __shared__ float Ws[128 * 8];
    __shared__ float bs[8];
    const int tid = threadIdx.x;
    const float* W2 = Wt2 + (size_t)k * 1024;
    for (int i = tid; i < 1024; i += 256) Ws[i] = W2[i];
    if (tid < 8) bs[tid] = bt2[k * 8 + tid];
    __syncthreads();
    const int OFFA[7] = {0, 3, 6, 9, 14, 15, 16};
    const int DIMSA[7] = {3, 3, 3, 5, 1, 1, 8};
    const int nl = tid >> 3, o = tid & 7;
    const int n = blockIdx.x * 32 + nl;
    if (n >= M) return;
    const _Float16* tr = &t[(size_t)n * 896 + k * 128];
    float acc = bs[o];
#pragma unroll 8
    for (int d = 0; d < 128; ++d) acc += (float)tr[d] * Ws[d * 8 + o];
    if (o < DIMSA[k]) out[(size_t)n * 24 + OFFA[k] + o] = acc;
}

// ---------------------------------------------------------------------------

extern "C" void kernel_launch(void* const* d_in, const int* in_sizes, int n_in,
                              void* d_out, int out_size, void* d_ws,
                              size_t ws_size, hipStream_t stream) {
    const float* xe_in = (const float*)d_in[0];
    const float* xs_in = (const float*)d_in[1];
    const int* ee_src = (const int*)d_in[2];
    const int* ee_dst = (const int*)d_in[3];
    const int* es_src = (const int*)d_in[4];
    const int* es_dst = (const int*)d_in[5];
    const int* se_src = (const int*)d_in[6];
    const int* se_dst = (const int*)d_in[7];
    const float* Wk = (const float*)d_in[8];
    const float* Wq = (const float*)d_in[9];
    const float* Wv = (const float*)d_in[10];
    const float* Wa = (const float*)d_in[11];
    const float* skip = (const float*)d_in[12];
    const float* Arel = (const float*)d_in[13];
    const float* Mrel = (const float*)d_in[14];
    const float* mu = (const float*)d_in[15];
    const float* Wsh = (const float*)d_in[16];
    const float* bsh = (const float*)d_in[17];
    const float* Wt1 = (const float*)d_in[18];
    const float* bt1 = (const float*)d_in[19];
    const float* Wt2 = (const float*)d_in[20];
    const float* bt2 = (const float*)d_in[21];
    float* out = (float*)d_out;

    const int N = in_sizes[0] / CDIM;  // 50000
    const int E = in_sizes[2];         // 200000
    const size_t NC = (size_t)N * CDIM;
    const size_t E4 = (size_t)E * 4;
    const size_t N4 = (size_t)N * 4;

    const size_t halfs = 7 * NC + 32 * (size_t)AR_R + 7 * 32768;
    const size_t floats = 3 * E4 + 4 * N4;
    const size_t ints = 3 * (size_t)(N + 1) + 3 * (size_t)E + 3 * (size_t)N;
    const size_t need = halfs * 2 + floats * 4 + ints * 4;
    if (ws_size < need) return;

    _Float16* xeH = (_Float16*)d_ws;
    _Float16* xsH = xeH + NC;
    _Float16* Hb = xsH + NC;  // H1..H5 contiguous
    _Float16* H1 = Hb;
    _Float16* H2 = Hb + NC;
    _Float16* H3 = Hb + 2 * NC;
    _Float16* H4 = Hb + 3 * NC;
    _Float16* H5 = Hb + 4 * NC;
    _Float16* arena = Hb + 5 * NC;                // 30 blocks
    _Float16* SA = arena + (size_t)30 * AR_R;     // 2 blocks
    _Float16* HA = SA + (size_t)2 * AR_R;         // 7*128 rows
    float* sc = (float*)(HA + (size_t)7 * 32768); // [3][E*4]
    float* mx_e = sc + 3 * E4;
    float* den_e = mx_e + N4;
    float* mx_s = den_e + N4;
    float* den_s = mx_s + N4;
    int* rp = (int*)(den_s + N4);
    int* colsrc = rp + 3 * (size_t)(N + 1);
    int* cnt = colsrc + 3 * (size_t)E;

    const int gx = (N + 127) / 128;
    const dim3 e3((E + 255) / 256, 3);
    const int wave_blocks = (N + 3) / 4;
    const int zc_blocks = (3 * N + 255) / 256;

    // ---- CSR build ----
    zero_k<<<zc_blocks, 256, 0, stream>>>(cnt, 3 * (size_t)N);
    hist3_k<<<e3, 256, 0, stream>>>(ee_dst, es_dst, se_dst, cnt, N, E);
    scan3_k<<<dim3(1, 3), 1024, 0, stream>>>(cnt, rp, N);
    zero_k<<<zc_blocks, 256, 0, stream>>>(cnt, 3 * (size_t)N);
    scatter3_k<<<e3, 256, 0, stream>>>(ee_dst, es_dst, se_dst, ee_src, es_src,
                                       se_src, rp, cnt, colsrc, N, E);

    // ---- weight prep ----
    for (int l = 0; l < 3; ++l)
        prep_layer_k<<<dim3(256, 10), 256, 0, stream>>>(Wk, Wq, Wv, Wa, Arel,
                                                        Mrel, l, arena);
    prep_stack_k<<<dim3(256, 2), 256, 0, stream>>>(Wsh, SA);
    prep_heads_k<<<dim3(128, 7), 256, 0, stream>>>(Wt1, HA);

    // ---- initial fp16 activations ----
    cvt_k<<<1024, 256, 0, stream>>>(xe_in, xeH, NC / 4);
    cvt_k<<<1024, 256, 0, stream>>>(xs_in, xsH, NC / 4);

    for (int l = 0; l < 3; ++l) {
        _Float16* L = arena + (size_t)l * 10 * AR_R;
        // projections (pre-update states)
        gemm_h<0, true><<<dim3(gx, 6), 256, 0, stream>>>(
            xeH, L, H1, N, 768, NC, nullptr, nullptr);  // q_e|kA0|kA1
        gemm_h<0, true><<<dim3(gx, 4), 256, 0, stream>>>(
            xsH, L + 3 * AR_R, H4, N, 512, NC, nullptr, nullptr);  // q_s|kA2
        score3_k<<<dim3(wave_blocks, 2), 256, 0, stream>>>(
            H1, H2, H3, H4, H5, rp, colsrc, mu + l * 12, sc, mx_e, den_e, mx_s,
            den_s, N, E);
        gemm_h<0, true><<<dim3(gx, 4), 256, 0, stream>>>(
            xeH, L + 5 * AR_R, H2, N, 512, NC, nullptr, nullptr);  // vM0|vM1
        gemm_h<0, false><<<dim3(gx, 2), 256, 0, stream>>>(
            xsH, L + 7 * AR_R, H5, N, 256, 0, nullptr, nullptr);  // vM2
        agg3_k<<<dim3(wave_blocks, 2), 256, 0, stream>>>(
            sc, H2, H3, H5, rp, colsrc, mx_e, den_e, mx_s, den_s, H1, H4, N, E);
        update2_k<<<dim3(gx, 4), 256, 0, stream>>>(
            H1, H4, L + 8 * AR_R, L + 9 * AR_R, xeH, xsH, skip + l * 2, N);
    }

    // shared linear stack
    gemm_h<2, false><<<dim3(gx, 2), 256, 0, stream>>>(xeH, SA, H5, N, 256, 0,
                                                      bsh, nullptr);
    gemm_h<2, false><<<dim3(gx, 2), 256, 0, stream>>>(H5, SA + AR_R, xsH, N,
                                                      256, 0, bsh + 256, nullptr);
    // 7 task heads: fused GEMM into [N][896], then batched epilogue
    gemm_h<2, false><<<dim3(gx, 7), 256, 0, stream>>>(xsH, HA, Hb, N, 896, 0,
                                                      bt1, nullptr);
    head2_k<<<dim3((N + 31) / 32, 7), 256, 0, stream>>>(Hb, Wt2, bt2, out, N);
}

// Round 8
// 1250.640 us; speedup vs baseline: 8.2556x; 1.0247x over previous
//
#include <hip/hip_runtime.h>
#include <hip/hip_fp16.h>
#include <cmath>

// ---------------------------------------------------------------------------
// DragonHGT R8: fp16 MFMA GEMMs (BK=64, XOR-swizzled LDS) + CSR edge pipeline
// (fdot2 scoring w/ max-only online stats; den computed lanes-split in agg).
// N=50000 x 2 node types, E=200000 x 3 relations, C=256 (H=4, D=64).
// ---------------------------------------------------------------------------

#define CDIM 256
#define AR_R (256 * 256)

using f16x8 = __attribute__((ext_vector_type(8))) _Float16;
using f16x4 = __attribute__((ext_vector_type(4))) _Float16;
using f16x2 = __attribute__((ext_vector_type(2))) _Float16;
using f32x4 = __attribute__((ext_vector_type(4))) float;

__device__ __forceinline__ float gelu_f(float x) {
    return 0.5f * x * (1.0f + erff(x * 0.70710678118654752f));
}

__device__ __forceinline__ float dot4f(const f16x4 a, const f16x4 b) {
#if __has_builtin(__builtin_amdgcn_fdot2)
    f16x2 al = {a[0], a[1]}, ah = {a[2], a[3]};
    f16x2 bl = {b[0], b[1]}, bh = {b[2], b[3]};
    float r = __builtin_amdgcn_fdot2(al, bl, 0.0f, false);
    return __builtin_amdgcn_fdot2(ah, bh, r, false);
#else
    return (float)a[0] * (float)b[0] + (float)a[1] * (float)b[1] +
           (float)a[2] * (float)b[2] + (float)a[3] * (float)b[3];
#endif
}

__global__ __launch_bounds__(256) void zero_k(int* __restrict__ p, size_t n) {
    size_t i = (size_t)blockIdx.x * blockDim.x + threadIdx.x;
    const size_t stride = (size_t)gridDim.x * blockDim.x;
    for (; i < n; i += stride) p[i] = 0;
}

__global__ __launch_bounds__(256) void cvt_k(const float* __restrict__ in,
                                             _Float16* __restrict__ out,
                                             size_t n4) {
    size_t i = (size_t)blockIdx.x * blockDim.x + threadIdx.x;
    const size_t stride = (size_t)gridDim.x * blockDim.x;
    for (; i < n4; i += stride) {
        const float4 v = ((const float4*)in)[i];
        f16x4 o;
        o[0] = (_Float16)v.x; o[1] = (_Float16)v.y;
        o[2] = (_Float16)v.z; o[3] = (_Float16)v.w;
        ((f16x4*)out)[i] = o;
    }
}

// ---------------------------------------------------------------------------
// Weight prep.
// ---------------------------------------------------------------------------
__device__ __forceinline__ void cvtT_dev(const float* __restrict__ W,
                                         _Float16* __restrict__ dst) {
    const int o = blockIdx.x, c = threadIdx.x;
    dst[(size_t)o * 256 + c] = (_Float16)W[(size_t)c * 256 + o];
}

__device__ __forceinline__ void foldT_dev(const float* __restrict__ Wbase,
                                          const float* __restrict__ T,
                                          _Float16* __restrict__ dst) {
    __shared__ float row[256];
    const int c = blockIdx.x, t = threadIdx.x;
    row[t] = Wbase[(size_t)c * 256 + t];
    __syncthreads();
    const int h = t >> 6, f = t & 63;
    const float* Th = T + h * 4096;
    float acc = 0.f;
#pragma unroll 8
    for (int d = 0; d < 64; ++d) acc += row[h * 64 + d] * Th[d * 64 + f];
    dst[(size_t)t * 256 + c] = (_Float16)acc;
}

// arena per layer: q_e|kA0|kA1 | q_s|kA2 | vM0|vM1 | vM2 | WaT0|WaT1
__global__ __launch_bounds__(256) void prep_layer_k(
    const float* __restrict__ Wk, const float* __restrict__ Wq,
    const float* __restrict__ Wv, const float* __restrict__ Wa,
    const float* __restrict__ Arel, const float* __restrict__ Mrel, int l,
    _Float16* __restrict__ arena) {
    const size_t CC = 65536, HDD = 16384;
    _Float16* L = arena + (size_t)l * 10 * AR_R;
    const float* Wk0 = Wk + (l * 2 + 0) * CC;
    const float* Wk1 = Wk + (l * 2 + 1) * CC;
    const float* Wv0 = Wv + (l * 2 + 0) * CC;
    const float* Wv1 = Wv + (l * 2 + 1) * CC;
    switch (blockIdx.y) {
        case 0: cvtT_dev(Wq + (l * 2 + 0) * CC, L); break;
        case 1: foldT_dev(Wk0, Arel + (l * 3 + 0) * HDD, L + 1 * AR_R); break;
        case 2: foldT_dev(Wk0, Arel + (l * 3 + 1) * HDD, L + 2 * AR_R); break;
        case 3: cvtT_dev(Wq + (l * 2 + 1) * CC, L + 3 * AR_R); break;
        case 4: foldT_dev(Wk1, Arel + (l * 3 + 2) * HDD, L + 4 * AR_R); break;
        case 5: foldT_dev(Wv0, Mrel + (l * 3 + 0) * HDD, L + 5 * AR_R); break;
        case 6: foldT_dev(Wv0, Mrel + (l * 3 + 1) * HDD, L + 6 * AR_R); break;
        case 7: foldT_dev(Wv1, Mrel + (l * 3 + 2) * HDD, L + 7 * AR_R); break;
        case 8: cvtT_dev(Wa + (l * 2 + 0) * CC, L + 8 * AR_R); break;
        case 9: cvtT_dev(Wa + (l * 2 + 1) * CC, L + 9 * AR_R); break;
    }
}

__global__ __launch_bounds__(256) void prep_stack_k(const float* __restrict__ Wsh,
                                                    _Float16* __restrict__ SA) {
    cvtT_dev(Wsh + (size_t)blockIdx.y * 65536, SA + (size_t)blockIdx.y * AR_R);
}

__global__ __launch_bounds__(256) void prep_heads_k(const float* __restrict__ Wt1,
                                                    _Float16* __restrict__ HA) {
    const int o = blockIdx.x, k = blockIdx.y, c = threadIdx.x;
    HA[(size_t)(k * 128 + o) * 256 + c] =
        (_Float16)Wt1[(size_t)k * 256 * 128 + (size_t)c * 128 + o];
}

// ---------------------------------------------------------------------------
// fp16 MFMA GEMM body: C = A[M,256] @ Bt[Nc,256]^T. 128x128 tile, 4 waves,
// BK=64, linear LDS [128][64] halfs (128B rows) with byte ^= (row&7)<<4
// swizzle on write and read (2 lanes/bank per phase = conflict-free).
// ---------------------------------------------------------------------------
template <int EPI, bool SPLIT>
__device__ __forceinline__ void gemm_body(
    const _Float16* __restrict__ A, const _Float16* __restrict__ Bt,
    _Float16* __restrict__ C, int M, int Nc, int bn, size_t bufStride,
    const float* __restrict__ bias, const float* __restrict__ skipv,
    _Float16* As, _Float16* Bs) {
    const int tid = threadIdx.x;
    const int bm = blockIdx.x * 128;
    const int wave = tid >> 6, lane = tid & 63;
    const int wm = (wave >> 1) * 64, wn = (wave & 1) * 64;
    const int l15 = lane & 15, g = lane >> 4;
    const int srow = tid >> 3;           // 0..31
    const int sbyte = (tid & 7) * 16;    // byte col 0..112

    f32x4 acc[4][4] = {};

    for (int k0 = 0; k0 < 256; k0 += 64) {
        __syncthreads();
#pragma unroll
        for (int p = 0; p < 4; ++p) {
            const int r = p * 32 + srow;
            int gr = bm + r; if (gr >= M) gr = M - 1;
            const f16x8 av = *(const f16x8*)((const char*)A +
                                             ((size_t)gr * 256 + k0) * 2 + sbyte);
            const f16x8 bv = *(const f16x8*)((const char*)Bt +
                                             ((size_t)(bn + r) * 256 + k0) * 2 + sbyte);
            const int wb = sbyte ^ ((r & 7) << 4);
            *(f16x8*)((char*)As + r * 128 + wb) = av;
            *(f16x8*)((char*)Bs + r * 128 + wb) = bv;
        }
        __syncthreads();
#pragma unroll
        for (int sub = 0; sub < 2; ++sub) {
            f16x8 af[4], bf[4];
#pragma unroll
            for (int i = 0; i < 4; ++i) {
                const int ra = wm + i * 16 + l15;
                const int rb = wn + i * 16 + l15;
                const int ka = (sub * 64 + g * 16) ^ ((ra & 7) << 4);
                const int kb = (sub * 64 + g * 16) ^ ((rb & 7) << 4);
                af[i] = *(const f16x8*)((const char*)As + ra * 128 + ka);
                bf[i] = *(const f16x8*)((const char*)Bs + rb * 128 + kb);
            }
#pragma unroll
            for (int mi = 0; mi < 4; ++mi)
#pragma unroll
                for (int ni = 0; ni < 4; ++ni)
                    acc[mi][ni] = __builtin_amdgcn_mfma_f32_16x16x32_f16(
                        af[mi], bf[ni], acc[mi][ni], 0, 0, 0);
        }
    }

    float be = 0.f, ombe = 0.f;
    if (EPI == 1) {
        const float s = skipv[0];
        be = 1.0f / (1.0f + expf(-s));
        ombe = 1.0f - be;
    }
#pragma unroll
    for (int mi = 0; mi < 4; ++mi) {
#pragma unroll
        for (int r = 0; r < 4; ++r) {
            const int row = bm + wm + mi * 16 + g * 4 + r;
            if (row >= M) continue;
#pragma unroll
            for (int ni = 0; ni < 4; ++ni) {
                const int colg = bn + wn + ni * 16 + l15;
                float v = acc[mi][ni][r];
                size_t idx;
                if (SPLIT)
                    idx = (size_t)(colg >> 8) * bufStride + (size_t)row * 256 +
                          (colg & 255);
                else
                    idx = (size_t)row * Nc + colg;
                if (EPI == 1) v = be * v + ombe * (float)C[idx];
                if (EPI == 2) v = fmaxf(v + bias[colg], 0.f);
                C[idx] = (_Float16)v;
            }
        }
    }
}

template <int EPI, bool SPLIT>
__global__ __launch_bounds__(256) void gemm_h(
    const _Float16* __restrict__ A, const _Float16* __restrict__ Bt,
    _Float16* __restrict__ C, int M, int Nc, size_t bufStride,
    const float* __restrict__ bias, const float* __restrict__ skipv) {
    __shared__ _Float16 As[128 * 64];
    __shared__ _Float16 Bs[128 * 64];
    gemm_body<EPI, SPLIT>(A, Bt, C, M, Nc, blockIdx.y * 128, bufStride, bias,
                          skipv, As, Bs);
}

// Fused skip-updates: y>>1==0 -> xe; ==1 -> xs.
__global__ __launch_bounds__(256) void update2_k(
    const _Float16* __restrict__ aggE, const _Float16* __restrict__ aggS,
    const _Float16* __restrict__ WaT0, const _Float16* __restrict__ WaT1,
    _Float16* __restrict__ xeH, _Float16* __restrict__ xsH,
    const float* __restrict__ skipb, int M) {
    __shared__ _Float16 As[128 * 64];
    __shared__ _Float16 Bs[128 * 64];
    const int sel = blockIdx.y >> 1;
    const int bn = (blockIdx.y & 1) * 128;
    if (sel == 0)
        gemm_body<1, false>(aggE, WaT0, xeH, M, 256, bn, 0, nullptr, skipb, As, Bs);
    else
        gemm_body<1, false>(aggS, WaT1, xsH, M, 256, bn, 0, nullptr, skipb + 1, As, Bs);
}

// ---------------------------------------------------------------------------
// CSR build: rp + colsrc.
// ---------------------------------------------------------------------------
__global__ __launch_bounds__(256) void hist3_k(const int* __restrict__ d0,
                                               const int* __restrict__ d1,
                                               const int* __restrict__ d2,
                                               int* __restrict__ cnt, int N,
                                               int E) {
    const int i = blockIdx.x * 256 + threadIdx.x;
    if (i >= E) return;
    const int r = blockIdx.y;
    const int* d = r == 0 ? d0 : r == 1 ? d1 : d2;
    atomicAdd(&cnt[(size_t)r * N + d[i]], 1);
}

__global__ __launch_bounds__(1024) void scan3_k(const int* __restrict__ cnt,
                                                int* __restrict__ rp, int N) {
    __shared__ int sums[1024];
    const int r = blockIdx.y;
    const int* c = cnt + (size_t)r * N;
    int* o = rp + (size_t)r * (N + 1);
    const int tid = threadIdx.x;
    const int chunk = (N + 1023) / 1024;
    const int lo = min(tid * chunk, N), hi = min(lo + chunk, N);
    int s = 0;
    for (int i = lo; i < hi; ++i) s += c[i];
    sums[tid] = s;
    __syncthreads();
    for (int off = 1; off < 1024; off <<= 1) {
        const int v = (tid >= off) ? sums[tid - off] : 0;
        __syncthreads();
        sums[tid] += v;
        __syncthreads();
    }
    int run = (tid == 0) ? 0 : sums[tid - 1];
    for (int i = lo; i < hi; ++i) { o[i] = run; run += c[i]; }
    if (tid == 1023) o[N] = run;
}

__global__ __launch_bounds__(256) void scatter3_k(
    const int* __restrict__ d0, const int* __restrict__ d1,
    const int* __restrict__ d2, const int* __restrict__ s0_,
    const int* __restrict__ s1_, const int* __restrict__ s2_,
    const int* __restrict__ rp, int* __restrict__ fill,
    int* __restrict__ colsrc, int N, int E) {
    const int i = blockIdx.x * 256 + threadIdx.x;
    if (i >= E) return;
    const int r = blockIdx.y;
    const int* d = r == 0 ? d0 : r == 1 ? d1 : d2;
    const int* s = r == 0 ? s0_ : r == 1 ? s1_ : s2_;
    const int dd = d[i];
    const int p = rp[(size_t)r * (N + 1) + dd] + atomicAdd(&fill[(size_t)r * N + dd], 1);
    colsrc[(size_t)r * E + p] = s[i];
}

// ---------------------------------------------------------------------------
// Scoring: one wave per dst node; fdot2 dots; online MAX only (no exp chain).
// grid.y: 0 = expr (rel0 + rel2), 1 = stmt (rel1).
// ---------------------------------------------------------------------------
__device__ __forceinline__ void score_rel(
    const f16x4 qv, const _Float16* __restrict__ kA,
    const int* __restrict__ cs, int beg, int end, float scale,
    float* __restrict__ sc, int lane, int h, float& m) {
    int i = beg;
    for (; i + 1 < end; i += 2) {
        const int sA = cs[i], sB = cs[i + 1];
        const f16x4 k0 = *(const f16x4*)&kA[(size_t)sA * 256 + lane * 4];
        const f16x4 k1 = *(const f16x4*)&kA[(size_t)sB * 256 + lane * 4];
        float p0 = dot4f(qv, k0), p1 = dot4f(qv, k1);
        p0 += __shfl_xor(p0, 1); p1 += __shfl_xor(p1, 1);
        p0 += __shfl_xor(p0, 2); p1 += __shfl_xor(p1, 2);
        p0 += __shfl_xor(p0, 4); p1 += __shfl_xor(p1, 4);
        p0 += __shfl_xor(p0, 8); p1 += __shfl_xor(p1, 8);
        const float v0 = p0 * scale, v1 = p1 * scale;
        if ((lane & 15) == 0) {
            sc[(size_t)i * 4 + h] = v0;
            sc[(size_t)(i + 1) * 4 + h] = v1;
        }
        m = fmaxf(m, fmaxf(v0, v1));
    }
    if (i < end) {
        const int sA = cs[i];
        const f16x4 k0 = *(const f16x4*)&kA[(size_t)sA * 256 + lane * 4];
        float p0 = dot4f(qv, k0);
        p0 += __shfl_xor(p0, 1); p0 += __shfl_xor(p0, 2);
        p0 += __shfl_xor(p0, 4); p0 += __shfl_xor(p0, 8);
        const float v0 = p0 * scale;
        if ((lane & 15) == 0) sc[(size_t)i * 4 + h] = v0;
        m = fmaxf(m, v0);
    }
}

__global__ __launch_bounds__(256) void score3_k(
    const _Float16* __restrict__ qe, const _Float16* __restrict__ kA0,
    const _Float16* __restrict__ kA1, const _Float16* __restrict__ qs,
    const _Float16* __restrict__ kA2, const int* __restrict__ rp,
    const int* __restrict__ colsrc, const float* __restrict__ muL,
    float* __restrict__ sc, float* __restrict__ mx_e,
    float* __restrict__ mx_s, int N, int E) {
    const int wid = (blockIdx.x * blockDim.x + threadIdx.x) >> 6;
    if (wid >= N) return;
    const int lane = threadIdx.x & 63;
    const int h = lane >> 4;
    const size_t E4 = (size_t)E * 4;
    float m = -1e30f;
    if (blockIdx.y == 0) {
        const f16x4 qv = *(const f16x4*)&qe[(size_t)wid * 256 + lane * 4];
        score_rel(qv, kA0, colsrc, rp[wid], rp[wid + 1],
                  muL[0 * 4 + h] * 0.125f, sc, lane, h, m);
        const int* rp2 = rp + 2 * (N + 1);
        score_rel(qv, kA2, colsrc + 2 * (size_t)E, rp2[wid], rp2[wid + 1],
                  muL[2 * 4 + h] * 0.125f, sc + 2 * E4, lane, h, m);
        if ((lane & 15) == 0) mx_e[(size_t)wid * 4 + h] = m;
    } else {
        const f16x4 qv = *(const f16x4*)&qs[(size_t)wid * 256 + lane * 4];
        const int* rp1 = rp + (N + 1);
        score_rel(qv, kA1, colsrc + (size_t)E, rp1[wid], rp1[wid + 1],
                  muL[1 * 4 + h] * 0.125f, sc + E4, lane, h, m);
        if ((lane & 15) == 0) mx_s[(size_t)wid * 4 + h] = m;
    }
}

// ---------------------------------------------------------------------------
// Aggregation: phase 1 computes den lanes-split (64 lanes cover 16 edges x
// 4 heads); phase 2 gathers vM rows with softmax weights; gelu; fp16 store.
// grid.y: 0 = expr (rel0+rel2) -> outE, 1 = stmt -> outS.
// ---------------------------------------------------------------------------
__device__ __forceinline__ void agg_rel(const float* __restrict__ sc,
                                        const _Float16* __restrict__ vM,
                                        const int* __restrict__ cs, int beg,
                                        int end, float m, float dinv, int lane,
                                        int h, float4& acc) {
    int i = beg;
    for (; i + 1 < end; i += 2) {
        const int sA = cs[i], sB = cs[i + 1];
        const float w0 = expf(sc[(size_t)i * 4 + h] - m) * dinv;
        const float w1 = expf(sc[(size_t)(i + 1) * 4 + h] - m) * dinv;
        const f16x4 v0 = *(const f16x4*)&vM[(size_t)sA * 256 + lane * 4];
        const f16x4 v1 = *(const f16x4*)&vM[(size_t)sB * 256 + lane * 4];
        acc.x += w0 * (float)v0[0] + w1 * (float)v1[0];
        acc.y += w0 * (float)v0[1] + w1 * (float)v1[1];
        acc.z += w0 * (float)v0[2] + w1 * (float)v1[2];
        acc.w += w0 * (float)v0[3] + w1 * (float)v1[3];
    }
    if (i < end) {
        const int sA = cs[i];
        const float w0 = expf(sc[(size_t)i * 4 + h] - m) * dinv;
        const f16x4 v0 = *(const f16x4*)&vM[(size_t)sA * 256 + lane * 4];
        acc.x += w0 * (float)v0[0]; acc.y += w0 * (float)v0[1];
        acc.z += w0 * (float)v0[2]; acc.w += w0 * (float)v0[3];
    }
}

__global__ __launch_bounds__(256) void agg3_k(
    const float* __restrict__ sc, const _Float16* __restrict__ vM0,
    const _Float16* __restrict__ vM1, const _Float16* __restrict__ vM2,
    const int* __restrict__ rp, const int* __restrict__ colsrc,
    const float* __restrict__ mx_e, const float* __restrict__ mx_s,
    _Float16* __restrict__ outE, _Float16* __restrict__ outS, int N, int E) {
    const int wid = (blockIdx.x * blockDim.x + threadIdx.x) >> 6;
    if (wid >= N) return;
    const int lane = threadIdx.x & 63;
    const int hHi = lane >> 4, hLo = lane & 3, sl = lane >> 2;
    const size_t E4 = (size_t)E * 4;
    float4 acc = make_float4(0.f, 0.f, 0.f, 0.f);
    if (blockIdx.y == 0) {
        const float mLo = mx_e[(size_t)wid * 4 + hLo];
        const float mHi = mx_e[(size_t)wid * 4 + hHi];
        const int b0 = rp[wid], e0 = rp[wid + 1];
        const int* rp2 = rp + 2 * (N + 1);
        const int b2 = rp2[wid], e2 = rp2[wid + 1];
        const float* sc2 = sc + 2 * E4;
        float dl = 0.f;
        for (int i = b0 + sl; i < e0; i += 16)
            dl += expf(sc[(size_t)i * 4 + hLo] - mLo);
        for (int i = b2 + sl; i < e2; i += 16)
            dl += expf(sc2[(size_t)i * 4 + hLo] - mLo);
        dl += __shfl_xor(dl, 4); dl += __shfl_xor(dl, 8);
        dl += __shfl_xor(dl, 16); dl += __shfl_xor(dl, 32);
        const float dinv = 1.0f / (__shfl(dl, hHi) + 1e-16f);
        agg_rel(sc, vM0, colsrc, b0, e0, mHi, dinv, lane, hHi, acc);
        agg_rel(sc2, vM2, colsrc + 2 * (size_t)E, b2, e2, mHi, dinv, lane, hHi,
                acc);
        f16x4 o;
        o[0] = (_Float16)gelu_f(acc.x); o[1] = (_Float16)gelu_f(acc.y);
        o[2] = (_Float16)gelu_f(acc.z); o[3] = (_Float16)gelu_f(acc.w);
        *(f16x4*)&outE[(size_t)wid * 256 + lane * 4] = o;
    } else {
        const float mLo = mx_s[(size_t)wid * 4 + hLo];
        const float mHi = mx_s[(size_t)wid * 4 + hHi];
        const int* rp1 = rp + (N + 1);
        const int b1 = rp1[wid], e1 = rp1[wid + 1];
        const float* sc1 = sc + E4;
        float dl = 0.f;
        for (int i = b1 + sl; i < e1; i += 16)
            dl += expf(sc1[(size_t)i * 4 + hLo] - mLo);
        dl += __shfl_xor(dl, 4); dl += __shfl_xor(dl, 8);
        dl += __shfl_xor(dl, 16); dl += __shfl_xor(dl, 32);
        const float dinv = 1.0f / (__shfl(dl, hHi) + 1e-16f);
        agg_rel(sc1, vM1, colsrc + (size_t)E, b1, e1, mHi, dinv, lane, hHi,
                acc);
        f16x4 o;
        o[0] = (_Float16)gelu_f(acc.x); o[1] = (_Float16)gelu_f(acc.y);
        o[2] = (_Float16)gelu_f(acc.z); o[3] = (_Float16)gelu_f(acc.w);
        *(f16x4*)&outS[(size_t)wid * 256 + lane * 4] = o;
    }
}

// ---------------------------------------------------------------------------
// Batched head epilogue: t is [N][896]; head k uses cols k*128..k*128+127.
// ---------------------------------------------------------------------------
__global__ __launch_bounds__(256) void head2_k(const _Float16* __restrict__ t,
                                               const float* __restrict__ Wt2,
                                               const float* __restrict__ bt2,
                                               float* __restrict__ out, int M) {
    const int k = blockIdx.y;
    __shared__ float Ws[128 * 8];
    __shared__ float bs[8];
    const int tid = threadIdx.x;
    const float* W2 = Wt2 + (size_t)k * 1024;
    for (int i = tid; i < 1024; i += 256) Ws[i] = W2[i];
    if (tid < 8) bs[tid] = bt2[k * 8 + tid];
    __syncthreads();
    const int OFFA[7] = {0, 3, 6, 9, 14, 15, 16};
    const int DIMSA[7] = {3, 3, 3, 5, 1, 1, 8};
    const int nl = tid >> 3, o = tid & 7;
    const int n = blockIdx.x * 32 + nl;
    if (n >= M) return;
    const _Float16* tr = &t[(size_t)n * 896 + k * 128];
    float acc = bs[o];
#pragma unroll 8
    for (int d = 0; d < 128; ++d) acc += (float)tr[d] * Ws[d * 8 + o];
    if (o < DIMSA[k]) out[(size_t)n * 24 + OFFA[k] + o] = acc;
}

// ---------------------------------------------------------------------------

extern "C" void kernel_launch(void* const* d_in, const int* in_sizes, int n_in,
                              void* d_out, int out_size, void* d_ws,
                              size_t ws_size, hipStream_t stream) {
    const float* xe_in = (const float*)d_in[0];
    const float* xs_in = (const float*)d_in[1];
    const int* ee_src = (const int*)d_in[2];
    const int* ee_dst = (const int*)d_in[3];
    const int* es_src = (const int*)d_in[4];
    const int* es_dst = (const int*)d_in[5];
    const int* se_src = (const int*)d_in[6];
    const int* se_dst = (const int*)d_in[7];
    const float* Wk = (const float*)d_in[8];
    const float* Wq = (const float*)d_in[9];
    const float* Wv = (const float*)d_in[10];
    const float* Wa = (const float*)d_in[11];
    const float* skip = (const float*)d_in[12];
    const float* Arel = (const float*)d_in[13];
    const float* Mrel = (const float*)d_in[14];
    const float* mu = (const float*)d_in[15];
    const float* Wsh = (const float*)d_in[16];
    const float* bsh = (const float*)d_in[17];
    const float* Wt1 = (const float*)d_in[18];
    const float* bt1 = (const float*)d_in[19];
    const float* Wt2 = (const float*)d_in[20];
    const float* bt2 = (const float*)d_in[21];
    float* out = (float*)d_out;

    const int N = in_sizes[0] / CDIM;  // 50000
    const int E = in_sizes[2];         // 200000
    const size_t NC = (size_t)N * CDIM;
    const size_t E4 = (size_t)E * 4;
    const size_t N4 = (size_t)N * 4;

    const size_t halfs = 7 * NC + 32 * (size_t)AR_R + 7 * 32768;
    const size_t floats = 3 * E4 + 2 * N4;
    const size_t ints = 3 * (size_t)(N + 1) + 3 * (size_t)E + 3 * (size_t)N;
    const size_t need = halfs * 2 + floats * 4 + ints * 4;
    if (ws_size < need) return;

    _Float16* xeH = (_Float16*)d_ws;
    _Float16* xsH = xeH + NC;
    _Float16* Hb = xsH + NC;  // H1..H5 contiguous
    _Float16* H1 = Hb;
    _Float16* H2 = Hb + NC;
    _Float16* H3 = Hb + 2 * NC;
    _Float16* H4 = Hb + 3 * NC;
    _Float16* H5 = Hb + 4 * NC;
    _Float16* arena = Hb + 5 * NC;
    _Float16* SA = arena + (size_t)30 * AR_R;
    _Float16* HA = SA + (size_t)2 * AR_R;
    float* sc = (float*)(HA + (size_t)7 * 32768);
    float* mx_e = sc + 3 * E4;
    float* mx_s = mx_e + N4;
    int* rp = (int*)(mx_s + N4);
    int* colsrc = rp + 3 * (size_t)(N + 1);
    int* cnt = colsrc + 3 * (size_t)E;

    const int gx = (N + 127) / 128;
    const dim3 e3((E + 255) / 256, 3);
    const int wave_blocks = (N + 3) / 4;
    const int zc_blocks = (3 * N + 255) / 256;

    // ---- CSR build ----
    zero_k<<<zc_blocks, 256, 0, stream>>>(cnt, 3 * (size_t)N);
    hist3_k<<<e3, 256, 0, stream>>>(ee_dst, es_dst, se_dst, cnt, N, E);
    scan3_k<<<dim3(1, 3), 1024, 0, stream>>>(cnt, rp, N);
    zero_k<<<zc_blocks, 256, 0, stream>>>(cnt, 3 * (size_t)N);
    scatter3_k<<<e3, 256, 0, stream>>>(ee_dst, es_dst, se_dst, ee_src, es_src,
                                       se_src, rp, cnt, colsrc, N, E);

    // ---- weight prep ----
    for (int l = 0; l < 3; ++l)
        prep_layer_k<<<dim3(256, 10), 256, 0, stream>>>(Wk, Wq, Wv, Wa, Arel,
                                                        Mrel, l, arena);
    prep_stack_k<<<dim3(256, 2), 256, 0, stream>>>(Wsh, SA);
    prep_heads_k<<<dim3(128, 7), 256, 0, stream>>>(Wt1, HA);

    // ---- initial fp16 activations ----
    cvt_k<<<1024, 256, 0, stream>>>(xe_in, xeH, NC / 4);
    cvt_k<<<1024, 256, 0, stream>>>(xs_in, xsH, NC / 4);

    for (int l = 0; l < 3; ++l) {
        _Float16* L = arena + (size_t)l * 10 * AR_R;
        gemm_h<0, true><<<dim3(gx, 6), 256, 0, stream>>>(
            xeH, L, H1, N, 768, NC, nullptr, nullptr);  // q_e|kA0|kA1
        gemm_h<0, true><<<dim3(gx, 4), 256, 0, stream>>>(
            xsH, L + 3 * AR_R, H4, N, 512, NC, nullptr, nullptr);  // q_s|kA2
        score3_k<<<dim3(wave_blocks, 2), 256, 0, stream>>>(
            H1, H2, H3, H4, H5, rp, colsrc, mu + l * 12, sc, mx_e, mx_s, N, E);
        gemm_h<0, true><<<dim3(gx, 4), 256, 0, stream>>>(
            xeH, L + 5 * AR_R, H2, N, 512, NC, nullptr, nullptr);  // vM0|vM1
        gemm_h<0, false><<<dim3(gx, 2), 256, 0, stream>>>(
            xsH, L + 7 * AR_R, H5, N, 256, 0, nullptr, nullptr);  // vM2
        agg3_k<<<dim3(wave_blocks, 2), 256, 0, stream>>>(
            sc, H2, H3, H5, rp, colsrc, mx_e, mx_s, H1, H4, N, E);
        update2_k<<<dim3(gx, 4), 256, 0, stream>>>(
            H1, H4, L + 8 * AR_R, L + 9 * AR_R, xeH, xsH, skip + l * 2, N);
    }

    // shared linear stack
    gemm_h<2, false><<<dim3(gx, 2), 256, 0, stream>>>(xeH, SA, H5, N, 256, 0,
                                                      bsh, nullptr);
    gemm_h<2, false><<<dim3(gx, 2), 256, 0, stream>>>(H5, SA + AR_R, xsH, N,
                                                      256, 0, bsh + 256, nullptr);
    // 7 task heads
    gemm_h<2, false><<<dim3(gx, 7), 256, 0, stream>>>(xsH, HA, Hb, N, 896, 0,
                                                      bt1, nullptr);
    head2_k<<<dim3((N + 31) / 32, 7), 256, 0, stream>>>(Hb, Wt2, bt2, out, N);
}

// Round 9
// 1202.397 us; speedup vs baseline: 8.5869x; 1.0401x over previous
//
#include <hip/hip_runtime.h>
#include <hip/hip_fp16.h>
#include <cmath>

// ---------------------------------------------------------------------------
// DragonHGT R9: fp16 MFMA GEMMs (BK=64, XOR-swizzled LDS) + CSR edge pipeline
// with 16-lane-per-edge group scheme (4 edges in flight per wave).
// N=50000 x 2 node types, E=200000 x 3 relations, C=256 (H=4, D=64).
// ---------------------------------------------------------------------------

#define CDIM 256
#define AR_R (256 * 256)

using f16x8 = __attribute__((ext_vector_type(8))) _Float16;
using f16x4 = __attribute__((ext_vector_type(4))) _Float16;
using f16x2 = __attribute__((ext_vector_type(2))) _Float16;
using f32x4 = __attribute__((ext_vector_type(4))) float;

__device__ __forceinline__ float gelu_f(float x) {
    return 0.5f * x * (1.0f + erff(x * 0.70710678118654752f));
}

__device__ __forceinline__ float dot8f(const f16x8 a, const f16x8 b, float r) {
#if __has_builtin(__builtin_amdgcn_fdot2)
#pragma unroll
    for (int t = 0; t < 4; ++t) {
        f16x2 av = {a[2 * t], a[2 * t + 1]};
        f16x2 bv = {b[2 * t], b[2 * t + 1]};
        r = __builtin_amdgcn_fdot2(av, bv, r, false);
    }
#else
#pragma unroll
    for (int t = 0; t < 8; ++t) r += (float)a[t] * (float)b[t];
#endif
    return r;
}

__global__ __launch_bounds__(256) void zero_k(int* __restrict__ p, size_t n) {
    size_t i = (size_t)blockIdx.x * blockDim.x + threadIdx.x;
    const size_t stride = (size_t)gridDim.x * blockDim.x;
    for (; i < n; i += stride) p[i] = 0;
}

__global__ __launch_bounds__(256) void cvt_k(const float* __restrict__ in,
                                             _Float16* __restrict__ out,
                                             size_t n4) {
    size_t i = (size_t)blockIdx.x * blockDim.x + threadIdx.x;
    const size_t stride = (size_t)gridDim.x * blockDim.x;
    for (; i < n4; i += stride) {
        const float4 v = ((const float4*)in)[i];
        f16x4 o;
        o[0] = (_Float16)v.x; o[1] = (_Float16)v.y;
        o[2] = (_Float16)v.z; o[3] = (_Float16)v.w;
        ((f16x4*)out)[i] = o;
    }
}

// ---------------------------------------------------------------------------
// Weight prep.
// ---------------------------------------------------------------------------
__device__ __forceinline__ void cvtT_dev(const float* __restrict__ W,
                                         _Float16* __restrict__ dst) {
    const int o = blockIdx.x, c = threadIdx.x;
    dst[(size_t)o * 256 + c] = (_Float16)W[(size_t)c * 256 + o];
}

__device__ __forceinline__ void foldT_dev(const float* __restrict__ Wbase,
                                          const float* __restrict__ T,
                                          _Float16* __restrict__ dst) {
    __shared__ float row[256];
    const int c = blockIdx.x, t = threadIdx.x;
    row[t] = Wbase[(size_t)c * 256 + t];
    __syncthreads();
    const int h = t >> 6, f = t & 63;
    const float* Th = T + h * 4096;
    float acc = 0.f;
#pragma unroll 8
    for (int d = 0; d < 64; ++d) acc += row[h * 64 + d] * Th[d * 64 + f];
    dst[(size_t)t * 256 + c] = (_Float16)acc;
}

// arena per layer: q_e|kA0|kA1 | q_s|kA2 | vM0|vM1 | vM2 | WaT0|WaT1
__global__ __launch_bounds__(256) void prep_layer_k(
    const float* __restrict__ Wk, const float* __restrict__ Wq,
    const float* __restrict__ Wv, const float* __restrict__ Wa,
    const float* __restrict__ Arel, const float* __restrict__ Mrel, int l,
    _Float16* __restrict__ arena) {
    const size_t CC = 65536, HDD = 16384;
    _Float16* L = arena + (size_t)l * 10 * AR_R;
    const float* Wk0 = Wk + (l * 2 + 0) * CC;
    const float* Wk1 = Wk + (l * 2 + 1) * CC;
    const float* Wv0 = Wv + (l * 2 + 0) * CC;
    const float* Wv1 = Wv + (l * 2 + 1) * CC;
    switch (blockIdx.y) {
        case 0: cvtT_dev(Wq + (l * 2 + 0) * CC, L); break;
        case 1: foldT_dev(Wk0, Arel + (l * 3 + 0) * HDD, L + 1 * AR_R); break;
        case 2: foldT_dev(Wk0, Arel + (l * 3 + 1) * HDD, L + 2 * AR_R); break;
        case 3: cvtT_dev(Wq + (l * 2 + 1) * CC, L + 3 * AR_R); break;
        case 4: foldT_dev(Wk1, Arel + (l * 3 + 2) * HDD, L + 4 * AR_R); break;
        case 5: foldT_dev(Wv0, Mrel + (l * 3 + 0) * HDD, L + 5 * AR_R); break;
        case 6: foldT_dev(Wv0, Mrel + (l * 3 + 1) * HDD, L + 6 * AR_R); break;
        case 7: foldT_dev(Wv1, Mrel + (l * 3 + 2) * HDD, L + 7 * AR_R); break;
        case 8: cvtT_dev(Wa + (l * 2 + 0) * CC, L + 8 * AR_R); break;
        case 9: cvtT_dev(Wa + (l * 2 + 1) * CC, L + 9 * AR_R); break;
    }
}

__global__ __launch_bounds__(256) void prep_stack_k(const float* __restrict__ Wsh,
                                                    _Float16* __restrict__ SA) {
    cvtT_dev(Wsh + (size_t)blockIdx.y * 65536, SA + (size_t)blockIdx.y * AR_R);
}

__global__ __launch_bounds__(256) void prep_heads_k(const float* __restrict__ Wt1,
                                                    _Float16* __restrict__ HA) {
    const int o = blockIdx.x, k = blockIdx.y, c = threadIdx.x;
    HA[(size_t)(k * 128 + o) * 256 + c] =
        (_Float16)Wt1[(size_t)k * 256 * 128 + (size_t)c * 128 + o];
}

// ---------------------------------------------------------------------------
// fp16 MFMA GEMM body (BK=64, XOR-swizzled linear LDS). Same as R8.
// ---------------------------------------------------------------------------
template <int EPI, bool SPLIT>
__device__ __forceinline__ void gemm_body(
    const _Float16* __restrict__ A, const _Float16* __restrict__ Bt,
    _Float16* __restrict__ C, int M, int Nc, int bn, size_t bufStride,
    const float* __restrict__ bias, const float* __restrict__ skipv,
    _Float16* As, _Float16* Bs) {
    const int tid = threadIdx.x;
    const int bm = blockIdx.x * 128;
    const int wave = tid >> 6, lane = tid & 63;
    const int wm = (wave >> 1) * 64, wn = (wave & 1) * 64;
    const int l15 = lane & 15, g = lane >> 4;
    const int srow = tid >> 3;
    const int sbyte = (tid & 7) * 16;

    f32x4 acc[4][4] = {};

    for (int k0 = 0; k0 < 256; k0 += 64) {
        __syncthreads();
#pragma unroll
        for (int p = 0; p < 4; ++p) {
            const int r = p * 32 + srow;
            int gr = bm + r; if (gr >= M) gr = M - 1;
            const f16x8 av = *(const f16x8*)((const char*)A +
                                             ((size_t)gr * 256 + k0) * 2 + sbyte);
            const f16x8 bv = *(const f16x8*)((const char*)Bt +
                                             ((size_t)(bn + r) * 256 + k0) * 2 + sbyte);
            const int wb = sbyte ^ ((r & 7) << 4);
            *(f16x8*)((char*)As + r * 128 + wb) = av;
            *(f16x8*)((char*)Bs + r * 128 + wb) = bv;
        }
        __syncthreads();
#pragma unroll
        for (int sub = 0; sub < 2; ++sub) {
            f16x8 af[4], bf[4];
#pragma unroll
            for (int i = 0; i < 4; ++i) {
                const int ra = wm + i * 16 + l15;
                const int rb = wn + i * 16 + l15;
                const int ka = (sub * 64 + g * 16) ^ ((ra & 7) << 4);
                const int kb = (sub * 64 + g * 16) ^ ((rb & 7) << 4);
                af[i] = *(const f16x8*)((const char*)As + ra * 128 + ka);
                bf[i] = *(const f16x8*)((const char*)Bs + rb * 128 + kb);
            }
#pragma unroll
            for (int mi = 0; mi < 4; ++mi)
#pragma unroll
                for (int ni = 0; ni < 4; ++ni)
                    acc[mi][ni] = __builtin_amdgcn_mfma_f32_16x16x32_f16(
                        af[mi], bf[ni], acc[mi][ni], 0, 0, 0);
        }
    }

    float be = 0.f, ombe = 0.f;
    if (EPI == 1) {
        const float s = skipv[0];
        be = 1.0f / (1.0f + expf(-s));
        ombe = 1.0f - be;
    }
#pragma unroll
    for (int mi = 0; mi < 4; ++mi) {
#pragma unroll
        for (int r = 0; r < 4; ++r) {
            const int row = bm + wm + mi * 16 + g * 4 + r;
            if (row >= M) continue;
#pragma unroll
            for (int ni = 0; ni < 4; ++ni) {
                const int colg = bn + wn + ni * 16 + l15;
                float v = acc[mi][ni][r];
                size_t idx;
                if (SPLIT)
                    idx = (size_t)(colg >> 8) * bufStride + (size_t)row * 256 +
                          (colg & 255);
                else
                    idx = (size_t)row * Nc + colg;
                if (EPI == 1) v = be * v + ombe * (float)C[idx];
                if (EPI == 2) v = fmaxf(v + bias[colg], 0.f);
                C[idx] = (_Float16)v;
            }
        }
    }
}

template <int EPI, bool SPLIT>
__global__ __launch_bounds__(256) void gemm_h(
    const _Float16* __restrict__ A, const _Float16* __restrict__ Bt,
    _Float16* __restrict__ C, int M, int Nc, size_t bufStride,
    const float* __restrict__ bias, const float* __restrict__ skipv) {
    __shared__ _Float16 As[128 * 64];
    __shared__ _Float16 Bs[128 * 64];
    gemm_body<EPI, SPLIT>(A, Bt, C, M, Nc, blockIdx.y * 128, bufStride, bias,
                          skipv, As, Bs);
}

__global__ __launch_bounds__(256) void update2_k(
    const _Float16* __restrict__ aggE, const _Float16* __restrict__ aggS,
    const _Float16* __restrict__ WaT0, const _Float16* __restrict__ WaT1,
    _Float16* __restrict__ xeH, _Float16* __restrict__ xsH,
    const float* __restrict__ skipb, int M) {
    __shared__ _Float16 As[128 * 64];
    __shared__ _Float16 Bs[128 * 64];
    const int sel = blockIdx.y >> 1;
    const int bn = (blockIdx.y & 1) * 128;
    if (sel == 0)
        gemm_body<1, false>(aggE, WaT0, xeH, M, 256, bn, 0, nullptr, skipb, As, Bs);
    else
        gemm_body<1, false>(aggS, WaT1, xsH, M, 256, bn, 0, nullptr, skipb + 1, As, Bs);
}

// ---------------------------------------------------------------------------
// CSR build: rp + colsrc.
// ---------------------------------------------------------------------------
__global__ __launch_bounds__(256) void hist3_k(const int* __restrict__ d0,
                                               const int* __restrict__ d1,
                                               const int* __restrict__ d2,
                                               int* __restrict__ cnt, int N,
                                               int E) {
    const int i = blockIdx.x * 256 + threadIdx.x;
    if (i >= E) return;
    const int r = blockIdx.y;
    const int* d = r == 0 ? d0 : r == 1 ? d1 : d2;
    atomicAdd(&cnt[(size_t)r * N + d[i]], 1);
}

__global__ __launch_bounds__(1024) void scan3_k(const int* __restrict__ cnt,
                                                int* __restrict__ rp, int N) {
    __shared__ int sums[1024];
    const int r = blockIdx.y;
    const int* c = cnt + (size_t)r * N;
    int* o = rp + (size_t)r * (N + 1);
    const int tid = threadIdx.x;
    const int chunk = (N + 1023) / 1024;
    const int lo = min(tid * chunk, N), hi = min(lo + chunk, N);
    int s = 0;
    for (int i = lo; i < hi; ++i) s += c[i];
    sums[tid] = s;
    __syncthreads();
    for (int off = 1; off < 1024; off <<= 1) {
        const int v = (tid >= off) ? sums[tid - off] : 0;
        __syncthreads();
        sums[tid] += v;
        __syncthreads();
    }
    int run = (tid == 0) ? 0 : sums[tid - 1];
    for (int i = lo; i < hi; ++i) { o[i] = run; run += c[i]; }
    if (tid == 1023) o[N] = run;
}

__global__ __launch_bounds__(256) void scatter3_k(
    const int* __restrict__ d0, const int* __restrict__ d1,
    const int* __restrict__ d2, const int* __restrict__ s0_,
    const int* __restrict__ s1_, const int* __restrict__ s2_,
    const int* __restrict__ rp, int* __restrict__ fill,
    int* __restrict__ colsrc, int N, int E) {
    const int i = blockIdx.x * 256 + threadIdx.x;
    if (i >= E) return;
    const int r = blockIdx.y;
    const int* d = r == 0 ? d0 : r == 1 ? d1 : d2;
    const int* s = r == 0 ? s0_ : r == 1 ? s1_ : s2_;
    const int dd = d[i];
    const int p = rp[(size_t)r * (N + 1) + dd] + atomicAdd(&fill[(size_t)r * N + dd], 1);
    colsrc[(size_t)r * E + p] = s[i];
}

// ---------------------------------------------------------------------------
// Scoring: wave per dst; 16 lanes per edge, 4 edges in flight.
// Lane j (0..15) of group grp covers halfs j*16..j*16+15; head h = j>>2.
// Dot reduce = 2 shfl_xor within the 4-lane head slice.
// ---------------------------------------------------------------------------
__device__ __forceinline__ void score_rel_g(
    const f16x8 q0, const f16x8 q1, const _Float16* __restrict__ kA,
    const int* __restrict__ cs, int beg, int end, float scl,
    float* __restrict__ sc, int grp, int j, float& m) {
    for (int i = beg + grp; i < end; i += 4) {
        const int s = cs[i];
        const _Float16* row = &kA[(size_t)s * 256 + j * 16];
        const f16x8 k0 = *(const f16x8*)row;
        const f16x8 k1 = *(const f16x8*)(row + 8);
        float p = dot8f(q1, k1, dot8f(q0, k0, 0.f));
        p += __shfl_xor(p, 1);
        p += __shfl_xor(p, 2);
        const float v = p * scl;
        if ((j & 3) == 0) {
            sc[(size_t)i * 4 + (j >> 2)] = v;
            m = fmaxf(m, v);
        }
    }
}

__global__ __launch_bounds__(256) void score3_k(
    const _Float16* __restrict__ qe, const _Float16* __restrict__ kA0,
    const _Float16* __restrict__ kA1, const _Float16* __restrict__ qs,
    const _Float16* __restrict__ kA2, const int* __restrict__ rp,
    const int* __restrict__ colsrc, const float* __restrict__ muL,
    float* __restrict__ sc, float* __restrict__ mx_e,
    float* __restrict__ mx_s, int N, int E) {
    const int wid = (blockIdx.x * blockDim.x + threadIdx.x) >> 6;
    if (wid >= N) return;
    const int lane = threadIdx.x & 63;
    const int grp = lane >> 4, j = lane & 15, h = j >> 2;
    const size_t E4 = (size_t)E * 4;
    float m = -1e30f;
    if (blockIdx.y == 0) {
        const _Float16* qrow = &qe[(size_t)wid * 256 + j * 16];
        const f16x8 q0 = *(const f16x8*)qrow;
        const f16x8 q1 = *(const f16x8*)(qrow + 8);
        score_rel_g(q0, q1, kA0, colsrc, rp[wid], rp[wid + 1],
                    muL[0 * 4 + h] * 0.125f, sc, grp, j, m);
        const int* rp2 = rp + 2 * (N + 1);
        score_rel_g(q0, q1, kA2, colsrc + 2 * (size_t)E, rp2[wid], rp2[wid + 1],
                    muL[2 * 4 + h] * 0.125f, sc + 2 * E4, grp, j, m);
        m = fmaxf(m, __shfl_xor(m, 16));
        m = fmaxf(m, __shfl_xor(m, 32));
        if (grp == 0 && (j & 3) == 0) mx_e[(size_t)wid * 4 + h] = m;
    } else {
        const _Float16* qrow = &qs[(size_t)wid * 256 + j * 16];
        const f16x8 q0 = *(const f16x8*)qrow;
        const f16x8 q1 = *(const f16x8*)(qrow + 8);
        const int* rp1 = rp + (N + 1);
        score_rel_g(q0, q1, kA1, colsrc + (size_t)E, rp1[wid], rp1[wid + 1],
                    muL[1 * 4 + h] * 0.125f, sc + E4, grp, j, m);
        m = fmaxf(m, __shfl_xor(m, 16));
        m = fmaxf(m, __shfl_xor(m, 32));
        if (grp == 0 && (j & 3) == 0) mx_s[(size_t)wid * 4 + h] = m;
    }
}

// ---------------------------------------------------------------------------
// Aggregation: den lanes-split; gather with 16-lane-per-edge groups,
// f32 accumulator slice per lane, cross-group shfl combine, gelu, fp16 store.
// ---------------------------------------------------------------------------
__device__ __forceinline__ void agg_rel_g(
    const float* __restrict__ sc, const _Float16* __restrict__ vM,
    const int* __restrict__ cs, int beg, int end, float mh, float dinv,
    int grp, int j, int h, float* accf) {
    for (int i = beg + grp; i < end; i += 4) {
        const int s = cs[i];
        const float w = expf(sc[(size_t)i * 4 + h] - mh) * dinv;
        const _Float16* row = &vM[(size_t)s * 256 + j * 16];
        const f16x8 v0 = *(const f16x8*)row;
        const f16x8 v1 = *(const f16x8*)(row + 8);
#pragma unroll
        for (int t = 0; t < 8; ++t) accf[t] += w * (float)v0[t];
#pragma unroll
        for (int t = 0; t < 8; ++t) accf[8 + t] += w * (float)v1[t];
    }
}

__global__ __launch_bounds__(256) void agg3_k(
    const float* __restrict__ sc, const _Float16* __restrict__ vM0,
    const _Float16* __restrict__ vM1, const _Float16* __restrict__ vM2,
    const int* __restrict__ rp, const int* __restrict__ colsrc,
    const float* __restrict__ mx_e, const float* __restrict__ mx_s,
    _Float16* __restrict__ outE, _Float16* __restrict__ outS, int N, int E) {
    const int wid = (blockIdx.x * blockDim.x + threadIdx.x) >> 6;
    if (wid >= N) return;
    const int lane = threadIdx.x & 63;
    const int grp = lane >> 4, j = lane & 15, h = j >> 2;
    const int hLo = lane & 3, sl = lane >> 2;
    const size_t E4 = (size_t)E * 4;
    float accf[16] = {};
    if (blockIdx.y == 0) {
        const float mLo = mx_e[(size_t)wid * 4 + hLo];
        const float mh = mx_e[(size_t)wid * 4 + h];
        const int b0 = rp[wid], e0 = rp[wid + 1];
        const int* rp2 = rp + 2 * (N + 1);
        const int b2 = rp2[wid], e2 = rp2[wid + 1];
        const float* sc2 = sc + 2 * E4;
        float dl = 0.f;
        for (int i = b0 + sl; i < e0; i += 16)
            dl += expf(sc[(size_t)i * 4 + hLo] - mLo);
        for (int i = b2 + sl; i < e2; i += 16)
            dl += expf(sc2[(size_t)i * 4 + hLo] - mLo);
        dl += __shfl_xor(dl, 4); dl += __shfl_xor(dl, 8);
        dl += __shfl_xor(dl, 16); dl += __shfl_xor(dl, 32);
        const float dinv = 1.0f / (__shfl(dl, h) + 1e-16f);
        agg_rel_g(sc, vM0, colsrc, b0, e0, mh, dinv, grp, j, h, accf);
        agg_rel_g(sc2, vM2, colsrc + 2 * (size_t)E, b2, e2, mh, dinv, grp, j,
                  h, accf);
#pragma unroll
        for (int t = 0; t < 16; ++t) {
            accf[t] += __shfl_xor(accf[t], 16);
            accf[t] += __shfl_xor(accf[t], 32);
        }
        if (grp == 0) {
            f16x8 o0, o1;
#pragma unroll
            for (int t = 0; t < 8; ++t) o0[t] = (_Float16)gelu_f(accf[t]);
#pragma unroll
            for (int t = 0; t < 8; ++t) o1[t] = (_Float16)gelu_f(accf[8 + t]);
            _Float16* dst = &outE[(size_t)wid * 256 + j * 16];
            *(f16x8*)dst = o0;
            *(f16x8*)(dst + 8) = o1;
        }
    } else {
        const float mLo = mx_s[(size_t)wid * 4 + hLo];
        const float mh = mx_s[(size_t)wid * 4 + h];
        const int* rp1 = rp + (N + 1);
        const int b1 = rp1[wid], e1 = rp1[wid + 1];
        const float* sc1 = sc + E4;
        float dl = 0.f;
        for (int i = b1 + sl; i < e1; i += 16)
            dl += expf(sc1[(size_t)i * 4 + hLo] - mLo);
        dl += __shfl_xor(dl, 4); dl += __shfl_xor(dl, 8);
        dl += __shfl_xor(dl, 16); dl += __shfl_xor(dl, 32);
        const float dinv = 1.0f / (__shfl(dl, h) + 1e-16f);
        agg_rel_g(sc1, vM1, colsrc + (size_t)E, b1, e1, mh, dinv, grp, j, h,
                  accf);
#pragma unroll
        for (int t = 0; t < 16; ++t) {
            accf[t] += __shfl_xor(accf[t], 16);
            accf[t] += __shfl_xor(accf[t], 32);
        }
        if (grp == 0) {
            f16x8 o0, o1;
#pragma unroll
            for (int t = 0; t < 8; ++t) o0[t] = (_Float16)gelu_f(accf[t]);
#pragma unroll
            for (int t = 0; t < 8; ++t) o1[t] = (_Float16)gelu_f(accf[8 + t]);
            _Float16* dst = &outS[(size_t)wid * 256 + j * 16];
            *(f16x8*)dst = o0;
            *(f16x8*)(dst + 8) = o1;
        }
    }
}

// ---------------------------------------------------------------------------
// Batched head epilogue.
// ---------------------------------------------------------------------------
__global__ __launch_bounds__(256) void head2_k(const _Float16* __restrict__ t,
                                               const float* __restrict__ Wt2,
                                               const float* __restrict__ bt2,
                                               float* __restrict__ out, int M) {
    const int k = blockIdx.y;
    __shared__ float Ws[128 * 8];
    __shared__ float bs[8];
    const int tid = threadIdx.x;
    const float* W2 = Wt2 + (size_t)k * 1024;
    for (int i = tid; i < 1024; i += 256) Ws[i] = W2[i];
    if (tid < 8) bs[tid] = bt2[k * 8 + tid];
    __syncthreads();
    const int OFFA[7] = {0, 3, 6, 9, 14, 15, 16};
    const int DIMSA[7] = {3, 3, 3, 5, 1, 1, 8};
    const int nl = tid >> 3, o = tid & 7;
    const int n = blockIdx.x * 32 + nl;
    if (n >= M) return;
    const _Float16* tr = &t[(size_t)n * 896 + k * 128];
    float acc = bs[o];
#pragma unroll 8
    for (int d = 0; d < 128; ++d) acc += (float)tr[d] * Ws[d * 8 + o];
    if (o < DIMSA[k]) out[(size_t)n * 24 + OFFA[k] + o] = acc;
}

// ---------------------------------------------------------------------------

extern "C" void kernel_launch(void* const* d_in, const int* in_sizes, int n_in,
                              void* d_out, int out_size, void* d_ws,
                              size_t ws_size, hipStream_t stream) {
    const float* xe_in = (const float*)d_in[0];
    const float* xs_in = (const float*)d_in[1];
    const int* ee_src = (const int*)d_in[2];
    const int* ee_dst = (const int*)d_in[3];
    const int* es_src = (const int*)d_in[4];
    const int* es_dst = (const int*)d_in[5];
    const int* se_src = (const int*)d_in[6];
    const int* se_dst = (const int*)d_in[7];
    const float* Wk = (const float*)d_in[8];
    const float* Wq = (const float*)d_in[9];
    const float* Wv = (const float*)d_in[10];
    const float* Wa = (const float*)d_in[11];
    const float* skip = (const float*)d_in[12];
    const float* Arel = (const float*)d_in[13];
    const float* Mrel = (const float*)d_in[14];
    const float* mu = (const float*)d_in[15];
    const float* Wsh = (const float*)d_in[16];
    const float* bsh = (const float*)d_in[17];
    const float* Wt1 = (const float*)d_in[18];
    const float* bt1 = (const float*)d_in[19];
    const float* Wt2 = (const float*)d_in[20];
    const float* bt2 = (const float*)d_in[21];
    float* out = (float*)d_out;

    const int N = in_sizes[0] / CDIM;  // 50000
    const int E = in_sizes[2];         // 200000
    const size_t NC = (size_t)N * CDIM;
    const size_t E4 = (size_t)E * 4;
    const size_t N4 = (size_t)N * 4;

    const size_t halfs = 7 * NC + 32 * (size_t)AR_R + 7 * 32768;
    const size_t floats = 3 * E4 + 2 * N4;
    const size_t ints = 3 * (size_t)(N + 1) + 3 * (size_t)E + 3 * (size_t)N;
    const size_t need = halfs * 2 + floats * 4 + ints * 4;
    if (ws_size < need) return;

    _Float16* xeH = (_Float16*)d_ws;
    _Float16* xsH = xeH + NC;
    _Float16* Hb = xsH + NC;
    _Float16* H1 = Hb;
    _Float16* H2 = Hb + NC;
    _Float16* H3 = Hb + 2 * NC;
    _Float16* H4 = Hb + 3 * NC;
    _Float16* H5 = Hb + 4 * NC;
    _Float16* arena = Hb + 5 * NC;
    _Float16* SA = arena + (size_t)30 * AR_R;
    _Float16* HA = SA + (size_t)2 * AR_R;
    float* sc = (float*)(HA + (size_t)7 * 32768);
    float* mx_e = sc + 3 * E4;
    float* mx_s = mx_e + N4;
    int* rp = (int*)(mx_s + N4);
    int* colsrc = rp + 3 * (size_t)(N + 1);
    int* cnt = colsrc + 3 * (size_t)E;

    const int gx = (N + 127) / 128;
    const dim3 e3((E + 255) / 256, 3);
    const int wave_blocks = (N + 3) / 4;
    const int zc_blocks = (3 * N + 255) / 256;

    // ---- CSR build ----
    zero_k<<<zc_blocks, 256, 0, stream>>>(cnt, 3 * (size_t)N);
    hist3_k<<<e3, 256, 0, stream>>>(ee_dst, es_dst, se_dst, cnt, N, E);
    scan3_k<<<dim3(1, 3), 1024, 0, stream>>>(cnt, rp, N);
    zero_k<<<zc_blocks, 256, 0, stream>>>(cnt, 3 * (size_t)N);
    scatter3_k<<<e3, 256, 0, stream>>>(ee_dst, es_dst, se_dst, ee_src, es_src,
                                       se_src, rp, cnt, colsrc, N, E);

    // ---- weight prep ----
    for (int l = 0; l < 3; ++l)
        prep_layer_k<<<dim3(256, 10), 256, 0, stream>>>(Wk, Wq, Wv, Wa, Arel,
                                                        Mrel, l, arena);
    prep_stack_k<<<dim3(256, 2), 256, 0, stream>>>(Wsh, SA);
    prep_heads_k<<<dim3(128, 7), 256, 0, stream>>>(Wt1, HA);

    // ---- initial fp16 activations ----
    cvt_k<<<1024, 256, 0, stream>>>(xe_in, xeH, NC / 4);
    cvt_k<<<1024, 256, 0, stream>>>(xs_in, xsH, NC / 4);

    for (int l = 0; l < 3; ++l) {
        _Float16* L = arena + (size_t)l * 10 * AR_R;
        gemm_h<0, true><<<dim3(gx, 6), 256, 0, stream>>>(
            xeH, L, H1, N, 768, NC, nullptr, nullptr);  // q_e|kA0|kA1
        gemm_h<0, true><<<dim3(gx, 4), 256, 0, stream>>>(
            xsH, L + 3 * AR_R, H4, N, 512, NC, nullptr, nullptr);  // q_s|kA2
        score3_k<<<dim3(wave_blocks, 2), 256, 0, stream>>>(
            H1, H2, H3, H4, H5, rp, colsrc, mu + l * 12, sc, mx_e, mx_s, N, E);
        gemm_h<0, true><<<dim3(gx, 4), 256, 0, stream>>>(
            xeH, L + 5 * AR_R, H2, N, 512, NC, nullptr, nullptr);  // vM0|vM1
        gemm_h<0, false><<<dim3(gx, 2), 256, 0, stream>>>(
            xsH, L + 7 * AR_R, H5, N, 256, 0, nullptr, nullptr);  // vM2
        agg3_k<<<dim3(wave_blocks, 2), 256, 0, stream>>>(
            sc, H2, H3, H5, rp, colsrc, mx_e, mx_s, H1, H4, N, E);
        update2_k<<<dim3(gx, 4), 256, 0, stream>>>(
            H1, H4, L + 8 * AR_R, L + 9 * AR_R, xeH, xsH, skip + l * 2, N);
    }

    // shared linear stack
    gemm_h<2, false><<<dim3(gx, 2), 256, 0, stream>>>(xeH, SA, H5, N, 256, 0,
                                                      bsh, nullptr);
    gemm_h<2, false><<<dim3(gx, 2), 256, 0, stream>>>(H5, SA + AR_R, xsH, N,
                                                      256, 0, bsh + 256, nullptr);
    // 7 task heads
    gemm_h<2, false><<<dim3(gx, 7), 256, 0, stream>>>(xsH, HA, Hb, N, 896, 0,
                                                      bt1, nullptr);
    head2_k<<<dim3((N + 31) / 32, 7), 256, 0, stream>>>(Hb, Wt2, bt2, out, N);
}

// Round 10
// 1167.319 us; speedup vs baseline: 8.8449x; 1.0301x over previous
//
#include <hip/hip_runtime.h>
#include <hip/hip_fp16.h>
#include <cmath>

// ---------------------------------------------------------------------------
// DragonHGT R10: fp16 MFMA GEMMs (BK=64, XOR LDS, col-fast block order for
// A-panel L2 reuse) + CSR edge pipeline (16-lane groups; single-pass online
// softmax aggregation with distributed GELU).
// N=50000 x 2 node types, E=200000 x 3 relations, C=256 (H=4, D=64).
// ---------------------------------------------------------------------------

#define CDIM 256
#define AR_R (256 * 256)

using f16x8 = __attribute__((ext_vector_type(8))) _Float16;
using f16x4 = __attribute__((ext_vector_type(4))) _Float16;
using f16x2 = __attribute__((ext_vector_type(2))) _Float16;
using f32x4 = __attribute__((ext_vector_type(4))) float;

__device__ __forceinline__ float gelu_f(float x) {
    return 0.5f * x * (1.0f + erff(x * 0.70710678118654752f));
}

__device__ __forceinline__ float dot8f(const f16x8 a, const f16x8 b, float r) {
#if __has_builtin(__builtin_amdgcn_fdot2)
#pragma unroll
    for (int t = 0; t < 4; ++t) {
        f16x2 av = {a[2 * t], a[2 * t + 1]};
        f16x2 bv = {b[2 * t], b[2 * t + 1]};
        r = __builtin_amdgcn_fdot2(av, bv, r, false);
    }
#else
#pragma unroll
    for (int t = 0; t < 8; ++t) r += (float)a[t] * (float)b[t];
#endif
    return r;
}

__global__ __launch_bounds__(256) void zero_k(int* __restrict__ p, size_t n) {
    size_t i = (size_t)blockIdx.x * blockDim.x + threadIdx.x;
    const size_t stride = (size_t)gridDim.x * blockDim.x;
    for (; i < n; i += stride) p[i] = 0;
}

__global__ __launch_bounds__(256) void cvt_k(const float* __restrict__ in,
                                             _Float16* __restrict__ out,
                                             size_t n4) {
    size_t i = (size_t)blockIdx.x * blockDim.x + threadIdx.x;
    const size_t stride = (size_t)gridDim.x * blockDim.x;
    for (; i < n4; i += stride) {
        const float4 v = ((const float4*)in)[i];
        f16x4 o;
        o[0] = (_Float16)v.x; o[1] = (_Float16)v.y;
        o[2] = (_Float16)v.z; o[3] = (_Float16)v.w;
        ((f16x4*)out)[i] = o;
    }
}

// ---------------------------------------------------------------------------
// Weight prep.
// ---------------------------------------------------------------------------
__device__ __forceinline__ void cvtT_dev(const float* __restrict__ W,
                                         _Float16* __restrict__ dst) {
    const int o = blockIdx.x, c = threadIdx.x;
    dst[(size_t)o * 256 + c] = (_Float16)W[(size_t)c * 256 + o];
}

__device__ __forceinline__ void foldT_dev(const float* __restrict__ Wbase,
                                          const float* __restrict__ T,
                                          _Float16* __restrict__ dst) {
    __shared__ float row[256];
    const int c = blockIdx.x, t = threadIdx.x;
    row[t] = Wbase[(size_t)c * 256 + t];
    __syncthreads();
    const int h = t >> 6, f = t & 63;
    const float* Th = T + h * 4096;
    float acc = 0.f;
#pragma unroll 8
    for (int d = 0; d < 64; ++d) acc += row[h * 64 + d] * Th[d * 64 + f];
    dst[(size_t)t * 256 + c] = (_Float16)acc;
}

// arena per layer: q_e|kA0|kA1 | q_s|kA2 | vM0|vM1 | vM2 | WaT0|WaT1
__global__ __launch_bounds__(256) void prep_layer_k(
    const float* __restrict__ Wk, const float* __restrict__ Wq,
    const float* __restrict__ Wv, const float* __restrict__ Wa,
    const float* __restrict__ Arel, const float* __restrict__ Mrel, int l,
    _Float16* __restrict__ arena) {
    const size_t CC = 65536, HDD = 16384;
    _Float16* L = arena + (size_t)l * 10 * AR_R;
    const float* Wk0 = Wk + (l * 2 + 0) * CC;
    const float* Wk1 = Wk + (l * 2 + 1) * CC;
    const float* Wv0 = Wv + (l * 2 + 0) * CC;
    const float* Wv1 = Wv + (l * 2 + 1) * CC;
    switch (blockIdx.y) {
        case 0: cvtT_dev(Wq + (l * 2 + 0) * CC, L); break;
        case 1: foldT_dev(Wk0, Arel + (l * 3 + 0) * HDD, L + 1 * AR_R); break;
        case 2: foldT_dev(Wk0, Arel + (l * 3 + 1) * HDD, L + 2 * AR_R); break;
        case 3: cvtT_dev(Wq + (l * 2 + 1) * CC, L + 3 * AR_R); break;
        case 4: foldT_dev(Wk1, Arel + (l * 3 + 2) * HDD, L + 4 * AR_R); break;
        case 5: foldT_dev(Wv0, Mrel + (l * 3 + 0) * HDD, L + 5 * AR_R); break;
        case 6: foldT_dev(Wv0, Mrel + (l * 3 + 1) * HDD, L + 6 * AR_R); break;
        case 7: foldT_dev(Wv1, Mrel + (l * 3 + 2) * HDD, L + 7 * AR_R); break;
        case 8: cvtT_dev(Wa + (l * 2 + 0) * CC, L + 8 * AR_R); break;
        case 9: cvtT_dev(Wa + (l * 2 + 1) * CC, L + 9 * AR_R); break;
    }
}

__global__ __launch_bounds__(256) void prep_stack_k(const float* __restrict__ Wsh,
                                                    _Float16* __restrict__ SA) {
    cvtT_dev(Wsh + (size_t)blockIdx.y * 65536, SA + (size_t)blockIdx.y * AR_R);
}

__global__ __launch_bounds__(256) void prep_heads_k(const float* __restrict__ Wt1,
                                                    _Float16* __restrict__ HA) {
    const int o = blockIdx.x, k = blockIdx.y, c = threadIdx.x;
    HA[(size_t)(k * 128 + o) * 256 + c] =
        (_Float16)Wt1[(size_t)k * 256 * 128 + (size_t)c * 128 + o];
}

// ---------------------------------------------------------------------------
// fp16 MFMA GEMM body (BK=64, XOR-swizzled linear LDS). bm/bn explicit.
// ---------------------------------------------------------------------------
template <int EPI, bool SPLIT>
__device__ __forceinline__ void gemm_body(
    const _Float16* __restrict__ A, const _Float16* __restrict__ Bt,
    _Float16* __restrict__ C, int M, int Nc, int bm, int bn, size_t bufStride,
    const float* __restrict__ bias, const float* __restrict__ skipv,
    _Float16* As, _Float16* Bs) {
    const int tid = threadIdx.x;
    const int wave = tid >> 6, lane = tid & 63;
    const int wm = (wave >> 1) * 64, wn = (wave & 1) * 64;
    const int l15 = lane & 15, g = lane >> 4;
    const int srow = tid >> 3;
    const int sbyte = (tid & 7) * 16;

    f32x4 acc[4][4] = {};

    for (int k0 = 0; k0 < 256; k0 += 64) {
        __syncthreads();
#pragma unroll
        for (int p = 0; p < 4; ++p) {
            const int r = p * 32 + srow;
            int gr = bm + r; if (gr >= M) gr = M - 1;
            const f16x8 av = *(const f16x8*)((const char*)A +
                                             ((size_t)gr * 256 + k0) * 2 + sbyte);
            const f16x8 bv = *(const f16x8*)((const char*)Bt +
                                             ((size_t)(bn + r) * 256 + k0) * 2 + sbyte);
            const int wb = sbyte ^ ((r & 7) << 4);
            *(f16x8*)((char*)As + r * 128 + wb) = av;
            *(f16x8*)((char*)Bs + r * 128 + wb) = bv;
        }
        __syncthreads();
#pragma unroll
        for (int sub = 0; sub < 2; ++sub) {
            f16x8 af[4], bf[4];
#pragma unroll
            for (int i = 0; i < 4; ++i) {
                const int ra = wm + i * 16 + l15;
                const int rb = wn + i * 16 + l15;
                const int ka = (sub * 64 + g * 16) ^ ((ra & 7) << 4);
                const int kb = (sub * 64 + g * 16) ^ ((rb & 7) << 4);
                af[i] = *(const f16x8*)((const char*)As + ra * 128 + ka);
                bf[i] = *(const f16x8*)((const char*)Bs + rb * 128 + kb);
            }
#pragma unroll
            for (int mi = 0; mi < 4; ++mi)
#pragma unroll
                for (int ni = 0; ni < 4; ++ni)
                    acc[mi][ni] = __builtin_amdgcn_mfma_f32_16x16x32_f16(
                        af[mi], bf[ni], acc[mi][ni], 0, 0, 0);
        }
    }

    float be = 0.f, ombe = 0.f;
    if (EPI == 1) {
        const float s = skipv[0];
        be = 1.0f / (1.0f + expf(-s));
        ombe = 1.0f - be;
    }
#pragma unroll
    for (int mi = 0; mi < 4; ++mi) {
#pragma unroll
        for (int r = 0; r < 4; ++r) {
            const int row = bm + wm + mi * 16 + g * 4 + r;
            if (row >= M) continue;
#pragma unroll
            for (int ni = 0; ni < 4; ++ni) {
                const int colg = bn + wn + ni * 16 + l15;
                float v = acc[mi][ni][r];
                size_t idx;
                if (SPLIT)
                    idx = (size_t)(colg >> 8) * bufStride + (size_t)row * 256 +
                          (colg & 255);
                else
                    idx = (size_t)row * Nc + colg;
                if (EPI == 1) v = be * v + ombe * (float)C[idx];
                if (EPI == 2) v = fmaxf(v + bias[colg], 0.f);
                C[idx] = (_Float16)v;
            }
        }
    }
}

// Grid = (cols, row_panels): consecutive blocks share the A row-panel (L2).
template <int EPI, bool SPLIT>
__global__ __launch_bounds__(256) void gemm_h(
    const _Float16* __restrict__ A, const _Float16* __restrict__ Bt,
    _Float16* __restrict__ C, int M, int Nc, size_t bufStride,
    const float* __restrict__ bias, const float* __restrict__ skipv) {
    __shared__ _Float16 As[128 * 64];
    __shared__ _Float16 Bs[128 * 64];
    gemm_body<EPI, SPLIT>(A, Bt, C, M, Nc, blockIdx.y * 128, blockIdx.x * 128,
                          bufStride, bias, skipv, As, Bs);
}

// Fused skip-updates; grid = (4, row_panels). x>>1: 0 -> xe, 1 -> xs.
__global__ __launch_bounds__(256) void update2_k(
    const _Float16* __restrict__ aggE, const _Float16* __restrict__ aggS,
    const _Float16* __restrict__ WaT0, const _Float16* __restrict__ WaT1,
    _Float16* __restrict__ xeH, _Float16* __restrict__ xsH,
    const float* __restrict__ skipb, int M) {
    __shared__ _Float16 As[128 * 64];
    __shared__ _Float16 Bs[128 * 64];
    const int sel = blockIdx.x >> 1;
    const int bn = (blockIdx.x & 1) * 128;
    const int bm = blockIdx.y * 128;
    if (sel == 0)
        gemm_body<1, false>(aggE, WaT0, xeH, M, 256, bm, bn, 0, nullptr, skipb,
                            As, Bs);
    else
        gemm_body<1, false>(aggS, WaT1, xsH, M, 256, bm, bn, 0, nullptr,
                            skipb + 1, As, Bs);
}

// ---------------------------------------------------------------------------
// CSR build: rp + colsrc.
// ---------------------------------------------------------------------------
__global__ __launch_bounds__(256) void hist3_k(const int* __restrict__ d0,
                                               const int* __restrict__ d1,
                                               const int* __restrict__ d2,
                                               int* __restrict__ cnt, int N,
                                               int E) {
    const int i = blockIdx.x * 256 + threadIdx.x;
    if (i >= E) return;
    const int r = blockIdx.y;
    const int* d = r == 0 ? d0 : r == 1 ? d1 : d2;
    atomicAdd(&cnt[(size_t)r * N + d[i]], 1);
}

__global__ __launch_bounds__(1024) void scan3_k(const int* __restrict__ cnt,
                                                int* __restrict__ rp, int N) {
    __shared__ int sums[1024];
    const int r = blockIdx.y;
    const int* c = cnt + (size_t)r * N;
    int* o = rp + (size_t)r * (N + 1);
    const int tid = threadIdx.x;
    const int chunk = (N + 1023) / 1024;
    const int lo = min(tid * chunk, N), hi = min(lo + chunk, N);
    int s = 0;
    for (int i = lo; i < hi; ++i) s += c[i];
    sums[tid] = s;
    __syncthreads();
    for (int off = 1; off < 1024; off <<= 1) {
        const int v = (tid >= off) ? sums[tid - off] : 0;
        __syncthreads();
        sums[tid] += v;
        __syncthreads();
    }
    int run = (tid == 0) ? 0 : sums[tid - 1];
    for (int i = lo; i < hi; ++i) { o[i] = run; run += c[i]; }
    if (tid == 1023) o[N] = run;
}

__global__ __launch_bounds__(256) void scatter3_k(
    const int* __restrict__ d0, const int* __restrict__ d1,
    const int* __restrict__ d2, const int* __restrict__ s0_,
    const int* __restrict__ s1_, const int* __restrict__ s2_,
    const int* __restrict__ rp, int* __restrict__ fill,
    int* __restrict__ colsrc, int N, int E) {
    const int i = blockIdx.x * 256 + threadIdx.x;
    if (i >= E) return;
    const int r = blockIdx.y;
    const int* d = r == 0 ? d0 : r == 1 ? d1 : d2;
    const int* s = r == 0 ? s0_ : r == 1 ? s1_ : s2_;
    const int dd = d[i];
    const int p = rp[(size_t)r * (N + 1) + dd] + atomicAdd(&fill[(size_t)r * N + dd], 1);
    colsrc[(size_t)r * E + p] = s[i];
}

// ---------------------------------------------------------------------------
// Scoring: wave per dst; 16 lanes per edge, 4 edges in flight (as R9).
// ---------------------------------------------------------------------------
__device__ __forceinline__ void score_rel_g(
    const f16x8 q0, const f16x8 q1, const _Float16* __restrict__ kA,
    const int* __restrict__ cs, int beg, int end, float scl,
    float* __restrict__ sc, int grp, int j, float& m) {
    for (int i = beg + grp; i < end; i += 4) {
        const int s = cs[i];
        const _Float16* row = &kA[(size_t)s * 256 + j * 16];
        const f16x8 k0 = *(const f16x8*)row;
        const f16x8 k1 = *(const f16x8*)(row + 8);
        float p = dot8f(q1, k1, dot8f(q0, k0, 0.f));
        p += __shfl_xor(p, 1);
        p += __shfl_xor(p, 2);
        const float v = p * scl;
        if ((j & 3) == 0) {
            sc[(size_t)i * 4 + (j >> 2)] = v;
            m = fmaxf(m, v);
        }
    }
}

__global__ __launch_bounds__(256) void score3_k(
    const _Float16* __restrict__ qe, const _Float16* __restrict__ kA0,
    const _Float16* __restrict__ kA1, const _Float16* __restrict__ qs,
    const _Float16* __restrict__ kA2, const int* __restrict__ rp,
    const int* __restrict__ colsrc, const float* __restrict__ muL,
    float* __restrict__ sc, float* __restrict__ mx_e,
    float* __restrict__ mx_s, int N, int E) {
    const int wid = (blockIdx.x * blockDim.x + threadIdx.x) >> 6;
    if (wid >= N) return;
    const int lane = threadIdx.x & 63;
    const int grp = lane >> 4, j = lane & 15, h = j >> 2;
    const size_t E4 = (size_t)E * 4;
    float m = -1e30f;
    if (blockIdx.y == 0) {
        const _Float16* qrow = &qe[(size_t)wid * 256 + j * 16];
        const f16x8 q0 = *(const f16x8*)qrow;
        const f16x8 q1 = *(const f16x8*)(qrow + 8);
        score_rel_g(q0, q1, kA0, colsrc, rp[wid], rp[wid + 1],
                    muL[0 * 4 + h] * 0.125f, sc, grp, j, m);
        const int* rp2 = rp + 2 * (N + 1);
        score_rel_g(q0, q1, kA2, colsrc + 2 * (size_t)E, rp2[wid], rp2[wid + 1],
                    muL[2 * 4 + h] * 0.125f, sc + 2 * E4, grp, j, m);
        m = fmaxf(m, __shfl_xor(m, 16));
        m = fmaxf(m, __shfl_xor(m, 32));
        if (grp == 0 && (j & 3) == 0) mx_e[(size_t)wid * 4 + h] = m;
    } else {
        const _Float16* qrow = &qs[(size_t)wid * 256 + j * 16];
        const f16x8 q0 = *(const f16x8*)qrow;
        const f16x8 q1 = *(const f16x8*)(qrow + 8);
        const int* rp1 = rp + (N + 1);
        score_rel_g(q0, q1, kA1, colsrc + (size_t)E, rp1[wid], rp1[wid + 1],
                    muL[1 * 4 + h] * 0.125f, sc + E4, grp, j, m);
        m = fmaxf(m, __shfl_xor(m, 16));
        m = fmaxf(m, __shfl_xor(m, 32));
        if (grp == 0 && (j & 3) == 0) mx_s[(size_t)wid * 4 + h] = m;
    }
}

// ---------------------------------------------------------------------------
// Aggregation (single-pass online): per edge w = exp(s - m); den += w;
// acc += w*v. After cross-group combine: normalize, gelu distributed across
// all 64 lanes (4 elems each), coalesced f16x4 stores.
// ---------------------------------------------------------------------------
__device__ __forceinline__ void agg_rel_on(
    const float* __restrict__ sc, const _Float16* __restrict__ vM,
    const int* __restrict__ cs, int beg, int end, float mh, int grp, int j,
    int h, float* accf, float& den) {
    for (int i = beg + grp; i < end; i += 4) {
        const int s = cs[i];
        const float w = expf(sc[(size_t)i * 4 + h] - mh);
        den += w;
        const _Float16* row = &vM[(size_t)s * 256 + j * 16];
        const f16x8 v0 = *(const f16x8*)row;
        const f16x8 v1 = *(const f16x8*)(row + 8);
#pragma unroll
        for (int t = 0; t < 8; ++t) accf[t] += w * (float)v0[t];
#pragma unroll
        for (int t = 0; t < 8; ++t) accf[8 + t] += w * (float)v1[t];
    }
}

__global__ __launch_bounds__(256) void agg3_k(
    const float* __restrict__ sc, const _Float16* __restrict__ vM0,
    const _Float16* __restrict__ vM1, const _Float16* __restrict__ vM2,
    const int* __restrict__ rp, const int* __restrict__ colsrc,
    const float* __restrict__ mx_e, const float* __restrict__ mx_s,
    _Float16* __restrict__ outE, _Float16* __restrict__ outS, int N, int E) {
    const int wid = (blockIdx.x * blockDim.x + threadIdx.x) >> 6;
    if (wid >= N) return;
    const int lane = threadIdx.x & 63;
    const int grp = lane >> 4, j = lane & 15, h = j >> 2;
    const size_t E4 = (size_t)E * 4;
    float accf[16] = {};
    float den = 0.f;
    _Float16* outp;
    if (blockIdx.y == 0) {
        const float mh = mx_e[(size_t)wid * 4 + h];
        const int b0 = rp[wid], e0 = rp[wid + 1];
        const int* rp2 = rp + 2 * (N + 1);
        const int b2 = rp2[wid], e2 = rp2[wid + 1];
        agg_rel_on(sc, vM0, colsrc, b0, e0, mh, grp, j, h, accf, den);
        agg_rel_on(sc + 2 * E4, vM2, colsrc + 2 * (size_t)E, b2, e2, mh, grp,
                   j, h, accf, den);
        outp = outE;
    } else {
        const float mh = mx_s[(size_t)wid * 4 + h];
        const int* rp1 = rp + (N + 1);
        const int b1 = rp1[wid], e1 = rp1[wid + 1];
        agg_rel_on(sc + E4, vM1, colsrc + (size_t)E, b1, e1, mh, grp, j, h,
                   accf, den);
        outp = outS;
    }
    den += __shfl_xor(den, 16);
    den += __shfl_xor(den, 32);
#pragma unroll
    for (int t = 0; t < 16; ++t) {
        accf[t] += __shfl_xor(accf[t], 16);
        accf[t] += __shfl_xor(accf[t], 32);
    }
    const float dinv = 1.0f / (den + 1e-16f);
    f16x4 o;
#pragma unroll
    for (int t = 0; t < 4; ++t)
        o[t] = (_Float16)gelu_f(accf[grp * 4 + t] * dinv);
    *(f16x4*)&outp[(size_t)wid * 256 + j * 16 + grp * 4] = o;
}

// ---------------------------------------------------------------------------
// Batched head epilogue.
// ---------------------------------------------------------------------------
__global__ __launch_bounds__(256) void head2_k(const _Float16* __restrict__ t,
                                               const float* __restrict__ Wt2,
                                               const float* __restrict__ bt2,
                                               float* __restrict__ out, int M) {
    const int k = blockIdx.y;
    __shared__ float Ws[128 * 8];
    __shared__ float bs[8];
    const int tid = threadIdx.x;
    const float* W2 = Wt2 + (size_t)k * 1024;
    for (int i = tid; i < 1024; i += 256) Ws[i] = W2[i];
    if (tid < 8) bs[tid] = bt2[k * 8 + tid];
    __syncthreads();
    const int OFFA[7] = {0, 3, 6, 9, 14, 15, 16};
    const int DIMSA[7] = {3, 3, 3, 5, 1, 1, 8};
    const int nl = tid >> 3, o = tid & 7;
    const int n = blockIdx.x * 32 + nl;
    if (n >= M) return;
    const _Float16* tr = &t[(size_t)n * 896 + k * 128];
    float acc = bs[o];
#pragma unroll 8
    for (int d = 0; d < 128; ++d) acc += (float)tr[d] * Ws[d * 8 + o];
    if (o < DIMSA[k]) out[(size_t)n * 24 + OFFA[k] + o] = acc;
}

// ---------------------------------------------------------------------------

extern "C" void kernel_launch(void* const* d_in, const int* in_sizes, int n_in,
                              void* d_out, int out_size, void* d_ws,
                              size_t ws_size, hipStream_t stream) {
    const float* xe_in = (const float*)d_in[0];
    const float* xs_in = (const float*)d_in[1];
    const int* ee_src = (const int*)d_in[2];
    const int* ee_dst = (const int*)d_in[3];
    const int* es_src = (const int*)d_in[4];
    const int* es_dst = (const int*)d_in[5];
    const int* se_src = (const int*)d_in[6];
    const int* se_dst = (const int*)d_in[7];
    const float* Wk = (const float*)d_in[8];
    const float* Wq = (const float*)d_in[9];
    const float* Wv = (const float*)d_in[10];
    const float* Wa = (const float*)d_in[11];
    const float* skip = (const float*)d_in[12];
    const float* Arel = (const float*)d_in[13];
    const float* Mrel = (const float*)d_in[14];
    const float* mu = (const float*)d_in[15];
    const float* Wsh = (const float*)d_in[16];
    const float* bsh = (const float*)d_in[17];
    const float* Wt1 = (const float*)d_in[18];
    const float* bt1 = (const float*)d_in[19];
    const float* Wt2 = (const float*)d_in[20];
    const float* bt2 = (const float*)d_in[21];
    float* out = (float*)d_out;

    const int N = in_sizes[0] / CDIM;  // 50000
    const int E = in_sizes[2];         // 200000
    const size_t NC = (size_t)N * CDIM;
    const size_t E4 = (size_t)E * 4;
    const size_t N4 = (size_t)N * 4;

    const size_t halfs = 7 * NC + 32 * (size_t)AR_R + 7 * 32768;
    const size_t floats = 3 * E4 + 2 * N4;
    const size_t ints = 3 * (size_t)(N + 1) + 3 * (size_t)E + 3 * (size_t)N;
    const size_t need = halfs * 2 + floats * 4 + ints * 4;
    if (ws_size < need) return;

    _Float16* xeH = (_Float16*)d_ws;
    _Float16* xsH = xeH + NC;
    _Float16* Hb = xsH + NC;
    _Float16* H1 = Hb;
    _Float16* H2 = Hb + NC;
    _Float16* H3 = Hb + 2 * NC;
    _Float16* H4 = Hb + 3 * NC;
    _Float16* H5 = Hb + 4 * NC;
    _Float16* arena = Hb + 5 * NC;
    _Float16* SA = arena + (size_t)30 * AR_R;
    _Float16* HA = SA + (size_t)2 * AR_R;
    float* sc = (float*)(HA + (size_t)7 * 32768);
    float* mx_e = sc + 3 * E4;
    float* mx_s = mx_e + N4;
    int* rp = (int*)(mx_s + N4);
    int* colsrc = rp + 3 * (size_t)(N + 1);
    int* cnt = colsrc + 3 * (size_t)E;

    const int gx = (N + 127) / 128;
    const dim3 e3((E + 255) / 256, 3);
    const int wave_blocks = (N + 3) / 4;
    const int zc_blocks = (3 * N + 255) / 256;

    // ---- CSR build ----
    zero_k<<<zc_blocks, 256, 0, stream>>>(cnt, 3 * (size_t)N);
    hist3_k<<<e3, 256, 0, stream>>>(ee_dst, es_dst, se_dst, cnt, N, E);
    scan3_k<<<dim3(1, 3), 1024, 0, stream>>>(cnt, rp, N);
    zero_k<<<zc_blocks, 256, 0, stream>>>(cnt, 3 * (size_t)N);
    scatter3_k<<<e3, 256, 0, stream>>>(ee_dst, es_dst, se_dst, ee_src, es_src,
                                       se_src, rp, cnt, colsrc, N, E);

    // ---- weight prep ----
    for (int l = 0; l < 3; ++l)
        prep_layer_k<<<dim3(256, 10), 256, 0, stream>>>(Wk, Wq, Wv, Wa, Arel,
                                                        Mrel, l, arena);
    prep_stack_k<<<dim3(256, 2), 256, 0, stream>>>(Wsh, SA);
    prep_heads_k<<<dim3(128, 7), 256, 0, stream>>>(Wt1, HA);

    // ---- initial fp16 activations ----
    cvt_k<<<1024, 256, 0, stream>>>(xe_in, xeH, NC / 4);
    cvt_k<<<1024, 256, 0, stream>>>(xs_in, xsH, NC / 4);

    for (int l = 0; l < 3; ++l) {
        _Float16* L = arena + (size_t)l * 10 * AR_R;
        gemm_h<0, true><<<dim3(6, gx), 256, 0, stream>>>(
            xeH, L, H1, N, 768, NC, nullptr, nullptr);  // q_e|kA0|kA1
        gemm_h<0, true><<<dim3(4, gx), 256, 0, stream>>>(
            xsH, L + 3 * AR_R, H4, N, 512, NC, nullptr, nullptr);  // q_s|kA2
        score3_k<<<dim3(wave_blocks, 2), 256, 0, stream>>>(
            H1, H2, H3, H4, H5, rp, colsrc, mu + l * 12, sc, mx_e, mx_s, N, E);
        gemm_h<0, true><<<dim3(4, gx), 256, 0, stream>>>(
            xeH, L + 5 * AR_R, H2, N, 512, NC, nullptr, nullptr);  // vM0|vM1
        gemm_h<0, false><<<dim3(2, gx), 256, 0, stream>>>(
            xsH, L + 7 * AR_R, H5, N, 256, 0, nullptr, nullptr);  // vM2
        agg3_k<<<dim3(wave_blocks, 2), 256, 0, stream>>>(
            sc, H2, H3, H5, rp, colsrc, mx_e, mx_s, H1, H4, N, E);
        update2_k<<<dim3(4, gx), 256, 0, stream>>>(
            H1, H4, L + 8 * AR_R, L + 9 * AR_R, xeH, xsH, skip + l * 2, N);
    }

    // shared linear stack
    gemm_h<2, false><<<dim3(2, gx), 256, 0, stream>>>(xeH, SA, H5, N, 256, 0,
                                                      bsh, nullptr);
    gemm_h<2, false><<<dim3(2, gx), 256, 0, stream>>>(H5, SA + AR_R, xsH, N,
                                                      256, 0, bsh + 256, nullptr);
    // 7 task heads
    gemm_h<2, false><<<dim3(7, gx), 256, 0, stream>>>(xsH, HA, Hb, N, 896, 0,
                                                      bt1, nullptr);
    head2_k<<<dim3((N + 31) / 32, 7), 256, 0, stream>>>(Hb, Wt2, bt2, out, N);
}

// Round 11
// 1098.412 us; speedup vs baseline: 9.3998x; 1.0627x over previous
//
#include <hip/hip_runtime.h>
#include <hip/hip_fp16.h>
#include <cmath>

// ---------------------------------------------------------------------------
// DragonHGT R11: fp16 MFMA GEMMs (BK=64, XOR LDS via pre-swizzled
// global_load_lds staging, col-fast block order) + CSR edge pipeline
// (16-lane groups, single-pass online softmax agg) + parallel 3-phase scan.
// N=50000 x 2 node types, E=200000 x 3 relations, C=256 (H=4, D=64).
// ---------------------------------------------------------------------------

#define CDIM 256
#define AR_R (256 * 256)

using f16x8 = __attribute__((ext_vector_type(8))) _Float16;
using f16x4 = __attribute__((ext_vector_type(4))) _Float16;
using f16x2 = __attribute__((ext_vector_type(2))) _Float16;
using f32x4 = __attribute__((ext_vector_type(4))) float;

__device__ __forceinline__ float gelu_f(float x) {
    return 0.5f * x * (1.0f + erff(x * 0.70710678118654752f));
}

__device__ __forceinline__ float dot8f(const f16x8 a, const f16x8 b, float r) {
#if __has_builtin(__builtin_amdgcn_fdot2)
#pragma unroll
    for (int t = 0; t < 4; ++t) {
        f16x2 av = {a[2 * t], a[2 * t + 1]};
        f16x2 bv = {b[2 * t], b[2 * t + 1]};
        r = __builtin_amdgcn_fdot2(av, bv, r, false);
    }
#else
#pragma unroll
    for (int t = 0; t < 8; ++t) r += (float)a[t] * (float)b[t];
#endif
    return r;
}

__global__ __launch_bounds__(256) void zero_k(int* __restrict__ p, size_t n) {
    size_t i = (size_t)blockIdx.x * blockDim.x + threadIdx.x;
    const size_t stride = (size_t)gridDim.x * blockDim.x;
    for (; i < n; i += stride) p[i] = 0;
}

__global__ __launch_bounds__(256) void cvt_k(const float* __restrict__ in,
                                             _Float16* __restrict__ out,
                                             size_t n4) {
    size_t i = (size_t)blockIdx.x * blockDim.x + threadIdx.x;
    const size_t stride = (size_t)gridDim.x * blockDim.x;
    for (; i < n4; i += stride) {
        const float4 v = ((const float4*)in)[i];
        f16x4 o;
        o[0] = (_Float16)v.x; o[1] = (_Float16)v.y;
        o[2] = (_Float16)v.z; o[3] = (_Float16)v.w;
        ((f16x4*)out)[i] = o;
    }
}

// ---------------------------------------------------------------------------
// Weight prep.
// ---------------------------------------------------------------------------
__device__ __forceinline__ void cvtT_dev(const float* __restrict__ W,
                                         _Float16* __restrict__ dst) {
    const int o = blockIdx.x, c = threadIdx.x;
    dst[(size_t)o * 256 + c] = (_Float16)W[(size_t)c * 256 + o];
}

__device__ __forceinline__ void foldT_dev(const float* __restrict__ Wbase,
                                          const float* __restrict__ T,
                                          _Float16* __restrict__ dst) {
    __shared__ float row[256];
    const int c = blockIdx.x, t = threadIdx.x;
    row[t] = Wbase[(size_t)c * 256 + t];
    __syncthreads();
    const int h = t >> 6, f = t & 63;
    const float* Th = T + h * 4096;
    float acc = 0.f;
#pragma unroll 8
    for (int d = 0; d < 64; ++d) acc += row[h * 64 + d] * Th[d * 64 + f];
    dst[(size_t)t * 256 + c] = (_Float16)acc;
}

// arena per layer: q_e|kA0|kA1 | q_s|kA2 | vM0|vM1 | vM2 | WaT0|WaT1
__global__ __launch_bounds__(256) void prep_layer_k(
    const float* __restrict__ Wk, const float* __restrict__ Wq,
    const float* __restrict__ Wv, const float* __restrict__ Wa,
    const float* __restrict__ Arel, const float* __restrict__ Mrel, int l,
    _Float16* __restrict__ arena) {
    const size_t CC = 65536, HDD = 16384;
    _Float16* L = arena + (size_t)l * 10 * AR_R;
    const float* Wk0 = Wk + (l * 2 + 0) * CC;
    const float* Wk1 = Wk + (l * 2 + 1) * CC;
    const float* Wv0 = Wv + (l * 2 + 0) * CC;
    const float* Wv1 = Wv + (l * 2 + 1) * CC;
    switch (blockIdx.y) {
        case 0: cvtT_dev(Wq + (l * 2 + 0) * CC, L); break;
        case 1: foldT_dev(Wk0, Arel + (l * 3 + 0) * HDD, L + 1 * AR_R); break;
        case 2: foldT_dev(Wk0, Arel + (l * 3 + 1) * HDD, L + 2 * AR_R); break;
        case 3: cvtT_dev(Wq + (l * 2 + 1) * CC, L + 3 * AR_R); break;
        case 4: foldT_dev(Wk1, Arel + (l * 3 + 2) * HDD, L + 4 * AR_R); break;
        case 5: foldT_dev(Wv0, Mrel + (l * 3 + 0) * HDD, L + 5 * AR_R); break;
        case 6: foldT_dev(Wv0, Mrel + (l * 3 + 1) * HDD, L + 6 * AR_R); break;
        case 7: foldT_dev(Wv1, Mrel + (l * 3 + 2) * HDD, L + 7 * AR_R); break;
        case 8: cvtT_dev(Wa + (l * 2 + 0) * CC, L + 8 * AR_R); break;
        case 9: cvtT_dev(Wa + (l * 2 + 1) * CC, L + 9 * AR_R); break;
    }
}

__global__ __launch_bounds__(256) void prep_stack_k(const float* __restrict__ Wsh,
                                                    _Float16* __restrict__ SA) {
    cvtT_dev(Wsh + (size_t)blockIdx.y * 65536, SA + (size_t)blockIdx.y * AR_R);
}

__global__ __launch_bounds__(256) void prep_heads_k(const float* __restrict__ Wt1,
                                                    _Float16* __restrict__ HA) {
    const int o = blockIdx.x, k = blockIdx.y, c = threadIdx.x;
    HA[(size_t)(k * 128 + o) * 256 + c] =
        (_Float16)Wt1[(size_t)k * 256 * 128 + (size_t)c * 128 + o];
}

// ---------------------------------------------------------------------------
// fp16 MFMA GEMM body (BK=64). Staging via global_load_lds width=16:
// LDS written LINEARLY (wave-uniform base + lane*16); the XOR swizzle is
// applied to the per-lane GLOBAL source byte-col (cb), so LDS[r][pc] holds
// global[r][pc ^ swz(r)]; the read side XORs again -> identity.
// ---------------------------------------------------------------------------
template <int EPI, bool SPLIT>
__device__ __forceinline__ void gemm_body(
    const _Float16* __restrict__ A, const _Float16* __restrict__ Bt,
    _Float16* __restrict__ C, int M, int Nc, int bm, int bn, size_t bufStride,
    const float* __restrict__ bias, const float* __restrict__ skipv,
    _Float16* As, _Float16* Bs) {
    const int tid = threadIdx.x;
    const int wave = tid >> 6, lane = tid & 63;
    const int wm = (wave >> 1) * 64, wn = (wave & 1) * 64;
    const int l15 = lane & 15, g = lane >> 4;

    f32x4 acc[4][4] = {};

    for (int k0 = 0; k0 < 256; k0 += 64) {
        __syncthreads();
#pragma unroll
        for (int p = 0; p < 4; ++p) {
            const int slot = p * 256 + tid;       // 0..1023 (16B slots)
            const int r = slot >> 3;              // row 0..127
            const int cb = ((slot & 7) << 4) ^ ((r & 7) << 4);  // swz byte col
            int gr = bm + r; if (gr >= M) gr = M - 1;
            __builtin_amdgcn_global_load_lds(
                (const __attribute__((address_space(1))) void*)
                    ((const char*)A + ((size_t)gr * 256 + k0) * 2 + cb),
                (__attribute__((address_space(3))) void*)((char*)As + slot * 16),
                16, 0, 0);
            __builtin_amdgcn_global_load_lds(
                (const __attribute__((address_space(1))) void*)
                    ((const char*)Bt + ((size_t)(bn + r) * 256 + k0) * 2 + cb),
                (__attribute__((address_space(3))) void*)((char*)Bs + slot * 16),
                16, 0, 0);
        }
        __syncthreads();
#pragma unroll
        for (int sub = 0; sub < 2; ++sub) {
            f16x8 af[4], bf[4];
#pragma unroll
            for (int i = 0; i < 4; ++i) {
                const int ra = wm + i * 16 + l15;
                const int rb = wn + i * 16 + l15;
                const int ka = (sub * 64 + g * 16) ^ ((ra & 7) << 4);
                const int kb = (sub * 64 + g * 16) ^ ((rb & 7) << 4);
                af[i] = *(const f16x8*)((const char*)As + ra * 128 + ka);
                bf[i] = *(const f16x8*)((const char*)Bs + rb * 128 + kb);
            }
#pragma unroll
            for (int mi = 0; mi < 4; ++mi)
#pragma unroll
                for (int ni = 0; ni < 4; ++ni)
                    acc[mi][ni] = __builtin_amdgcn_mfma_f32_16x16x32_f16(
                        af[mi], bf[ni], acc[mi][ni], 0, 0, 0);
        }
    }

    float be = 0.f, ombe = 0.f;
    if (EPI == 1) {
        const float s = skipv[0];
        be = 1.0f / (1.0f + expf(-s));
        ombe = 1.0f - be;
    }
#pragma unroll
    for (int mi = 0; mi < 4; ++mi) {
#pragma unroll
        for (int r = 0; r < 4; ++r) {
            const int row = bm + wm + mi * 16 + g * 4 + r;
            if (row >= M) continue;
#pragma unroll
            for (int ni = 0; ni < 4; ++ni) {
                const int colg = bn + wn + ni * 16 + l15;
                float v = acc[mi][ni][r];
                size_t idx;
                if (SPLIT)
                    idx = (size_t)(colg >> 8) * bufStride + (size_t)row * 256 +
                          (colg & 255);
                else
                    idx = (size_t)row * Nc + colg;
                if (EPI == 1) v = be * v + ombe * (float)C[idx];
                if (EPI == 2) v = fmaxf(v + bias[colg], 0.f);
                C[idx] = (_Float16)v;
            }
        }
    }
}

// Grid = (cols, row_panels): consecutive blocks share the A row-panel (L2).
template <int EPI, bool SPLIT>
__global__ __launch_bounds__(256) void gemm_h(
    const _Float16* __restrict__ A, const _Float16* __restrict__ Bt,
    _Float16* __restrict__ C, int M, int Nc, size_t bufStride,
    const float* __restrict__ bias, const float* __restrict__ skipv) {
    __shared__ _Float16 As[128 * 64];
    __shared__ _Float16 Bs[128 * 64];
    gemm_body<EPI, SPLIT>(A, Bt, C, M, Nc, blockIdx.y * 128, blockIdx.x * 128,
                          bufStride, bias, skipv, As, Bs);
}

// Fused skip-updates; grid = (4, row_panels). x>>1: 0 -> xe, 1 -> xs.
__global__ __launch_bounds__(256) void update2_k(
    const _Float16* __restrict__ aggE, const _Float16* __restrict__ aggS,
    const _Float16* __restrict__ WaT0, const _Float16* __restrict__ WaT1,
    _Float16* __restrict__ xeH, _Float16* __restrict__ xsH,
    const float* __restrict__ skipb, int M) {
    __shared__ _Float16 As[128 * 64];
    __shared__ _Float16 Bs[128 * 64];
    const int sel = blockIdx.x >> 1;
    const int bn = (blockIdx.x & 1) * 128;
    const int bm = blockIdx.y * 128;
    if (sel == 0)
        gemm_body<1, false>(aggE, WaT0, xeH, M, 256, bm, bn, 0, nullptr, skipb,
                            As, Bs);
    else
        gemm_body<1, false>(aggS, WaT1, xsH, M, 256, bm, bn, 0, nullptr,
                            skipb + 1, As, Bs);
}

// ---------------------------------------------------------------------------
// CSR build: hist -> 3-phase parallel scan -> scatter (colsrc).
// ---------------------------------------------------------------------------
__global__ __launch_bounds__(256) void hist3_k(const int* __restrict__ d0,
                                               const int* __restrict__ d1,
                                               const int* __restrict__ d2,
                                               int* __restrict__ cnt, int N,
                                               int E) {
    const int i = blockIdx.x * 256 + threadIdx.x;
    if (i >= E) return;
    const int r = blockIdx.y;
    const int* d = r == 0 ? d0 : r == 1 ? d1 : d2;
    atomicAdd(&cnt[(size_t)r * N + d[i]], 1);
}

// phase 1: per-block partial sums of cnt (256 elems/block)
__global__ __launch_bounds__(256) void partial_k(const int* __restrict__ cnt,
                                                 int* __restrict__ partials,
                                                 int N, int PB) {
    const int r = blockIdx.y, b = blockIdx.x, tid = threadIdx.x;
    const int gi = b * 256 + tid;
    int v = (gi < N) ? cnt[(size_t)r * N + gi] : 0;
#pragma unroll
    for (int o = 1; o < 64; o <<= 1) v += __shfl_xor(v, o);
    __shared__ int ws[4];
    if ((tid & 63) == 0) ws[tid >> 6] = v;
    __syncthreads();
    if (tid == 0) partials[r * PB + b] = ws[0] + ws[1] + ws[2] + ws[3];
}

// phase 2: exclusive scan of the PB (<=256) partials per relation; rp[N]=E.
__global__ __launch_bounds__(256) void scanp_k(int* __restrict__ partials,
                                               int* __restrict__ rp, int N,
                                               int PB, int E) {
    __shared__ int lds[256];
    const int r = blockIdx.y, tid = threadIdx.x;
    const int v = (tid < PB) ? partials[r * PB + tid] : 0;
    lds[tid] = v;
    __syncthreads();
    int acc = v;
    for (int off = 1; off < 256; off <<= 1) {
        const int t = (tid >= off) ? lds[tid - off] : 0;
        __syncthreads();
        acc += t;
        lds[tid] = acc;
        __syncthreads();
    }
    if (tid < PB) partials[r * PB + tid] = acc - v;  // exclusive
    if (tid == 0) rp[(size_t)r * (N + 1) + N] = E;
}

// phase 3: per-block exclusive scan + partial offset -> rp.
__global__ __launch_bounds__(256) void rpwrite_k(const int* __restrict__ cnt,
                                                 const int* __restrict__ partials,
                                                 int* __restrict__ rp, int N,
                                                 int PB) {
    __shared__ int lds[256];
    const int r = blockIdx.y, b = blockIdx.x, tid = threadIdx.x;
    const int gi = b * 256 + tid;
    const int v = (gi < N) ? cnt[(size_t)r * N + gi] : 0;
    lds[tid] = v;
    __syncthreads();
    int acc = v;
    for (int off = 1; off < 256; off <<= 1) {
        const int t = (tid >= off) ? lds[tid - off] : 0;
        __syncthreads();
        acc += t;
        lds[tid] = acc;
        __syncthreads();
    }
    if (gi < N) rp[(size_t)r * (N + 1) + gi] = partials[r * PB + b] + acc - v;
}

__global__ __launch_bounds__(256) void scatter3_k(
    const int* __restrict__ d0, const int* __restrict__ d1,
    const int* __restrict__ d2, const int* __restrict__ s0_,
    const int* __restrict__ s1_, const int* __restrict__ s2_,
    const int* __restrict__ rp, int* __restrict__ fill,
    int* __restrict__ colsrc, int N, int E) {
    const int i = blockIdx.x * 256 + threadIdx.x;
    if (i >= E) return;
    const int r = blockIdx.y;
    const int* d = r == 0 ? d0 : r == 1 ? d1 : d2;
    const int* s = r == 0 ? s0_ : r == 1 ? s1_ : s2_;
    const int dd = d[i];
    const int p = rp[(size_t)r * (N + 1) + dd] + atomicAdd(&fill[(size_t)r * N + dd], 1);
    colsrc[(size_t)r * E + p] = s[i];
}

// ---------------------------------------------------------------------------
// Scoring: wave per dst; 16 lanes per edge, 4 edges in flight.
// ---------------------------------------------------------------------------
__device__ __forceinline__ void score_rel_g(
    const f16x8 q0, const f16x8 q1, const _Float16* __restrict__ kA,
    const int* __restrict__ cs, int beg, int end, float scl,
    float* __restrict__ sc, int grp, int j, float& m) {
    for (int i = beg + grp; i < end; i += 4) {
        const int s = cs[i];
        const _Float16* row = &kA[(size_t)s * 256 + j * 16];
        const f16x8 k0 = *(const f16x8*)row;
        const f16x8 k1 = *(const f16x8*)(row + 8);
        float p = dot8f(q1, k1, dot8f(q0, k0, 0.f));
        p += __shfl_xor(p, 1);
        p += __shfl_xor(p, 2);
        const float v = p * scl;
        if ((j & 3) == 0) {
            sc[(size_t)i * 4 + (j >> 2)] = v;
            m = fmaxf(m, v);
        }
    }
}

__global__ __launch_bounds__(256) void score3_k(
    const _Float16* __restrict__ qe, const _Float16* __restrict__ kA0,
    const _Float16* __restrict__ kA1, const _Float16* __restrict__ qs,
    const _Float16* __restrict__ kA2, const int* __restrict__ rp,
    const int* __restrict__ colsrc, const float* __restrict__ muL,
    float* __restrict__ sc, float* __restrict__ mx_e,
    float* __restrict__ mx_s, int N, int E) {
    const int wid = (blockIdx.x * blockDim.x + threadIdx.x) >> 6;
    if (wid >= N) return;
    const int lane = threadIdx.x & 63;
    const int grp = lane >> 4, j = lane & 15, h = j >> 2;
    const size_t E4 = (size_t)E * 4;
    float m = -1e30f;
    if (blockIdx.y == 0) {
        const _Float16* qrow = &qe[(size_t)wid * 256 + j * 16];
        const f16x8 q0 = *(const f16x8*)qrow;
        const f16x8 q1 = *(const f16x8*)(qrow + 8);
        score_rel_g(q0, q1, kA0, colsrc, rp[wid], rp[wid + 1],
                    muL[0 * 4 + h] * 0.125f, sc, grp, j, m);
        const int* rp2 = rp + 2 * (N + 1);
        score_rel_g(q0, q1, kA2, colsrc + 2 * (size_t)E, rp2[wid], rp2[wid + 1],
                    muL[2 * 4 + h] * 0.125f, sc + 2 * E4, grp, j, m);
        m = fmaxf(m, __shfl_xor(m, 16));
        m = fmaxf(m, __shfl_xor(m, 32));
        if (grp == 0 && (j & 3) == 0) mx_e[(size_t)wid * 4 + h] = m;
    } else {
        const _Float16* qrow = &qs[(size_t)wid * 256 + j * 16];
        const f16x8 q0 = *(const f16x8*)qrow;
        const f16x8 q1 = *(const f16x8*)(qrow + 8);
        const int* rp1 = rp + (N + 1);
        score_rel_g(q0, q1, kA1, colsrc + (size_t)E, rp1[wid], rp1[wid + 1],
                    muL[1 * 4 + h] * 0.125f, sc + E4, grp, j, m);
        m = fmaxf(m, __shfl_xor(m, 16));
        m = fmaxf(m, __shfl_xor(m, 32));
        if (grp == 0 && (j & 3) == 0) mx_s[(size_t)wid * 4 + h] = m;
    }
}

// ---------------------------------------------------------------------------
// Aggregation (single-pass online): per edge w = exp(s-m); den += w;
// acc += w*v. Cross-group combine, normalize, distributed GELU, f16x4 store.
// ---------------------------------------------------------------------------
__device__ __forceinline__ void agg_rel_on(
    const float* __restrict__ sc, const _Float16* __restrict__ vM,
    const int* __restrict__ cs, int beg, int end, float mh, int grp, int j,
    int h, float* accf, float& den) {
    for (int i = beg + grp; i < end; i += 4) {
        const int s = cs[i];
        const float w = expf(sc[(size_t)i * 4 + h] - mh);
        den += w;
        const _Float16* row = &vM[(size_t)s * 256 + j * 16];
        const f16x8 v0 = *(const f16x8*)row;
        const f16x8 v1 = *(const f16x8*)(row + 8);
#pragma unroll
        for (int t = 0; t < 8; ++t) accf[t] += w * (float)v0[t];
#pragma unroll
        for (int t = 0; t < 8; ++t) accf[8 + t] += w * (float)v1[t];
    }
}

__global__ __launch_bounds__(256) void agg3_k(
    const float* __restrict__ sc, const _Float16* __restrict__ vM0,
    const _Float16* __restrict__ vM1, const _Float16* __restrict__ vM2,
    const int* __restrict__ rp, const int* __restrict__ colsrc,
    const float* __restrict__ mx_e, const float* __restrict__ mx_s,
    _Float16* __restrict__ outE, _Float16* __restrict__ outS, int N, int E) {
    const int wid = (blockIdx.x * blockDim.x + threadIdx.x) >> 6;
    if (wid >= N) return;
    const int lane = threadIdx.x & 63;
    const int grp = lane >> 4, j = lane & 15, h = j >> 2;
    const size_t E4 = (size_t)E * 4;
    float accf[16] = {};
    float den = 0.f;
    _Float16* outp;
    if (blockIdx.y == 0) {
        const float mh = mx_e[(size_t)wid * 4 + h];
        const int b0 = rp[wid], e0 = rp[wid + 1];
        const int* rp2 = rp + 2 * (N + 1);
        const int b2 = rp2[wid], e2 = rp2[wid + 1];
        agg_rel_on(sc, vM0, colsrc, b0, e0, mh, grp, j, h, accf, den);
        agg_rel_on(sc + 2 * E4, vM2, colsrc + 2 * (size_t)E, b2, e2, mh, grp,
                   j, h, accf, den);
        outp = outE;
    } else {
        const float mh = mx_s[(size_t)wid * 4 + h];
        const int* rp1 = rp + (N + 1);
        const int b1 = rp1[wid], e1 = rp1[wid + 1];
        agg_rel_on(sc + E4, vM1, colsrc + (size_t)E, b1, e1, mh, grp, j, h,
                   accf, den);
        outp = outS;
    }
    den += __shfl_xor(den, 16);
    den += __shfl_xor(den, 32);
#pragma unroll
    for (int t = 0; t < 16; ++t) {
        accf[t] += __shfl_xor(accf[t], 16);
        accf[t] += __shfl_xor(accf[t], 32);
    }
    const float dinv = 1.0f / (den + 1e-16f);
    f16x4 o;
#pragma unroll
    for (int t = 0; t < 4; ++t)
        o[t] = (_Float16)gelu_f(accf[grp * 4 + t] * dinv);
    *(f16x4*)&outp[(size_t)wid * 256 + j * 16 + grp * 4] = o;
}

// ---------------------------------------------------------------------------
// Batched head epilogue.
// ---------------------------------------------------------------------------
__global__ __launch_bounds__(256) void head2_k(const _Float16* __restrict__ t,
                                               const float* __restrict__ Wt2,
                                               const float* __restrict__ bt2,
                                               float* __restrict__ out, int M) {
    const int k = blockIdx.y;
    __shared__ float Ws[128 * 8];
    __shared__ float bs[8];
    const int tid = threadIdx.x;
    const float* W2 = Wt2 + (size_t)k * 1024;
    for (int i = tid; i < 1024; i += 256) Ws[i] = W2[i];
    if (tid < 8) bs[tid] = bt2[k * 8 + tid];
    __syncthreads();
    const int OFFA[7] = {0, 3, 6, 9, 14, 15, 16};
    const int DIMSA[7] = {3, 3, 3, 5, 1, 1, 8};
    const int nl = tid >> 3, o = tid & 7;
    const int n = blockIdx.x * 32 + nl;
    if (n >= M) return;
    const _Float16* tr = &t[(size_t)n * 896 + k * 128];
    float acc = bs[o];
#pragma unroll 8
    for (int d = 0; d < 128; ++d) acc += (float)tr[d] * Ws[d * 8 + o];
    if (o < DIMSA[k]) out[(size_t)n * 24 + OFFA[k] + o] = acc;
}

// ---------------------------------------------------------------------------

extern "C" void kernel_launch(void* const* d_in, const int* in_sizes, int n_in,
                              void* d_out, int out_size, void* d_ws,
                              size_t ws_size, hipStream_t stream) {
    const float* xe_in = (const float*)d_in[0];
    const float* xs_in = (const float*)d_in[1];
    const int* ee_src = (const int*)d_in[2];
    const int* ee_dst = (const int*)d_in[3];
    const int* es_src = (const int*)d_in[4];
    const int* es_dst = (const int*)d_in[5];
    const int* se_src = (const int*)d_in[6];
    const int* se_dst = (const int*)d_in[7];
    const float* Wk = (const float*)d_in[8];
    const float* Wq = (const float*)d_in[9];
    const float* Wv = (const float*)d_in[10];
    const float* Wa = (const float*)d_in[11];
    const float* skip = (const float*)d_in[12];
    const float* Arel = (const float*)d_in[13];
    const float* Mrel = (const float*)d_in[14];
    const float* mu = (const float*)d_in[15];
    const float* Wsh = (const float*)d_in[16];
    const float* bsh = (const float*)d_in[17];
    const float* Wt1 = (const float*)d_in[18];
    const float* bt1 = (const float*)d_in[19];
    const float* Wt2 = (const float*)d_in[20];
    const float* bt2 = (const float*)d_in[21];
    float* out = (float*)d_out;

    const int N = in_sizes[0] / CDIM;  // 50000
    const int E = in_sizes[2];         // 200000
    const size_t NC = (size_t)N * CDIM;
    const size_t E4 = (size_t)E * 4;
    const size_t N4 = (size_t)N * 4;
    const int PB = (N + 255) / 256;  // 196 (<= 256 assumed)

    const size_t halfs = 7 * NC + 32 * (size_t)AR_R + 7 * 32768;
    const size_t floats = 3 * E4 + 2 * N4;
    const size_t ints =
        3 * (size_t)(N + 1) + 3 * (size_t)E + 3 * (size_t)N + 3 * (size_t)PB;
    const size_t need = halfs * 2 + floats * 4 + ints * 4;
    if (ws_size < need) return;

    _Float16* xeH = (_Float16*)d_ws;
    _Float16* xsH = xeH + NC;
    _Float16* Hb = xsH + NC;
    _Float16* H1 = Hb;
    _Float16* H2 = Hb + NC;
    _Float16* H3 = Hb + 2 * NC;
    _Float16* H4 = Hb + 3 * NC;
    _Float16* H5 = Hb + 4 * NC;
    _Float16* arena = Hb + 5 * NC;
    _Float16* SA = arena + (size_t)30 * AR_R;
    _Float16* HA = SA + (size_t)2 * AR_R;
    float* sc = (float*)(HA + (size_t)7 * 32768);
    float* mx_e = sc + 3 * E4;
    float* mx_s = mx_e + N4;
    int* rp = (int*)(mx_s + N4);
    int* colsrc = rp + 3 * (size_t)(N + 1);
    int* cnt = colsrc + 3 * (size_t)E;
    int* partials = cnt + 3 * (size_t)N;

    const int gx = (N + 127) / 128;
    const dim3 e3((E + 255) / 256, 3);
    const dim3 p3(PB, 3);
    const int wave_blocks = (N + 3) / 4;
    const int zc_blocks = (3 * N + 255) / 256;

    // ---- CSR build (parallel 3-phase scan) ----
    zero_k<<<zc_blocks, 256, 0, stream>>>(cnt, 3 * (size_t)N);
    hist3_k<<<e3, 256, 0, stream>>>(ee_dst, es_dst, se_dst, cnt, N, E);
    partial_k<<<p3, 256, 0, stream>>>(cnt, partials, N, PB);
    scanp_k<<<dim3(1, 3), 256, 0, stream>>>(partials, rp, N, PB, E);
    rpwrite_k<<<p3, 256, 0, stream>>>(cnt, partials, rp, N, PB);
    zero_k<<<zc_blocks, 256, 0, stream>>>(cnt, 3 * (size_t)N);
    scatter3_k<<<e3, 256, 0, stream>>>(ee_dst, es_dst, se_dst, ee_src, es_src,
                                       se_src, rp, cnt, colsrc, N, E);

    // ---- weight prep ----
    for (int l = 0; l < 3; ++l)
        prep_layer_k<<<dim3(256, 10), 256, 0, stream>>>(Wk, Wq, Wv, Wa, Arel,
                                                        Mrel, l, arena);
    prep_stack_k<<<dim3(256, 2), 256, 0, stream>>>(Wsh, SA);
    prep_heads_k<<<dim3(128, 7), 256, 0, stream>>>(Wt1, HA);

    // ---- initial fp16 activations ----
    cvt_k<<<1024, 256, 0, stream>>>(xe_in, xeH, NC / 4);
    cvt_k<<<1024, 256, 0, stream>>>(xs_in, xsH, NC / 4);

    for (int l = 0; l < 3; ++l) {
        _Float16* L = arena + (size_t)l * 10 * AR_R;
        gemm_h<0, true><<<dim3(6, gx), 256, 0, stream>>>(
            xeH, L, H1, N, 768, NC, nullptr, nullptr);  // q_e|kA0|kA1
        gemm_h<0, true><<<dim3(4, gx), 256, 0, stream>>>(
            xsH, L + 3 * AR_R, H4, N, 512, NC, nullptr, nullptr);  // q_s|kA2
        score3_k<<<dim3(wave_blocks, 2), 256, 0, stream>>>(
            H1, H2, H3, H4, H5, rp, colsrc, mu + l * 12, sc, mx_e, mx_s, N, E);
        gemm_h<0, true><<<dim3(4, gx), 256, 0, stream>>>(
            xeH, L + 5 * AR_R, H2, N, 512, NC, nullptr, nullptr);  // vM0|vM1
        gemm_h<0, false><<<dim3(2, gx), 256, 0, stream>>>(
            xsH, L + 7 * AR_R, H5, N, 256, 0, nullptr, nullptr);  // vM2
        agg3_k<<<dim3(wave_blocks, 2), 256, 0, stream>>>(
            sc, H2, H3, H5, rp, colsrc, mx_e, mx_s, H1, H4, N, E);
        update2_k<<<dim3(4, gx), 256, 0, stream>>>(
            H1, H4, L + 8 * AR_R, L + 9 * AR_R, xeH, xsH, skip + l * 2, N);
    }

    // shared linear stack
    gemm_h<2, false><<<dim3(2, gx), 256, 0, stream>>>(xeH, SA, H5, N, 256, 0,
                                                      bsh, nullptr);
    gemm_h<2, false><<<dim3(2, gx), 256, 0, stream>>>(H5, SA + AR_R, xsH, N,
                                                      256, 0, bsh + 256, nullptr);
    // 7 task heads
    gemm_h<2, false><<<dim3(7, gx), 256, 0, stream>>>(xsH, HA, Hb, N, 896, 0,
                                                      bt1, nullptr);
    head2_k<<<dim3((N + 31) / 32, 7), 256, 0, stream>>>(Hb, Wt2, bt2, out, N);
}

// Round 12
// 1048.071 us; speedup vs baseline: 9.8513x; 1.0480x over previous
//
#include <hip/hip_runtime.h>
#include <hip/hip_fp16.h>
#include <cmath>

// ---------------------------------------------------------------------------
// DragonHGT R12: consolidated dispatches (job-table projection GEMMs) +
// __expf in the aggregation hot loop. fp16 MFMA GEMMs (BK=64, XOR LDS via
// pre-swizzled global_load_lds), CSR edge pipeline (16-lane groups).
// N=50000 x 2 node types, E=200000 x 3 relations, C=256 (H=4, D=64).
// ---------------------------------------------------------------------------

#define CDIM 256
#define AR_R (256 * 256)

using f16x8 = __attribute__((ext_vector_type(8))) _Float16;
using f16x4 = __attribute__((ext_vector_type(4))) _Float16;
using f16x2 = __attribute__((ext_vector_type(2))) _Float16;
using f32x4 = __attribute__((ext_vector_type(4))) float;

__device__ __forceinline__ float gelu_f(float x) {
    return 0.5f * x * (1.0f + erff(x * 0.70710678118654752f));
}

__device__ __forceinline__ float dot8f(const f16x8 a, const f16x8 b, float r) {
#if __has_builtin(__builtin_amdgcn_fdot2)
#pragma unroll
    for (int t = 0; t < 4; ++t) {
        f16x2 av = {a[2 * t], a[2 * t + 1]};
        f16x2 bv = {b[2 * t], b[2 * t + 1]};
        r = __builtin_amdgcn_fdot2(av, bv, r, false);
    }
#else
#pragma unroll
    for (int t = 0; t < 8; ++t) r += (float)a[t] * (float)b[t];
#endif
    return r;
}

__global__ __launch_bounds__(256) void zero_k(int* __restrict__ p, size_t n) {
    size_t i = (size_t)blockIdx.x * blockDim.x + threadIdx.x;
    const size_t stride = (size_t)gridDim.x * blockDim.x;
    for (; i < n; i += stride) p[i] = 0;
}

// both initial fp32->fp16 conversions in one dispatch (grid.y selects)
__global__ __launch_bounds__(256) void cvt2_k(const float* __restrict__ xe_in,
                                              const float* __restrict__ xs_in,
                                              _Float16* __restrict__ xeH,
                                              _Float16* __restrict__ xsH,
                                              size_t n4) {
    const float* in = blockIdx.y ? xs_in : xe_in;
    _Float16* out = blockIdx.y ? xsH : xeH;
    size_t i = (size_t)blockIdx.x * blockDim.x + threadIdx.x;
    const size_t stride = (size_t)gridDim.x * blockDim.x;
    for (; i < n4; i += stride) {
        const float4 v = ((const float4*)in)[i];
        f16x4 o;
        o[0] = (_Float16)v.x; o[1] = (_Float16)v.y;
        o[2] = (_Float16)v.z; o[3] = (_Float16)v.w;
        ((f16x4*)out)[i] = o;
    }
}

// ---------------------------------------------------------------------------
// Weight prep (single dispatch for all 3 layers: grid (256, 30)).
// ---------------------------------------------------------------------------
__device__ __forceinline__ void cvtT_dev(const float* __restrict__ W,
                                         _Float16* __restrict__ dst) {
    const int o = blockIdx.x, c = threadIdx.x;
    dst[(size_t)o * 256 + c] = (_Float16)W[(size_t)c * 256 + o];
}

__device__ __forceinline__ void foldT_dev(const float* __restrict__ Wbase,
                                          const float* __restrict__ T,
                                          _Float16* __restrict__ dst) {
    __shared__ float row[256];
    const int c = blockIdx.x, t = threadIdx.x;
    row[t] = Wbase[(size_t)c * 256 + t];
    __syncthreads();
    const int h = t >> 6, f = t & 63;
    const float* Th = T + h * 4096;
    float acc = 0.f;
#pragma unroll 8
    for (int d = 0; d < 64; ++d) acc += row[h * 64 + d] * Th[d * 64 + f];
    dst[(size_t)t * 256 + c] = (_Float16)acc;
}

// arena per layer: [0]q_e [1]kA0 [2]kA1 [3]q_s [4]kA2 [5]vM0 [6]vM1 [7]vM2
//                  [8]WaT0 [9]WaT1
__global__ __launch_bounds__(256) void prep_layer_k(
    const float* __restrict__ Wk, const float* __restrict__ Wq,
    const float* __restrict__ Wv, const float* __restrict__ Wa,
    const float* __restrict__ Arel, const float* __restrict__ Mrel,
    _Float16* __restrict__ arena) {
    const size_t CC = 65536, HDD = 16384;
    const int l = blockIdx.y / 10;
    const int c = blockIdx.y % 10;
    _Float16* L = arena + (size_t)l * 10 * AR_R;
    const float* Wk0 = Wk + (l * 2 + 0) * CC;
    const float* Wk1 = Wk + (l * 2 + 1) * CC;
    const float* Wv0 = Wv + (l * 2 + 0) * CC;
    const float* Wv1 = Wv + (l * 2 + 1) * CC;
    switch (c) {
        case 0: cvtT_dev(Wq + (l * 2 + 0) * CC, L); break;
        case 1: foldT_dev(Wk0, Arel + (l * 3 + 0) * HDD, L + 1 * AR_R); break;
        case 2: foldT_dev(Wk0, Arel + (l * 3 + 1) * HDD, L + 2 * AR_R); break;
        case 3: cvtT_dev(Wq + (l * 2 + 1) * CC, L + 3 * AR_R); break;
        case 4: foldT_dev(Wk1, Arel + (l * 3 + 2) * HDD, L + 4 * AR_R); break;
        case 5: foldT_dev(Wv0, Mrel + (l * 3 + 0) * HDD, L + 5 * AR_R); break;
        case 6: foldT_dev(Wv0, Mrel + (l * 3 + 1) * HDD, L + 6 * AR_R); break;
        case 7: foldT_dev(Wv1, Mrel + (l * 3 + 2) * HDD, L + 7 * AR_R); break;
        case 8: cvtT_dev(Wa + (l * 2 + 0) * CC, L + 8 * AR_R); break;
        case 9: cvtT_dev(Wa + (l * 2 + 1) * CC, L + 9 * AR_R); break;
    }
}

__global__ __launch_bounds__(256) void prep_stack_k(const float* __restrict__ Wsh,
                                                    _Float16* __restrict__ SA) {
    cvtT_dev(Wsh + (size_t)blockIdx.y * 65536, SA + (size_t)blockIdx.y * AR_R);
}

__global__ __launch_bounds__(256) void prep_heads_k(const float* __restrict__ Wt1,
                                                    _Float16* __restrict__ HA) {
    const int o = blockIdx.x, k = blockIdx.y, c = threadIdx.x;
    HA[(size_t)(k * 128 + o) * 256 + c] =
        (_Float16)Wt1[(size_t)k * 256 * 128 + (size_t)c * 128 + o];
}

// ---------------------------------------------------------------------------
// fp16 MFMA GEMM body (BK=64; global_load_lds width=16, pre-swizzled source).
// ---------------------------------------------------------------------------
template <int EPI, bool SPLIT>
__device__ __forceinline__ void gemm_body(
    const _Float16* __restrict__ A, const _Float16* __restrict__ Bt,
    _Float16* __restrict__ C, int M, int Nc, int bm, int bn, size_t bufStride,
    const float* __restrict__ bias, const float* __restrict__ skipv,
    _Float16* As, _Float16* Bs) {
    const int tid = threadIdx.x;
    const int wave = tid >> 6, lane = tid & 63;
    const int wm = (wave >> 1) * 64, wn = (wave & 1) * 64;
    const int l15 = lane & 15, g = lane >> 4;

    f32x4 acc[4][4] = {};

    for (int k0 = 0; k0 < 256; k0 += 64) {
        __syncthreads();
#pragma unroll
        for (int p = 0; p < 4; ++p) {
            const int slot = p * 256 + tid;
            const int r = slot >> 3;
            const int cb = ((slot & 7) << 4) ^ ((r & 7) << 4);
            int gr = bm + r; if (gr >= M) gr = M - 1;
            __builtin_amdgcn_global_load_lds(
                (const __attribute__((address_space(1))) void*)
                    ((const char*)A + ((size_t)gr * 256 + k0) * 2 + cb),
                (__attribute__((address_space(3))) void*)((char*)As + slot * 16),
                16, 0, 0);
            __builtin_amdgcn_global_load_lds(
                (const __attribute__((address_space(1))) void*)
                    ((const char*)Bt + ((size_t)(bn + r) * 256 + k0) * 2 + cb),
                (__attribute__((address_space(3))) void*)((char*)Bs + slot * 16),
                16, 0, 0);
        }
        __syncthreads();
#pragma unroll
        for (int sub = 0; sub < 2; ++sub) {
            f16x8 af[4], bf[4];
#pragma unroll
            for (int i = 0; i < 4; ++i) {
                const int ra = wm + i * 16 + l15;
                const int rb = wn + i * 16 + l15;
                const int ka = (sub * 64 + g * 16) ^ ((ra & 7) << 4);
                const int kb = (sub * 64 + g * 16) ^ ((rb & 7) << 4);
                af[i] = *(const f16x8*)((const char*)As + ra * 128 + ka);
                bf[i] = *(const f16x8*)((const char*)Bs + rb * 128 + kb);
            }
#pragma unroll
            for (int mi = 0; mi < 4; ++mi)
#pragma unroll
                for (int ni = 0; ni < 4; ++ni)
                    acc[mi][ni] = __builtin_amdgcn_mfma_f32_16x16x32_f16(
                        af[mi], bf[ni], acc[mi][ni], 0, 0, 0);
        }
    }

    float be = 0.f, ombe = 0.f;
    if (EPI == 1) {
        const float s = skipv[0];
        be = 1.0f / (1.0f + expf(-s));
        ombe = 1.0f - be;
    }
#pragma unroll
    for (int mi = 0; mi < 4; ++mi) {
#pragma unroll
        for (int r = 0; r < 4; ++r) {
            const int row = bm + wm + mi * 16 + g * 4 + r;
            if (row >= M) continue;
#pragma unroll
            for (int ni = 0; ni < 4; ++ni) {
                const int colg = bn + wn + ni * 16 + l15;
                float v = acc[mi][ni][r];
                size_t idx;
                if (SPLIT)
                    idx = (size_t)(colg >> 8) * bufStride + (size_t)row * 256 +
                          (colg & 255);
                else
                    idx = (size_t)row * Nc + colg;
                if (EPI == 1) v = be * v + ombe * (float)C[idx];
                if (EPI == 2) v = fmaxf(v + bias[colg], 0.f);
                C[idx] = (_Float16)v;
            }
        }
    }
}

// Generic GEMM (grid = (cols, row_panels)).
template <int EPI, bool SPLIT>
__global__ __launch_bounds__(256) void gemm_h(
    const _Float16* __restrict__ A, const _Float16* __restrict__ Bt,
    _Float16* __restrict__ C, int M, int Nc, size_t bufStride,
    const float* __restrict__ bias, const float* __restrict__ skipv) {
    __shared__ _Float16 As[128 * 64];
    __shared__ _Float16 Bs[128 * 64];
    gemm_body<EPI, SPLIT>(A, Bt, C, M, Nc, blockIdx.y * 128, blockIdx.x * 128,
                          bufStride, bias, skipv, As, Bs);
}

// Q/K projection super-dispatch: 5 jobs x 2 col-panels, grid (10, gx).
// job: 0 q_e<-xe, 1 kA0<-xe, 2 kA1<-xe, 3 q_s<-xs, 4 kA2<-xs -> Hb+job*NC.
__global__ __launch_bounds__(256) void projq_k(
    const _Float16* __restrict__ xeH, const _Float16* __restrict__ xsH,
    const _Float16* __restrict__ L, _Float16* __restrict__ Hb, int M) {
    __shared__ _Float16 As[128 * 64];
    __shared__ _Float16 Bs[128 * 64];
    const int job = blockIdx.x >> 1;
    const int bn = (blockIdx.x & 1) * 128;
    const _Float16* A = (job < 3) ? xeH : xsH;
    const _Float16* Bt = L + (size_t)job * AR_R;
    _Float16* C = Hb + (size_t)job * (size_t)M * 256;
    gemm_body<0, false>(A, Bt, C, M, 256, blockIdx.y * 128, bn, 0, nullptr,
                        nullptr, As, Bs);
}

// V projection super-dispatch: 3 jobs, grid (6, gx).
// job: 0 vM0<-xe -> H2, 1 vM1<-xe -> H3, 2 vM2<-xs -> H5.
__global__ __launch_bounds__(256) void projv_k(
    const _Float16* __restrict__ xeH, const _Float16* __restrict__ xsH,
    const _Float16* __restrict__ L, _Float16* __restrict__ Hb, int M) {
    __shared__ _Float16 As[128 * 64];
    __shared__ _Float16 Bs[128 * 64];
    const int job = blockIdx.x >> 1;
    const int bn = (blockIdx.x & 1) * 128;
    const _Float16* A = (job < 2) ? xeH : xsH;
    const _Float16* Bt = L + (size_t)(5 + job) * AR_R;
    const int dsti = (job == 0) ? 1 : (job == 1) ? 2 : 4;
    _Float16* C = Hb + (size_t)dsti * (size_t)M * 256;
    gemm_body<0, false>(A, Bt, C, M, 256, blockIdx.y * 128, bn, 0, nullptr,
                        nullptr, As, Bs);
}

// Fused skip-updates; grid = (4, row_panels). x>>1: 0 -> xe, 1 -> xs.
__global__ __launch_bounds__(256) void update2_k(
    const _Float16* __restrict__ aggE, const _Float16* __restrict__ aggS,
    const _Float16* __restrict__ WaT0, const _Float16* __restrict__ WaT1,
    _Float16* __restrict__ xeH, _Float16* __restrict__ xsH,
    const float* __restrict__ skipb, int M) {
    __shared__ _Float16 As[128 * 64];
    __shared__ _Float16 Bs[128 * 64];
    const int sel = blockIdx.x >> 1;
    const int bn = (blockIdx.x & 1) * 128;
    const int bm = blockIdx.y * 128;
    if (sel == 0)
        gemm_body<1, false>(aggE, WaT0, xeH, M, 256, bm, bn, 0, nullptr, skipb,
                            As, Bs);
    else
        gemm_body<1, false>(aggS, WaT1, xsH, M, 256, bm, bn, 0, nullptr,
                            skipb + 1, As, Bs);
}

// ---------------------------------------------------------------------------
// CSR build: hist -> 3-phase parallel scan -> scatter (colsrc).
// ---------------------------------------------------------------------------
__global__ __launch_bounds__(256) void hist3_k(const int* __restrict__ d0,
                                               const int* __restrict__ d1,
                                               const int* __restrict__ d2,
                                               int* __restrict__ cnt, int N,
                                               int E) {
    const int i = blockIdx.x * 256 + threadIdx.x;
    if (i >= E) return;
    const int r = blockIdx.y;
    const int* d = r == 0 ? d0 : r == 1 ? d1 : d2;
    atomicAdd(&cnt[(size_t)r * N + d[i]], 1);
}

__global__ __launch_bounds__(256) void partial_k(const int* __restrict__ cnt,
                                                 int* __restrict__ partials,
                                                 int N, int PB) {
    const int r = blockIdx.y, b = blockIdx.x, tid = threadIdx.x;
    const int gi = b * 256 + tid;
    int v = (gi < N) ? cnt[(size_t)r * N + gi] : 0;
#pragma unroll
    for (int o = 1; o < 64; o <<= 1) v += __shfl_xor(v, o);
    __shared__ int ws[4];
    if ((tid & 63) == 0) ws[tid >> 6] = v;
    __syncthreads();
    if (tid == 0) partials[r * PB + b] = ws[0] + ws[1] + ws[2] + ws[3];
}

__global__ __launch_bounds__(256) void scanp_k(int* __restrict__ partials,
                                               int* __restrict__ rp, int N,
                                               int PB, int E) {
    __shared__ int lds[256];
    const int r = blockIdx.y, tid = threadIdx.x;
    const int v = (tid < PB) ? partials[r * PB + tid] : 0;
    lds[tid] = v;
    __syncthreads();
    int acc = v;
    for (int off = 1; off < 256; off <<= 1) {
        const int t = (tid >= off) ? lds[tid - off] : 0;
        __syncthreads();
        acc += t;
        lds[tid] = acc;
        __syncthreads();
    }
    if (tid < PB) partials[r * PB + tid] = acc - v;
    if (tid == 0) rp[(size_t)r * (N + 1) + N] = E;
}

__global__ __launch_bounds__(256) void rpwrite_k(const int* __restrict__ cnt,
                                                 const int* __restrict__ partials,
                                                 int* __restrict__ rp, int N,
                                                 int PB) {
    __shared__ int lds[256];
    const int r = blockIdx.y, b = blockIdx.x, tid = threadIdx.x;
    const int gi = b * 256 + tid;
    const int v = (gi < N) ? cnt[(size_t)r * N + gi] : 0;
    lds[tid] = v;
    __syncthreads();
    int acc = v;
    for (int off = 1; off < 256; off <<= 1) {
        const int t = (tid >= off) ? lds[tid - off] : 0;
        __syncthreads();
        acc += t;
        lds[tid] = acc;
        __syncthreads();
    }
    if (gi < N) rp[(size_t)r * (N + 1) + gi] = partials[r * PB + b] + acc - v;
}

__global__ __launch_bounds__(256) void scatter3_k(
    const int* __restrict__ d0, const int* __restrict__ d1,
    const int* __restrict__ d2, const int* __restrict__ s0_,
    const int* __restrict__ s1_, const int* __restrict__ s2_,
    const int* __restrict__ rp, int* __restrict__ fill,
    int* __restrict__ colsrc, int N, int E) {
    const int i = blockIdx.x * 256 + threadIdx.x;
    if (i >= E) return;
    const int r = blockIdx.y;
    const int* d = r == 0 ? d0 : r == 1 ? d1 : d2;
    const int* s = r == 0 ? s0_ : r == 1 ? s1_ : s2_;
    const int dd = d[i];
    const int p = rp[(size_t)r * (N + 1) + dd] + atomicAdd(&fill[(size_t)r * N + dd], 1);
    colsrc[(size_t)r * E + p] = s[i];
}

// ---------------------------------------------------------------------------
// Scoring: wave per dst; 16 lanes per edge, 4 edges in flight.
// ---------------------------------------------------------------------------
__device__ __forceinline__ void score_rel_g(
    const f16x8 q0, const f16x8 q1, const _Float16* __restrict__ kA,
    const int* __restrict__ cs, int beg, int end, float scl,
    float* __restrict__ sc, int grp, int j, float& m) {
    for (int i = beg + grp; i < end; i += 4) {
        const int s = cs[i];
        const _Float16* row = &kA[(size_t)s * 256 + j * 16];
        const f16x8 k0 = *(const f16x8*)row;
        const f16x8 k1 = *(const f16x8*)(row + 8);
        float p = dot8f(q1, k1, dot8f(q0, k0, 0.f));
        p += __shfl_xor(p, 1);
        p += __shfl_xor(p, 2);
        const float v = p * scl;
        if ((j & 3) == 0) {
            sc[(size_t)i * 4 + (j >> 2)] = v;
            m = fmaxf(m, v);
        }
    }
}

__global__ __launch_bounds__(256) void score3_k(
    const _Float16* __restrict__ qe, const _Float16* __restrict__ kA0,
    const _Float16* __restrict__ kA1, const _Float16* __restrict__ qs,
    const _Float16* __restrict__ kA2, const int* __restrict__ rp,
    const int* __restrict__ colsrc, const float* __restrict__ muL,
    float* __restrict__ sc, float* __restrict__ mx_e,
    float* __restrict__ mx_s, int N, int E) {
    const int wid = (blockIdx.x * blockDim.x + threadIdx.x) >> 6;
    if (wid >= N) return;
    const int lane = threadIdx.x & 63;
    const int grp = lane >> 4, j = lane & 15, h = j >> 2;
    const size_t E4 = (size_t)E * 4;
    float m = -1e30f;
    if (blockIdx.y == 0) {
        const _Float16* qrow = &qe[(size_t)wid * 256 + j * 16];
        const f16x8 q0 = *(const f16x8*)qrow;
        const f16x8 q1 = *(const f16x8*)(qrow + 8);
        score_rel_g(q0, q1, kA0, colsrc, rp[wid], rp[wid + 1],
                    muL[0 * 4 + h] * 0.125f, sc, grp, j, m);
        const int* rp2 = rp + 2 * (N + 1);
        score_rel_g(q0, q1, kA2, colsrc + 2 * (size_t)E, rp2[wid], rp2[wid + 1],
                    muL[2 * 4 + h] * 0.125f, sc + 2 * E4, grp, j, m);
        m = fmaxf(m, __shfl_xor(m, 16));
        m = fmaxf(m, __shfl_xor(m, 32));
        if (grp == 0 && (j & 3) == 0) mx_e[(size_t)wid * 4 + h] = m;
    } else {
        const _Float16* qrow = &qs[(size_t)wid * 256 + j * 16];
        const f16x8 q0 = *(const f16x8*)qrow;
        const f16x8 q1 = *(const f16x8*)(qrow + 8);
        const int* rp1 = rp + (N + 1);
        score_rel_g(q0, q1, kA1, colsrc + (size_t)E, rp1[wid], rp1[wid + 1],
                    muL[1 * 4 + h] * 0.125f, sc + E4, grp, j, m);
        m = fmaxf(m, __shfl_xor(m, 16));
        m = fmaxf(m, __shfl_xor(m, 32));
        if (grp == 0 && (j & 3) == 0) mx_s[(size_t)wid * 4 + h] = m;
    }
}

// ---------------------------------------------------------------------------
// Aggregation (single-pass online, native __expf): w = __expf(s-m); den += w;
// acc += w*v. Cross-group combine, normalize, distributed GELU, f16x4 store.
// ---------------------------------------------------------------------------
__device__ __forceinline__ void agg_rel_on(
    const float* __restrict__ sc, const _Float16* __restrict__ vM,
    const int* __restrict__ cs, int beg, int end, float mh, int grp, int j,
    int h, float* accf, float& den) {
    for (int i = beg + grp; i < end; i += 4) {
        const int s = cs[i];
        const float w = __expf(sc[(size_t)i * 4 + h] - mh);
        den += w;
        const _Float16* row = &vM[(size_t)s * 256 + j * 16];
        const f16x8 v0 = *(const f16x8*)row;
        const f16x8 v1 = *(const f16x8*)(row + 8);
#pragma unroll
        for (int t = 0; t < 8; ++t) accf[t] += w * (float)v0[t];
#pragma unroll
        for (int t = 0; t < 8; ++t) accf[8 + t] += w * (float)v1[t];
    }
}

__global__ __launch_bounds__(256) void agg3_k(
    const float* __restrict__ sc, const _Float16* __restrict__ vM0,
    const _Float16* __restrict__ vM1, const _Float16* __restrict__ vM2,
    const int* __restrict__ rp, const int* __restrict__ colsrc,
    const float* __restrict__ mx_e, const float* __restrict__ mx_s,
    _Float16* __restrict__ outE, _Float16* __restrict__ outS, int N, int E) {
    const int wid = (blockIdx.x * blockDim.x + threadIdx.x) >> 6;
    if (wid >= N) return;
    const int lane = threadIdx.x & 63;
    const int grp = lane >> 4, j = lane & 15, h = j >> 2;
    const size_t E4 = (size_t)E * 4;
    float accf[16] = {};
    float den = 0.f;
    _Float16* outp;
    if (blockIdx.y == 0) {
        const float mh = mx_e[(size_t)wid * 4 + h];
        const int b0 = rp[wid], e0 = rp[wid + 1];
        const int* rp2 = rp + 2 * (N + 1);
        const int b2 = rp2[wid], e2 = rp2[wid + 1];
        agg_rel_on(sc, vM0, colsrc, b0, e0, mh, grp, j, h, accf, den);
        agg_rel_on(sc + 2 * E4, vM2, colsrc + 2 * (size_t)E, b2, e2, mh, grp,
                   j, h, accf, den);
        outp = outE;
    } else {
        const float mh = mx_s[(size_t)wid * 4 + h];
        const int* rp1 = rp + (N + 1);
        const int b1 = rp1[wid], e1 = rp1[wid + 1];
        agg_rel_on(sc + E4, vM1, colsrc + (size_t)E, b1, e1, mh, grp, j, h,
                   accf, den);
        outp = outS;
    }
    den += __shfl_xor(den, 16);
    den += __shfl_xor(den, 32);
#pragma unroll
    for (int t = 0; t < 16; ++t) {
        accf[t] += __shfl_xor(accf[t], 16);
        accf[t] += __shfl_xor(accf[t], 32);
    }
    const float dinv = 1.0f / (den + 1e-16f);
    f16x4 o;
#pragma unroll
    for (int t = 0; t < 4; ++t)
        o[t] = (_Float16)gelu_f(accf[grp * 4 + t] * dinv);
    *(f16x4*)&outp[(size_t)wid * 256 + j * 16 + grp * 4] = o;
}

// ---------------------------------------------------------------------------
// Batched head epilogue.
// ---------------------------------------------------------------------------
__global__ __launch_bounds__(256) void head2_k(const _Float16* __restrict__ t,
                                               const float* __restrict__ Wt2,
                                               const float* __restrict__ bt2,
                                               float* __restrict__ out, int M) {
    const int k = blockIdx.y;
    __shared__ float Ws[128 * 8];
    __shared__ float bs[8];
    const int tid = threadIdx.x;
    const float* W2 = Wt2 + (size_t)k * 1024;
    for (int i = tid; i < 1024; i += 256) Ws[i] = W2[i];
    if (tid < 8) bs[tid] = bt2[k * 8 + tid];
    __syncthreads();
    const int OFFA[7] = {0, 3, 6, 9, 14, 15, 16};
    const int DIMSA[7] = {3, 3, 3, 5, 1, 1, 8};
    const int nl = tid >> 3, o = tid & 7;
    const int n = blockIdx.x * 32 + nl;
    if (n >= M) return;
    const _Float16* tr = &t[(size_t)n * 896 + k * 128];
    float acc = bs[o];
#pragma unroll 8
    for (int d = 0; d < 128; ++d) acc += (float)tr[d] * Ws[d * 8 + o];
    if (o < DIMSA[k]) out[(size_t)n * 24 + OFFA[k] + o] = acc;
}

// ---------------------------------------------------------------------------

extern "C" void kernel_launch(void* const* d_in, const int* in_sizes, int n_in,
                              void* d_out, int out_size, void* d_ws,
                              size_t ws_size, hipStream_t stream) {
    const float* xe_in = (const float*)d_in[0];
    const float* xs_in = (const float*)d_in[1];
    const int* ee_src = (const int*)d_in[2];
    const int* ee_dst = (const int*)d_in[3];
    const int* es_src = (const int*)d_in[4];
    const int* es_dst = (const int*)d_in[5];
    const int* se_src = (const int*)d_in[6];
    const int* se_dst = (const int*)d_in[7];
    const float* Wk = (const float*)d_in[8];
    const float* Wq = (const float*)d_in[9];
    const float* Wv = (const float*)d_in[10];
    const float* Wa = (const float*)d_in[11];
    const float* skip = (const float*)d_in[12];
    const float* Arel = (const float*)d_in[13];
    const float* Mrel = (const float*)d_in[14];
    const float* mu = (const float*)d_in[15];
    const float* Wsh = (const float*)d_in[16];
    const float* bsh = (const float*)d_in[17];
    const float* Wt1 = (const float*)d_in[18];
    const float* bt1 = (const float*)d_in[19];
    const float* Wt2 = (const float*)d_in[20];
    const float* bt2 = (const float*)d_in[21];
    float* out = (float*)d_out;

    const int N = in_sizes[0] / CDIM;  // 50000
    const int E = in_sizes[2];         // 200000
    const size_t NC = (size_t)N * CDIM;
    const size_t E4 = (size_t)E * 4;
    const size_t N4 = (size_t)N * 4;
    const int PB = (N + 255) / 256;

    const size_t halfs = 7 * NC + 32 * (size_t)AR_R + 7 * 32768;
    const size_t floats = 3 * E4 + 2 * N4;
    const size_t ints =
        3 * (size_t)(N + 1) + 3 * (size_t)E + 3 * (size_t)N + 3 * (size_t)PB;
    const size_t need = halfs * 2 + floats * 4 + ints * 4;
    if (ws_size < need) return;

    _Float16* xeH = (_Float16*)d_ws;
    _Float16* xsH = xeH + NC;
    _Float16* Hb = xsH + NC;
    _Float16* H1 = Hb;
    _Float16* H2 = Hb + NC;
    _Float16* H3 = Hb + 2 * NC;
    _Float16* H4 = Hb + 3 * NC;
    _Float16* H5 = Hb + 4 * NC;
    _Float16* arena = Hb + 5 * NC;
    _Float16* SA = arena + (size_t)30 * AR_R;
    _Float16* HA = SA + (size_t)2 * AR_R;
    float* sc = (float*)(HA + (size_t)7 * 32768);
    float* mx_e = sc + 3 * E4;
    float* mx_s = mx_e + N4;
    int* rp = (int*)(mx_s + N4);
    int* colsrc = rp + 3 * (size_t)(N + 1);
    int* cnt = colsrc + 3 * (size_t)E;
    int* partials = cnt + 3 * (size_t)N;

    const int gx = (N + 127) / 128;
    const dim3 e3((E + 255) / 256, 3);
    const dim3 p3(PB, 3);
    const int wave_blocks = (N + 3) / 4;
    const int zc_blocks = (3 * N + 255) / 256;

    // ---- CSR build ----
    zero_k<<<zc_blocks, 256, 0, stream>>>(cnt, 3 * (size_t)N);
    hist3_k<<<e3, 256, 0, stream>>>(ee_dst, es_dst, se_dst, cnt, N, E);
    partial_k<<<p3, 256, 0, stream>>>(cnt, partials, N, PB);
    scanp_k<<<dim3(1, 3), 256, 0, stream>>>(partials, rp, N, PB, E);
    rpwrite_k<<<p3, 256, 0, stream>>>(cnt, partials, rp, N, PB);
    zero_k<<<zc_blocks, 256, 0, stream>>>(cnt, 3 * (size_t)N);
    scatter3_k<<<e3, 256, 0, stream>>>(ee_dst, es_dst, se_dst, ee_src, es_src,
                                       se_src, rp, cnt, colsrc, N, E);

    // ---- weight prep (one dispatch for all layers) + stack/heads ----
    prep_layer_k<<<dim3(256, 30), 256, 0, stream>>>(Wk, Wq, Wv, Wa, Arel, Mrel,
                                                    arena);
    prep_stack_k<<<dim3(256, 2), 256, 0, stream>>>(Wsh, SA);
    prep_heads_k<<<dim3(128, 7), 256, 0, stream>>>(Wt1, HA);

    // ---- initial fp16 activations (one dispatch) ----
    cvt2_k<<<dim3(1024, 2), 256, 0, stream>>>(xe_in, xs_in, xeH, xsH, NC / 4);

    for (int l = 0; l < 3; ++l) {
        _Float16* L = arena + (size_t)l * 10 * AR_R;
        projq_k<<<dim3(10, gx), 256, 0, stream>>>(xeH, xsH, L, Hb, N);
        score3_k<<<dim3(wave_blocks, 2), 256, 0, stream>>>(
            H1, H2, H3, H4, H5, rp, colsrc, mu + l * 12, sc, mx_e, mx_s, N, E);
        projv_k<<<dim3(6, gx), 256, 0, stream>>>(xeH, xsH, L, Hb, N);
        agg3_k<<<dim3(wave_blocks, 2), 256, 0, stream>>>(
            sc, H2, H3, H5, rp, colsrc, mx_e, mx_s, H1, H4, N, E);
        update2_k<<<dim3(4, gx), 256, 0, stream>>>(
            H1, H4, L + 8 * AR_R, L + 9 * AR_R, xeH, xsH, skip + l * 2, N);
    }

    // shared linear stack
    gemm_h<2, false><<<dim3(2, gx), 256, 0, stream>>>(xeH, SA, H5, N, 256, 0,
                                                      bsh, nullptr);
    gemm_h<2, false><<<dim3(2, gx), 256, 0, stream>>>(H5, SA + AR_R, xsH, N,
                                                      256, 0, bsh + 256, nullptr);
    // 7 task heads
    gemm_h<2, false><<<dim3(7, gx), 256, 0, stream>>>(xsH, HA, Hb, N, 896, 0,
                                                      bt1, nullptr);
    head2_k<<<dim3((N + 31) / 32, 7), 256, 0, stream>>>(Hb, Wt2, bt2, out, N);
}